// Round 1
// baseline (2937.317 us; speedup 1.0000x reference)
//
#include <hip/hip_runtime.h>
#include <math.h>

#define BB 2
#define TT 24
#define DD 32
#define HWp 4096            // 64*64
#define NN (BB*TT)          // 48
#define PIX (NN*HWp)        // 196608
#define C2 (2*DD)           // 64

// d_out offsets (floats)
#define MAIN_RE 0
#define MAIN_IM (NN*DD*HWp)              // 6291456
#define HOUT_RE (2*NN*DD*HWp)            // 12582912
#define HOUT_IM (HOUT_RE + BB*HWp*DD)    // 12845056
#define FLUX_RE (HOUT_RE + 2*BB*HWp*DD)  // 13107200
#define FLUX_IM (FLUX_RE + BB*DD)        // 13107264

// ws offsets (floats)
#define WS_XN   0                        // PIX*64   xn (LN output), later: dec (channels-last)
#define WS_XE   (WS_XN + PIX*C2)         // PIX*64   x_eig -> u_t -> u_out (channels-last, re at +e, im at +32+e)
#define WS_G1   (WS_XE + PIX*C2)         // PIX*32   g1 -> sp_gate
#define WS_G2   (WS_G1 + PIX*DD)         // PIX*32   g2
#define WS_WINV (WS_G2 + PIX*DD)         // 2048 (re 1024, im 1024)
#define WS_SUMS (WS_WINV + 2048)         // 3072  per-(n) channel sums (re 0..31, im 32..63)
#define WS_GATE (WS_SUMS + 3072)         // 1536
#define WS_SRCR (WS_GATE + 1536)
#define WS_SRCI (WS_SRCR + 1536)
#define WS_ODR  (WS_SRCI + 1536)
#define WS_ODI  (WS_ODR + 1536)
#define WS_OFR  (WS_ODI + 1536)
#define WS_OFI  (WS_OFR + 1536)

__device__ __forceinline__ float sigmoidf_(float x) { return 1.f / (1.f + expf(-x)); }
__device__ __forceinline__ float softplusf_(float x) { return log1pf(expf(x)); }

// ---------------- Gauss-Jordan inverse of Wb (32x32 complex), partial pivoting ----------------
__global__ void k_invert(const float* __restrict__ Wre, const float* __restrict__ Wim,
                         float* __restrict__ ws) {
  __shared__ float Mre[32][64];
  __shared__ float Mim[32][64];
  __shared__ float fre[32], fim[32];
  __shared__ float pr_s, pi_s;
  __shared__ int piv_s;
  int tid = threadIdx.x;  // 256 threads
  for (int idx = tid; idx < 2048; idx += 256) {
    int i = idx >> 6, j = idx & 63;
    if (j < 32) { Mre[i][j] = Wre[i * 32 + j]; Mim[i][j] = Wim[i * 32 + j]; }
    else        { Mre[i][j] = (j - 32 == i) ? 1.f : 0.f; Mim[i][j] = 0.f; }
  }
  __syncthreads();
  for (int k = 0; k < 32; ++k) {
    if (tid == 0) {
      int best = k; float bm = fabsf(Mre[k][k]) + fabsf(Mim[k][k]);
      for (int r = k + 1; r < 32; ++r) {
        float m = fabsf(Mre[r][k]) + fabsf(Mim[r][k]);
        if (m > bm) { bm = m; best = r; }
      }
      piv_s = best;
    }
    __syncthreads();
    int pv = piv_s;
    if (pv != k && tid < 64) {
      float tr = Mre[k][tid], ti = Mim[k][tid];
      Mre[k][tid] = Mre[pv][tid]; Mim[k][tid] = Mim[pv][tid];
      Mre[pv][tid] = tr; Mim[pv][tid] = ti;
    }
    __syncthreads();
    if (tid == 0) {
      float a = Mre[k][k], b = Mim[k][k];
      float d = a * a + b * b;
      pr_s = a / d; pi_s = -b / d;
    }
    __syncthreads();
    float pr = pr_s, pi = pi_s;
    if (tid < 64) {
      float a = Mre[k][tid], b = Mim[k][tid];
      Mre[k][tid] = a * pr - b * pi;
      Mim[k][tid] = a * pi + b * pr;
    }
    __syncthreads();
    if (tid < 32) { fre[tid] = Mre[tid][k]; fim[tid] = Mim[tid][k]; }
    __syncthreads();
    for (int idx = tid; idx < 2048; idx += 256) {
      int i = idx >> 6, j = idx & 63;
      if (i != k) {
        float fr = fre[i], fi = fim[i];
        float ar = Mre[k][j], ai = Mim[k][j];
        Mre[i][j] -= fr * ar - fi * ai;
        Mim[i][j] -= fr * ai + fi * ar;
      }
    }
    __syncthreads();
  }
  for (int idx = tid; idx < 1024; idx += 256) {
    int e = idx >> 5, d = idx & 31;
    ws[WS_WINV + e * 32 + d] = Mre[e][32 + d];
    ws[WS_WINV + 1024 + e * 32 + d] = Mim[e][32 + d];
  }
}

// ---------------- spatial LayerNorm over 64 (re,im) channels -> xn (NCHW) ----------------
__global__ void k_ln_s(const float* __restrict__ xre, const float* __restrict__ xim,
                       const float* __restrict__ g, const float* __restrict__ b,
                       float* __restrict__ ws) {
  int gid = blockIdx.x * 256 + threadIdx.x;
  if (gid >= PIX) return;
  int n = gid >> 12, p = gid & 4095;
  float v[64];
  float s = 0.f;
#pragma unroll
  for (int c = 0; c < 32; ++c) { v[c] = xre[(n * 32 + c) * 4096 + p]; s += v[c]; }
#pragma unroll
  for (int c = 0; c < 32; ++c) { v[32 + c] = xim[(n * 32 + c) * 4096 + p]; s += v[32 + c]; }
  float m = s * (1.f / 64.f);
  float vs = 0.f;
#pragma unroll
  for (int c = 0; c < 64; ++c) { float d = v[c] - m; vs += d * d; }
  float rs = rsqrtf(vs * (1.f / 64.f) + 1e-5f);
#pragma unroll
  for (int c = 0; c < 64; ++c)
    ws[WS_XN + (n * 64 + c) * 4096 + p] = (v[c] - m) * rs * g[c] + b[c];
}

// ---------------- 3x3 conv 64->64 (each thread: one pixel, co and co+32) + residual x ----------------
// writes x_upd = x + conv into d_out main slots
__global__ void k_conv(const float* __restrict__ ws, const float* __restrict__ wconv,
                       const float* __restrict__ bconv,
                       const float* __restrict__ xre, const float* __restrict__ xim,
                       float* __restrict__ out) {
  int gid = blockIdx.x * 256 + threadIdx.x;
  if (gid >= NN * DD * HWp) return;
  int p = gid & 4095;
  int co = (gid >> 12) & 31;
  int n = gid >> 17;
  int y = p >> 6, x = p & 63;
  float ar = bconv[co], ai = bconv[co + 32];
  const float* xn = ws + WS_XN + n * 64 * 4096;
  for (int ci = 0; ci < 64; ++ci) {
    const float* wr = wconv + (co * 64 + ci) * 9;
    const float* wi = wconv + ((co + 32) * 64 + ci) * 9;
    const float* in = xn + ci * 4096;
#pragma unroll
    for (int ky = 0; ky < 3; ++ky) {
      int yy = y + ky - 1;
      if ((unsigned)yy < 64u) {
        const float* row = in + yy * 64;
#pragma unroll
        for (int kx = 0; kx < 3; ++kx) {
          int xx = x + kx - 1;
          if ((unsigned)xx < 64u) {
            float v = row[xx];
            ar = fmaf(v, wr[ky * 3 + kx], ar);
            ai = fmaf(v, wi[ky * 3 + kx], ai);
          }
        }
      }
    }
  }
  int oidx = (n * 32 + co) * 4096 + p;
  out[MAIN_RE + oidx] = xre[oidx] + ar;
  out[MAIN_IM + oidx] = xim[oidx] + ai;
}

// ---------------- x_eig = x_upd @ Wb (complex, per pixel) -> channels-last ----------------
__global__ void k_xeig(const float* __restrict__ out,
                       const float* __restrict__ Wre, const float* __restrict__ Wim,
                       float* __restrict__ ws) {
  int gid = blockIdx.x * 256 + threadIdx.x;
  if (gid >= PIX * 32) return;
  int e = gid & 31;
  int g = gid >> 5;
  int n = g >> 12, p = g & 4095;
  float ar = 0.f, ai = 0.f;
#pragma unroll 8
  for (int d = 0; d < 32; ++d) {
    float xr = out[MAIN_RE + (n * 32 + d) * 4096 + p];
    float xi = out[MAIN_IM + (n * 32 + d) * 4096 + p];
    float wr = Wre[d * 32 + e], wi = Wim[d * 32 + e];
    ar += xr * wr - xi * wi;
    ai += xr * wi + xi * wr;
  }
  ws[WS_XE + g * 64 + e] = ar;
  ws[WS_XE + g * 64 + 32 + e] = ai;
}

// ---------------- spatial sums of x_eig per (n, channel) ----------------
__global__ void k_mean(float* __restrict__ ws) {
  __shared__ float red[256];
  int n = blockIdx.x;
  int tid = threadIdx.x;
  int c = tid & 63, pg = tid >> 6;
  float s = 0.f;
  for (int p = pg; p < 4096; p += 4)
    s += ws[WS_XE + (n * 4096 + p) * 64 + c];
  red[tid] = s;
  __syncthreads();
  if (tid < 64)
    ws[WS_SUMS + n * 64 + tid] = red[tid] + red[64 + tid] + red[128 + tid] + red[192 + tid];
  (void)c;
}

// ---------------- flux scan (T=24) + all per-(b,t,d) coefficients ----------------
__global__ void k_flux(float* __restrict__ ws, float* __restrict__ out,
                       const float* __restrict__ dt_seq,
                       const float* __restrict__ flux_re, const float* __restrict__ flux_im,
                       const float* __restrict__ lam_flux,
                       const float* __restrict__ bf_re, const float* __restrict__ bf_im,
                       const float* __restrict__ c_re, const float* __restrict__ c_im,
                       const float* __restrict__ g_w, const float* __restrict__ g_b,
                       const float* __restrict__ a_decay, const float* __restrict__ b_freq) {
  int tid = threadIdx.x;
  if (tid >= 64) return;
  int b = tid >> 5, e = tid & 31;
  float sp_lf = softplusf_(lam_flux[e]);
  float lr = -softplusf_(a_decay[e]);
  float li = b_freq[e];
  float den = lr * lr + li * li;
  float bfr = bf_re[e], bfi = bf_im[e];
  float cr = c_re[e], ci = c_im[e];
  float fr = flux_re[b * 32 + e], fi = flux_im[b * 32 + e];
  for (int t = 0; t < 24; ++t) {
    int n = b * 24 + t;
    float dt = dt_seq[n];
    float A = expf(-sp_lf * dt);
    float xmr = ws[WS_SUMS + n * 64 + e] * (1.f / 4096.f);
    float xmi = ws[WS_SUMS + n * 64 + 32 + e] * (1.f / 4096.f);
    float Xr = (bfr * xmr - bfi * xmi) * dt;
    float Xi = (bfr * xmi + bfi * xmr) * dt;
    fr = A * fr + Xr;
    fi = A * fi + Xi;
    ws[WS_GATE + n * 32 + e] = sigmoidf_(fr * g_w[e] + g_b[e]);
    ws[WS_SRCR + n * 32 + e] = fr * cr - fi * ci;
    ws[WS_SRCI + n * 32 + e] = fr * ci + fi * cr;
    float er = expf(lr * dt);
    float odr = er * cosf(li * dt);
    float odi = er * sinf(li * dt);
    ws[WS_ODR + n * 32 + e] = odr;
    ws[WS_ODI + n * 32 + e] = odi;
    float nr = odr - 1.f, ni = odi;
    ws[WS_OFR + n * 32 + e] = (nr * lr + ni * li) / den;
    ws[WS_OFI + n * 32 + e] = (ni * lr - nr * li) / den;
  }
  out[FLUX_RE + b * 32 + e] = fr;
  out[FLUX_IM + b * 32 + e] = fi;
}

// ---------------- spatial gate: 1x1 conv 64->32 + silu ----------------
__global__ void k_sg1(float* __restrict__ ws, const float* __restrict__ w1, const float* __restrict__ b1) {
  int gid = blockIdx.x * 256 + threadIdx.x;
  if (gid >= PIX * 32) return;
  int oc = gid & 31, g = gid >> 5;
  float acc = b1[oc];
#pragma unroll 8
  for (int c = 0; c < 64; ++c)
    acc = fmaf(ws[WS_XE + g * 64 + c], w1[oc * 64 + c], acc);
  ws[WS_G1 + g * 32 + oc] = acc * sigmoidf_(acc);
}

// ---------------- spatial gate: depthwise 3x3 ----------------
__global__ void k_sgdw(float* __restrict__ ws, const float* __restrict__ dw) {
  int gid = blockIdx.x * 256 + threadIdx.x;
  if (gid >= PIX * 32) return;
  int oc = gid & 31, g = gid >> 5;
  int n = g >> 12, p = g & 4095;
  int y = p >> 6, x = p & 63;
  float acc = 0.f;
#pragma unroll
  for (int ky = 0; ky < 3; ++ky) {
    int yy = y + ky - 1;
    if ((unsigned)yy < 64u) {
#pragma unroll
      for (int kx = 0; kx < 3; ++kx) {
        int xx = x + kx - 1;
        if ((unsigned)xx < 64u)
          acc = fmaf(ws[WS_G1 + (n * 4096 + yy * 64 + xx) * 32 + oc], dw[oc * 9 + ky * 3 + kx], acc);
      }
    }
  }
  ws[WS_G2 + g * 32 + oc] = acc;
}

// ---------------- spatial gate: 1x1 conv 32->32 + sigmoid (overwrites g1 buffer) ----------------
__global__ void k_sg3(float* __restrict__ ws, const float* __restrict__ w2, const float* __restrict__ b2) {
  int gid = blockIdx.x * 256 + threadIdx.x;
  if (gid >= PIX * 32) return;
  int oc = gid & 31, g = gid >> 5;
  float acc = b2[oc];
#pragma unroll 8
  for (int c = 0; c < 32; ++c)
    acc = fmaf(ws[WS_G2 + g * 32 + c], w2[oc * 32 + c], acc);
  ws[WS_G1 + g * 32 + oc] = sigmoidf_(acc);
}

// ---------------- forcing -> u_t (in place over x_eig buffer) ----------------
__global__ void k_force(float* __restrict__ ws,
                        const float* __restrict__ hre, const float* __restrict__ him) {
  int gid = blockIdx.x * 256 + threadIdx.x;
  if (gid >= PIX * 32) return;
  int e = gid & 31, g = gid >> 5;
  int n = g >> 12, p = g & 4095;
  int b = (n >= 24) ? 1 : 0;
  int t = n - b * 24;
  int ie = n * 32 + e;
  float gc = ws[WS_GATE + ie] * ws[WS_G1 + g * 32 + e];
  float xr = ws[WS_XE + g * 64 + e];
  float xi = ws[WS_XE + g * 64 + 32 + e];
  float om = 1.f - gc;
  float fr2 = xr * gc + ws[WS_SRCR + ie] * om;
  float fi2 = xi * gc + ws[WS_SRCI + ie] * om;
  float ofr = ws[WS_OFR + ie], ofi = ws[WS_OFI + ie];
  float ur = fr2 * ofr - fi2 * ofi;
  float ui = fr2 * ofi + fi2 * ofr;
  if (t == 0) {
    int hb = (b * 4096 + p) * 32 + e;
    float hr = hre[hb], hi = him[hb];
    float odr = ws[WS_ODR + (b * 24) * 32 + e], odi = ws[WS_ODI + (b * 24) * 32 + e];
    ur += hr * odr - hi * odi;
    ui += hr * odi + hi * odr;
  }
  ws[WS_XE + g * 64 + e] = ur;
  ws[WS_XE + g * 64 + 32 + e] = ui;
}

// ---------------- temporal scan over T=24 (in place), emit h_out ----------------
__global__ void k_scan(float* __restrict__ ws, float* __restrict__ out) {
  int gid = blockIdx.x * 256 + threadIdx.x;
  if (gid >= BB * HWp * 32) return;
  int e = gid & 31;
  int p = (gid >> 5) & 4095;
  int b = gid >> 17;
  float ur = 0.f, ui = 0.f;
  for (int t = 0; t < 24; ++t) {
    int n = b * 24 + t;
    int idx = WS_XE + (n * 4096 + p) * 64 + e;
    float ar = ws[WS_ODR + n * 32 + e], ai = ws[WS_ODI + n * 32 + e];
    float xr = ws[idx], xi = ws[idx + 32];
    float nr = ar * ur - ai * ui + xr;
    float ni = ar * ui + ai * ur + xi;
    ur = nr; ui = ni;
    ws[idx] = ur;
    ws[idx + 32] = ui;
  }
  int hb = (b * 4096 + p) * 32 + e;
  out[HOUT_RE + hb] = ur;
  out[HOUT_IM + hb] = ui;
}

// ---------------- dec = u_out @ Wb_inv (complex, per pixel) -> channels-last in WS_XN ----------------
__global__ void k_dec(float* __restrict__ ws) {
  int gid = blockIdx.x * 256 + threadIdx.x;
  if (gid >= PIX * 32) return;
  int d = gid & 31, g = gid >> 5;
  float ar = 0.f, ai = 0.f;
#pragma unroll 8
  for (int e = 0; e < 32; ++e) {
    float ur = ws[WS_XE + g * 64 + e], ui = ws[WS_XE + g * 64 + 32 + e];
    float wr = ws[WS_WINV + e * 32 + d], wi = ws[WS_WINV + 1024 + e * 32 + d];
    ar += ur * wr - ui * wi;
    ai += ur * wi + ui * wr;
  }
  ws[WS_XN + g * 64 + d] = ar;
  ws[WS_XN + g * 64 + 32 + d] = ai;
}

// ---------------- LN_t + FFN (64->128->64) + z = x_upd + dec + delta (in place on d_out) ----------------
__global__ void k_final(float* __restrict__ ws, float* __restrict__ out,
                        const float* __restrict__ lg, const float* __restrict__ lb,
                        const float* __restrict__ w1, const float* __restrict__ b1,
                        const float* __restrict__ w2, const float* __restrict__ b2) {
  int gid = blockIdx.x * 256 + threadIdx.x;
  if (gid >= PIX) return;
  int n = gid >> 12, p = gid & 4095;
  float dn[64];
  float s = 0.f;
#pragma unroll
  for (int c = 0; c < 64; ++c) { dn[c] = ws[WS_XN + gid * 64 + c]; s += dn[c]; }
  float m = s * (1.f / 64.f);
  float vs = 0.f;
#pragma unroll
  for (int c = 0; c < 64; ++c) { float d = dn[c] - m; vs += d * d; }
  float rs = rsqrtf(vs * (1.f / 64.f) + 1e-5f);
#pragma unroll
  for (int c = 0; c < 64; ++c) dn[c] = (dn[c] - m) * rs * lg[c] + lb[c];
  float o2[64];
#pragma unroll
  for (int c = 0; c < 64; ++c) o2[c] = b2[c];
  for (int k = 0; k < 128; ++k) {
    float sacc = b1[k];
#pragma unroll
    for (int c = 0; c < 64; ++c) sacc = fmaf(dn[c], w1[c * 128 + k], sacc);
    float h = sacc * sigmoidf_(sacc);
#pragma unroll
    for (int c = 0; c < 64; ++c) o2[c] = fmaf(h, w2[k * 64 + c], o2[c]);
  }
#pragma unroll
  for (int d = 0; d < 32; ++d) {
    int oi = (n * 32 + d) * 4096 + p;
    out[MAIN_RE + oi] += ws[WS_XN + gid * 64 + d] + o2[d];
    out[MAIN_IM + oi] += ws[WS_XN + gid * 64 + 32 + d] + o2[32 + d];
  }
}

extern "C" void kernel_launch(void* const* d_in, const int* in_sizes, int n_in,
                              void* d_out, int out_size, void* d_ws, size_t ws_size,
                              hipStream_t stream) {
  (void)in_sizes; (void)n_in; (void)out_size; (void)ws_size;
  const float* xre      = (const float*)d_in[0];
  const float* xim      = (const float*)d_in[1];
  const float* hre      = (const float*)d_in[2];
  const float* him      = (const float*)d_in[3];
  const float* flux_re  = (const float*)d_in[4];
  const float* flux_im  = (const float*)d_in[5];
  const float* dt_seq   = (const float*)d_in[6];
  const float* ln_s_g   = (const float*)d_in[7];
  const float* ln_s_b   = (const float*)d_in[8];
  const float* conv_w   = (const float*)d_in[9];
  const float* conv_b   = (const float*)d_in[10];
  const float* ln_t_g   = (const float*)d_in[11];
  const float* ln_t_b   = (const float*)d_in[12];
  const float* W_re     = (const float*)d_in[13];
  const float* W_im     = (const float*)d_in[14];
  const float* lam_flux = (const float*)d_in[15];
  const float* bf_re    = (const float*)d_in[16];
  const float* bf_im    = (const float*)d_in[17];
  const float* c_re     = (const float*)d_in[18];
  const float* c_im     = (const float*)d_in[19];
  const float* g_w      = (const float*)d_in[20];
  const float* g_b      = (const float*)d_in[21];
  const float* a_decay  = (const float*)d_in[22];
  const float* b_freq   = (const float*)d_in[23];
  const float* ffn_w1   = (const float*)d_in[24];
  const float* ffn_b1   = (const float*)d_in[25];
  const float* ffn_w2   = (const float*)d_in[26];
  const float* ffn_b2   = (const float*)d_in[27];
  const float* sg_w1    = (const float*)d_in[28];
  const float* sg_b1    = (const float*)d_in[29];
  const float* sg_dw    = (const float*)d_in[30];
  const float* sg_w2    = (const float*)d_in[31];
  const float* sg_b2    = (const float*)d_in[32];
  float* out = (float*)d_out;
  float* ws  = (float*)d_ws;

  k_invert<<<1, 256, 0, stream>>>(W_re, W_im, ws);
  k_ln_s<<<PIX / 256, 256, 0, stream>>>(xre, xim, ln_s_g, ln_s_b, ws);
  k_conv<<<(NN * DD * HWp) / 256, 256, 0, stream>>>(ws, conv_w, conv_b, xre, xim, out);
  k_xeig<<<(PIX * 32) / 256, 256, 0, stream>>>(out, W_re, W_im, ws);
  k_mean<<<NN, 256, 0, stream>>>(ws);
  k_flux<<<1, 64, 0, stream>>>(ws, out, dt_seq, flux_re, flux_im, lam_flux,
                               bf_re, bf_im, c_re, c_im, g_w, g_b, a_decay, b_freq);
  k_sg1<<<(PIX * 32) / 256, 256, 0, stream>>>(ws, sg_w1, sg_b1);
  k_sgdw<<<(PIX * 32) / 256, 256, 0, stream>>>(ws, sg_dw);
  k_sg3<<<(PIX * 32) / 256, 256, 0, stream>>>(ws, sg_w2, sg_b2);
  k_force<<<(PIX * 32) / 256, 256, 0, stream>>>(ws, hre, him);
  k_scan<<<(BB * HWp * 32) / 256, 256, 0, stream>>>(ws, out);
  k_dec<<<(PIX * 32) / 256, 256, 0, stream>>>(ws);
  k_final<<<PIX / 256, 256, 0, stream>>>(ws, out, ln_t_g, ln_t_b,
                                         ffn_w1, ffn_b1, ffn_w2, ffn_b2);
}

// Round 2
// 1923.585 us; speedup vs baseline: 1.5270x; 1.5270x over previous
//
#include <hip/hip_runtime.h>
#include <math.h>

#define BB 2
#define TT 24
#define DD 32
#define HWp 4096            // 64*64
#define NN (BB*TT)          // 48
#define PIX (NN*HWp)        // 196608
#define C2 (2*DD)           // 64

// d_out offsets (floats)
#define MAIN_RE 0
#define MAIN_IM (NN*DD*HWp)              // 6291456
#define HOUT_RE (2*NN*DD*HWp)            // 12582912
#define HOUT_IM (HOUT_RE + BB*HWp*DD)    // 12845056
#define FLUX_RE (HOUT_RE + 2*BB*HWp*DD)  // 13107200
#define FLUX_IM (FLUX_RE + BB*DD)        // 13107264

// ws offsets (floats)
#define WS_XN   0                        // PIX*64   xn (LN output), later: dec (channels-last)
#define WS_XE   (WS_XN + PIX*C2)         // PIX*64   x_eig -> u_t -> u_out (channels-last)
#define WS_G1   (WS_XE + PIX*C2)         // PIX*32   g1 -> sp_gate
#define WS_G2   (WS_G1 + PIX*DD)         // PIX*32   g2
#define WS_WINV (WS_G2 + PIX*DD)         // 2048 (re 1024, im 1024)
#define WS_SUMS (WS_WINV + 2048)         // 3072  per-(n) channel sums
#define WS_GATE (WS_SUMS + 3072)         // 1536
#define WS_SRCR (WS_GATE + 1536)
#define WS_SRCI (WS_SRCR + 1536)
#define WS_ODR  (WS_SRCI + 1536)
#define WS_ODI  (WS_ODR + 1536)
#define WS_OFR  (WS_ODI + 1536)
#define WS_OFI  (WS_OFR + 1536)

__device__ __forceinline__ float sigmoidf_(float x) { return 1.f / (1.f + expf(-x)); }
__device__ __forceinline__ float softplusf_(float x) { return log1pf(expf(x)); }

// ---------------- Gauss-Jordan inverse of Wb (32x32 complex), partial pivoting ----------------
__global__ void k_invert(const float* __restrict__ Wre, const float* __restrict__ Wim,
                         float* __restrict__ ws) {
  __shared__ float Mre[32][64];
  __shared__ float Mim[32][64];
  __shared__ float fre[32], fim[32];
  __shared__ float pr_s, pi_s;
  __shared__ int piv_s;
  int tid = threadIdx.x;  // 256 threads
  for (int idx = tid; idx < 2048; idx += 256) {
    int i = idx >> 6, j = idx & 63;
    if (j < 32) { Mre[i][j] = Wre[i * 32 + j]; Mim[i][j] = Wim[i * 32 + j]; }
    else        { Mre[i][j] = (j - 32 == i) ? 1.f : 0.f; Mim[i][j] = 0.f; }
  }
  __syncthreads();
  for (int k = 0; k < 32; ++k) {
    if (tid == 0) {
      int best = k; float bm = fabsf(Mre[k][k]) + fabsf(Mim[k][k]);
      for (int r = k + 1; r < 32; ++r) {
        float m = fabsf(Mre[r][k]) + fabsf(Mim[r][k]);
        if (m > bm) { bm = m; best = r; }
      }
      piv_s = best;
    }
    __syncthreads();
    int pv = piv_s;
    if (pv != k && tid < 64) {
      float tr = Mre[k][tid], ti = Mim[k][tid];
      Mre[k][tid] = Mre[pv][tid]; Mim[k][tid] = Mim[pv][tid];
      Mre[pv][tid] = tr; Mim[pv][tid] = ti;
    }
    __syncthreads();
    if (tid == 0) {
      float a = Mre[k][k], b = Mim[k][k];
      float d = a * a + b * b;
      pr_s = a / d; pi_s = -b / d;
    }
    __syncthreads();
    float pr = pr_s, pi = pi_s;
    if (tid < 64) {
      float a = Mre[k][tid], b = Mim[k][tid];
      Mre[k][tid] = a * pr - b * pi;
      Mim[k][tid] = a * pi + b * pr;
    }
    __syncthreads();
    if (tid < 32) { fre[tid] = Mre[tid][k]; fim[tid] = Mim[tid][k]; }
    __syncthreads();
    for (int idx = tid; idx < 2048; idx += 256) {
      int i = idx >> 6, j = idx & 63;
      if (i != k) {
        float fr = fre[i], fi = fim[i];
        float ar = Mre[k][j], ai = Mim[k][j];
        Mre[i][j] -= fr * ar - fi * ai;
        Mim[i][j] -= fr * ai + fi * ar;
      }
    }
    __syncthreads();
  }
  for (int idx = tid; idx < 1024; idx += 256) {
    int e = idx >> 5, d = idx & 31;
    ws[WS_WINV + e * 32 + d] = Mre[e][32 + d];
    ws[WS_WINV + 1024 + e * 32 + d] = Mim[e][32 + d];
  }
}

// ---------------- spatial LayerNorm over 64 (re,im) channels -> xn (NCHW) ----------------
__global__ void k_ln_s(const float* __restrict__ xre, const float* __restrict__ xim,
                       const float* __restrict__ g, const float* __restrict__ b,
                       float* __restrict__ ws) {
  int gid = blockIdx.x * 256 + threadIdx.x;
  if (gid >= PIX) return;
  int n = gid >> 12, p = gid & 4095;
  float v[64];
  float s = 0.f;
#pragma unroll
  for (int c = 0; c < 32; ++c) { v[c] = xre[(n * 32 + c) * 4096 + p]; s += v[c]; }
#pragma unroll
  for (int c = 0; c < 32; ++c) { v[32 + c] = xim[(n * 32 + c) * 4096 + p]; s += v[32 + c]; }
  float m = s * (1.f / 64.f);
  float vs = 0.f;
#pragma unroll
  for (int c = 0; c < 64; ++c) { float d = v[c] - m; vs += d * d; }
  float rs = rsqrtf(vs * (1.f / 64.f) + 1e-5f);
#pragma unroll
  for (int c = 0; c < 64; ++c)
    ws[WS_XN + (n * 64 + c) * 4096 + p] = (v[c] - m) * rs * g[c] + b[c];
}

// ---------------- 3x3 conv 64->64, LDS-tiled + register-blocked ----------------
// grid: 48 n * 8 ocg * 2 ytile = 768 blocks, 256 threads.
// thread (tx=col, rg=rowgroup) computes 8 rows x 8 oc. Input staged in LDS
// (chunks of 4 ci, halo rows zeroed); weights via block-uniform scalar loads.
// writes x_upd = x + conv into d_out main slots.
__global__ void __launch_bounds__(256) k_conv(
    const float* __restrict__ ws, const float* __restrict__ wconv,
    const float* __restrict__ bconv,
    const float* __restrict__ xre, const float* __restrict__ xim,
    float* __restrict__ out) {
  __shared__ float in_lds[34][4][64];   // [local row][ci in chunk][col]
  int bid = blockIdx.x;
  int n = bid >> 4;
  int rem = bid & 15;
  int ocg = rem >> 1;         // 0..7 : oc = ocg*8 .. +7
  int yt = rem & 1;           // 0..1 : rows yt*32 .. +31
  int tid = threadIdx.x;
  int tx = tid & 63;          // col
  int rg = tid >> 6;          // 0..3 row group (8 rows each); also ci-lane for staging
  int y0 = yt * 32;
  int ybase = rg * 8;

  float acc[8][8];
#pragma unroll
  for (int r = 0; r < 8; ++r)
#pragma unroll
    for (int o = 0; o < 8; ++o) acc[r][o] = 0.f;

  const float* xn = ws + WS_XN + n * 64 * 4096;

  for (int cc = 0; cc < 16; ++cc) {
    int ci0 = cc * 4;
    // stage 34 halo rows x 4 ci x 64 cols; each wave stages one (row, ci) line
    __syncthreads();
#pragma unroll
    for (int r = 0; r < 34; ++r) {
      int gy = y0 - 1 + r;
      float v = 0.f;
      if ((unsigned)gy < 64u) v = xn[(ci0 + rg) * 4096 + gy * 64 + tx];
      in_lds[r][rg][tx] = v;
    }
    __syncthreads();

#pragma unroll
    for (int j = 0; j < 4; ++j) {
      // load this thread's 10x3 input window from LDS
      float win[10][3];
#pragma unroll
      for (int rl = 0; rl < 10; ++rl) {
        const float* row = &in_lds[ybase + rl][j][0];
        win[rl][0] = (tx > 0) ? row[tx - 1] : 0.f;
        win[rl][1] = row[tx];
        win[rl][2] = (tx < 63) ? row[tx + 1] : 0.f;
      }
      int ci = ci0 + j;
#pragma unroll
      for (int o = 0; o < 8; ++o) {
        const float* wp = wconv + ((ocg * 8 + o) * 64 + ci) * 9;  // block-uniform -> s_load
        float w0 = wp[0], w1 = wp[1], w2 = wp[2];
        float w3 = wp[3], w4 = wp[4], w5 = wp[5];
        float w6 = wp[6], w7 = wp[7], w8 = wp[8];
#pragma unroll
        for (int r = 0; r < 8; ++r) {
          float s = acc[r][o];
          s = fmaf(win[r][0], w0, s);
          s = fmaf(win[r][1], w1, s);
          s = fmaf(win[r][2], w2, s);
          s = fmaf(win[r + 1][0], w3, s);
          s = fmaf(win[r + 1][1], w4, s);
          s = fmaf(win[r + 1][2], w5, s);
          s = fmaf(win[r + 2][0], w6, s);
          s = fmaf(win[r + 2][1], w7, s);
          s = fmaf(win[r + 2][2], w8, s);
          acc[r][o] = s;
        }
      }
    }
  }

  // epilogue: add bias + residual, write to d_out
#pragma unroll
  for (int o = 0; o < 8; ++o) {
    int oc = ocg * 8 + o;
    float bias = bconv[oc];
    int d = (oc < 32) ? oc : oc - 32;
    long base = ((oc < 32) ? (long)MAIN_RE : (long)MAIN_IM) + (long)(n * 32 + d) * 4096;
    const float* resid = (oc < 32) ? xre : xim;
#pragma unroll
    for (int r = 0; r < 8; ++r) {
      int p = (y0 + ybase + r) * 64 + tx;
      int oi = (n * 32 + d) * 4096 + p;
      out[base + p] = resid[oi] + acc[r][o] + bias;
    }
  }
}

// ---------------- x_eig = x_upd @ Wb (complex, per pixel) -> channels-last ----------------
__global__ void k_xeig(const float* __restrict__ out,
                       const float* __restrict__ Wre, const float* __restrict__ Wim,
                       float* __restrict__ ws) {
  int gid = blockIdx.x * 256 + threadIdx.x;
  if (gid >= PIX * 32) return;
  int e = gid & 31;
  int g = gid >> 5;
  int n = g >> 12, p = g & 4095;
  float ar = 0.f, ai = 0.f;
#pragma unroll 8
  for (int d = 0; d < 32; ++d) {
    float xr = out[MAIN_RE + (n * 32 + d) * 4096 + p];
    float xi = out[MAIN_IM + (n * 32 + d) * 4096 + p];
    float wr = Wre[d * 32 + e], wi = Wim[d * 32 + e];
    ar += xr * wr - xi * wi;
    ai += xr * wi + xi * wr;
  }
  ws[WS_XE + g * 64 + e] = ar;
  ws[WS_XE + g * 64 + 32 + e] = ai;
}

// ---------------- spatial sums of x_eig per (n, channel) ----------------
__global__ void k_mean(float* __restrict__ ws) {
  __shared__ float red[256];
  int n = blockIdx.x;
  int tid = threadIdx.x;
  int c = tid & 63, pg = tid >> 6;
  float s = 0.f;
  for (int p = pg; p < 4096; p += 4)
    s += ws[WS_XE + (n * 4096 + p) * 64 + c];
  red[tid] = s;
  __syncthreads();
  if (tid < 64)
    ws[WS_SUMS + n * 64 + tid] = red[tid] + red[64 + tid] + red[128 + tid] + red[192 + tid];
  (void)c;
}

// ---------------- flux scan (T=24) + all per-(b,t,d) coefficients ----------------
__global__ void k_flux(float* __restrict__ ws, float* __restrict__ out,
                       const float* __restrict__ dt_seq,
                       const float* __restrict__ flux_re, const float* __restrict__ flux_im,
                       const float* __restrict__ lam_flux,
                       const float* __restrict__ bf_re, const float* __restrict__ bf_im,
                       const float* __restrict__ c_re, const float* __restrict__ c_im,
                       const float* __restrict__ g_w, const float* __restrict__ g_b,
                       const float* __restrict__ a_decay, const float* __restrict__ b_freq) {
  int tid = threadIdx.x;
  if (tid >= 64) return;
  int b = tid >> 5, e = tid & 31;
  float sp_lf = softplusf_(lam_flux[e]);
  float lr = -softplusf_(a_decay[e]);
  float li = b_freq[e];
  float den = lr * lr + li * li;
  float bfr = bf_re[e], bfi = bf_im[e];
  float cr = c_re[e], ci = c_im[e];
  float fr = flux_re[b * 32 + e], fi = flux_im[b * 32 + e];
  for (int t = 0; t < 24; ++t) {
    int n = b * 24 + t;
    float dt = dt_seq[n];
    float A = expf(-sp_lf * dt);
    float xmr = ws[WS_SUMS + n * 64 + e] * (1.f / 4096.f);
    float xmi = ws[WS_SUMS + n * 64 + 32 + e] * (1.f / 4096.f);
    float Xr = (bfr * xmr - bfi * xmi) * dt;
    float Xi = (bfr * xmi + bfi * xmr) * dt;
    fr = A * fr + Xr;
    fi = A * fi + Xi;
    ws[WS_GATE + n * 32 + e] = sigmoidf_(fr * g_w[e] + g_b[e]);
    ws[WS_SRCR + n * 32 + e] = fr * cr - fi * ci;
    ws[WS_SRCI + n * 32 + e] = fr * ci + fi * cr;
    float er = expf(lr * dt);
    float odr = er * cosf(li * dt);
    float odi = er * sinf(li * dt);
    ws[WS_ODR + n * 32 + e] = odr;
    ws[WS_ODI + n * 32 + e] = odi;
    float nr = odr - 1.f, ni = odi;
    ws[WS_OFR + n * 32 + e] = (nr * lr + ni * li) / den;
    ws[WS_OFI + n * 32 + e] = (ni * lr - nr * li) / den;
  }
  out[FLUX_RE + b * 32 + e] = fr;
  out[FLUX_IM + b * 32 + e] = fi;
}

// ---------------- spatial gate: 1x1 conv 64->32 + silu ----------------
__global__ void k_sg1(float* __restrict__ ws, const float* __restrict__ w1, const float* __restrict__ b1) {
  int gid = blockIdx.x * 256 + threadIdx.x;
  if (gid >= PIX * 32) return;
  int oc = gid & 31, g = gid >> 5;
  float acc = b1[oc];
#pragma unroll 8
  for (int c = 0; c < 64; ++c)
    acc = fmaf(ws[WS_XE + g * 64 + c], w1[oc * 64 + c], acc);
  ws[WS_G1 + g * 32 + oc] = acc * sigmoidf_(acc);
}

// ---------------- spatial gate: depthwise 3x3 ----------------
__global__ void k_sgdw(float* __restrict__ ws, const float* __restrict__ dw) {
  int gid = blockIdx.x * 256 + threadIdx.x;
  if (gid >= PIX * 32) return;
  int oc = gid & 31, g = gid >> 5;
  int n = g >> 12, p = g & 4095;
  int y = p >> 6, x = p & 63;
  float acc = 0.f;
#pragma unroll
  for (int ky = 0; ky < 3; ++ky) {
    int yy = y + ky - 1;
    if ((unsigned)yy < 64u) {
#pragma unroll
      for (int kx = 0; kx < 3; ++kx) {
        int xx = x + kx - 1;
        if ((unsigned)xx < 64u)
          acc = fmaf(ws[WS_G1 + (n * 4096 + yy * 64 + xx) * 32 + oc], dw[oc * 9 + ky * 3 + kx], acc);
      }
    }
  }
  ws[WS_G2 + g * 32 + oc] = acc;
}

// ---------------- spatial gate: 1x1 conv 32->32 + sigmoid (overwrites g1 buffer) ----------------
__global__ void k_sg3(float* __restrict__ ws, const float* __restrict__ w2, const float* __restrict__ b2) {
  int gid = blockIdx.x * 256 + threadIdx.x;
  if (gid >= PIX * 32) return;
  int oc = gid & 31, g = gid >> 5;
  float acc = b2[oc];
#pragma unroll 8
  for (int c = 0; c < 32; ++c)
    acc = fmaf(ws[WS_G2 + g * 32 + c], w2[oc * 32 + c], acc);
  ws[WS_G1 + g * 32 + oc] = sigmoidf_(acc);
}

// ---------------- forcing -> u_t (in place over x_eig buffer) ----------------
__global__ void k_force(float* __restrict__ ws,
                        const float* __restrict__ hre, const float* __restrict__ him) {
  int gid = blockIdx.x * 256 + threadIdx.x;
  if (gid >= PIX * 32) return;
  int e = gid & 31, g = gid >> 5;
  int n = g >> 12, p = g & 4095;
  int b = (n >= 24) ? 1 : 0;
  int t = n - b * 24;
  int ie = n * 32 + e;
  float gc = ws[WS_GATE + ie] * ws[WS_G1 + g * 32 + e];
  float xr = ws[WS_XE + g * 64 + e];
  float xi = ws[WS_XE + g * 64 + 32 + e];
  float om = 1.f - gc;
  float fr2 = xr * gc + ws[WS_SRCR + ie] * om;
  float fi2 = xi * gc + ws[WS_SRCI + ie] * om;
  float ofr = ws[WS_OFR + ie], ofi = ws[WS_OFI + ie];
  float ur = fr2 * ofr - fi2 * ofi;
  float ui = fr2 * ofi + fi2 * ofr;
  if (t == 0) {
    int hb = (b * 4096 + p) * 32 + e;
    float hr = hre[hb], hi = him[hb];
    float odr = ws[WS_ODR + (b * 24) * 32 + e], odi = ws[WS_ODI + (b * 24) * 32 + e];
    ur += hr * odr - hi * odi;
    ui += hr * odi + hi * odr;
  }
  ws[WS_XE + g * 64 + e] = ur;
  ws[WS_XE + g * 64 + 32 + e] = ui;
}

// ---------------- temporal scan over T=24 (in place), emit h_out ----------------
__global__ void k_scan(float* __restrict__ ws, float* __restrict__ out) {
  int gid = blockIdx.x * 256 + threadIdx.x;
  if (gid >= BB * HWp * 32) return;
  int e = gid & 31;
  int p = (gid >> 5) & 4095;
  int b = gid >> 17;
  float ur = 0.f, ui = 0.f;
  for (int t = 0; t < 24; ++t) {
    int n = b * 24 + t;
    int idx = WS_XE + (n * 4096 + p) * 64 + e;
    float ar = ws[WS_ODR + n * 32 + e], ai = ws[WS_ODI + n * 32 + e];
    float xr = ws[idx], xi = ws[idx + 32];
    float nr = ar * ur - ai * ui + xr;
    float ni = ar * ui + ai * ur + xi;
    ur = nr; ui = ni;
    ws[idx] = ur;
    ws[idx + 32] = ui;
  }
  int hb = (b * 4096 + p) * 32 + e;
  out[HOUT_RE + hb] = ur;
  out[HOUT_IM + hb] = ui;
}

// ---------------- dec = u_out @ Wb_inv (complex, per pixel) -> channels-last in WS_XN ----------------
__global__ void k_dec(float* __restrict__ ws) {
  int gid = blockIdx.x * 256 + threadIdx.x;
  if (gid >= PIX * 32) return;
  int d = gid & 31, g = gid >> 5;
  float ar = 0.f, ai = 0.f;
#pragma unroll 8
  for (int e = 0; e < 32; ++e) {
    float ur = ws[WS_XE + g * 64 + e], ui = ws[WS_XE + g * 64 + 32 + e];
    float wr = ws[WS_WINV + e * 32 + d], wi = ws[WS_WINV + 1024 + e * 32 + d];
    ar += ur * wr - ui * wi;
    ai += ur * wi + ui * wr;
  }
  ws[WS_XN + g * 64 + d] = ar;
  ws[WS_XN + g * 64 + 32 + d] = ai;
}

// ---------------- LN_t + FFN (64->128->64) + z = x_upd + dec + delta (in place on d_out) ----------------
__global__ void k_final(float* __restrict__ ws, float* __restrict__ out,
                        const float* __restrict__ lg, const float* __restrict__ lb,
                        const float* __restrict__ w1, const float* __restrict__ b1,
                        const float* __restrict__ w2, const float* __restrict__ b2) {
  int gid = blockIdx.x * 256 + threadIdx.x;
  if (gid >= PIX) return;
  int n = gid >> 12, p = gid & 4095;
  float dn[64];
  float s = 0.f;
#pragma unroll
  for (int c = 0; c < 64; ++c) { dn[c] = ws[WS_XN + gid * 64 + c]; s += dn[c]; }
  float m = s * (1.f / 64.f);
  float vs = 0.f;
#pragma unroll
  for (int c = 0; c < 64; ++c) { float d = dn[c] - m; vs += d * d; }
  float rs = rsqrtf(vs * (1.f / 64.f) + 1e-5f);
#pragma unroll
  for (int c = 0; c < 64; ++c) dn[c] = (dn[c] - m) * rs * lg[c] + lb[c];
  float o2[64];
#pragma unroll
  for (int c = 0; c < 64; ++c) o2[c] = b2[c];
  for (int k = 0; k < 128; ++k) {
    float sacc = b1[k];
#pragma unroll
    for (int c = 0; c < 64; ++c) sacc = fmaf(dn[c], w1[c * 128 + k], sacc);
    float h = sacc * sigmoidf_(sacc);
#pragma unroll
    for (int c = 0; c < 64; ++c) o2[c] = fmaf(h, w2[k * 64 + c], o2[c]);
  }
#pragma unroll
  for (int d = 0; d < 32; ++d) {
    int oi = (n * 32 + d) * 4096 + p;
    out[MAIN_RE + oi] += ws[WS_XN + gid * 64 + d] + o2[d];
    out[MAIN_IM + oi] += ws[WS_XN + gid * 64 + 32 + d] + o2[32 + d];
  }
}

extern "C" void kernel_launch(void* const* d_in, const int* in_sizes, int n_in,
                              void* d_out, int out_size, void* d_ws, size_t ws_size,
                              hipStream_t stream) {
  (void)in_sizes; (void)n_in; (void)out_size; (void)ws_size;
  const float* xre      = (const float*)d_in[0];
  const float* xim      = (const float*)d_in[1];
  const float* hre      = (const float*)d_in[2];
  const float* him      = (const float*)d_in[3];
  const float* flux_re  = (const float*)d_in[4];
  const float* flux_im  = (const float*)d_in[5];
  const float* dt_seq   = (const float*)d_in[6];
  const float* ln_s_g   = (const float*)d_in[7];
  const float* ln_s_b   = (const float*)d_in[8];
  const float* conv_w   = (const float*)d_in[9];
  const float* conv_b   = (const float*)d_in[10];
  const float* ln_t_g   = (const float*)d_in[11];
  const float* ln_t_b   = (const float*)d_in[12];
  const float* W_re     = (const float*)d_in[13];
  const float* W_im     = (const float*)d_in[14];
  const float* lam_flux = (const float*)d_in[15];
  const float* bf_re    = (const float*)d_in[16];
  const float* bf_im    = (const float*)d_in[17];
  const float* c_re     = (const float*)d_in[18];
  const float* c_im     = (const float*)d_in[19];
  const float* g_w      = (const float*)d_in[20];
  const float* g_b      = (const float*)d_in[21];
  const float* a_decay  = (const float*)d_in[22];
  const float* b_freq   = (const float*)d_in[23];
  const float* ffn_w1   = (const float*)d_in[24];
  const float* ffn_b1   = (const float*)d_in[25];
  const float* ffn_w2   = (const float*)d_in[26];
  const float* ffn_b2   = (const float*)d_in[27];
  const float* sg_w1    = (const float*)d_in[28];
  const float* sg_b1    = (const float*)d_in[29];
  const float* sg_dw    = (const float*)d_in[30];
  const float* sg_w2    = (const float*)d_in[31];
  const float* sg_b2    = (const float*)d_in[32];
  float* out = (float*)d_out;
  float* ws  = (float*)d_ws;

  k_invert<<<1, 256, 0, stream>>>(W_re, W_im, ws);
  k_ln_s<<<PIX / 256, 256, 0, stream>>>(xre, xim, ln_s_g, ln_s_b, ws);
  k_conv<<<768, 256, 0, stream>>>(ws, conv_w, conv_b, xre, xim, out);
  k_xeig<<<(PIX * 32) / 256, 256, 0, stream>>>(out, W_re, W_im, ws);
  k_mean<<<NN, 256, 0, stream>>>(ws);
  k_flux<<<1, 64, 0, stream>>>(ws, out, dt_seq, flux_re, flux_im, lam_flux,
                               bf_re, bf_im, c_re, c_im, g_w, g_b, a_decay, b_freq);
  k_sg1<<<(PIX * 32) / 256, 256, 0, stream>>>(ws, sg_w1, sg_b1);
  k_sgdw<<<(PIX * 32) / 256, 256, 0, stream>>>(ws, sg_dw);
  k_sg3<<<(PIX * 32) / 256, 256, 0, stream>>>(ws, sg_w2, sg_b2);
  k_force<<<(PIX * 32) / 256, 256, 0, stream>>>(ws, hre, him);
  k_scan<<<(BB * HWp * 32) / 256, 256, 0, stream>>>(ws, out);
  k_dec<<<(PIX * 32) / 256, 256, 0, stream>>>(ws);
  k_final<<<PIX / 256, 256, 0, stream>>>(ws, out, ln_t_g, ln_t_b,
                                         ffn_w1, ffn_b1, ffn_w2, ffn_b2);
}

// Round 3
// 1543.484 us; speedup vs baseline: 1.9030x; 1.2463x over previous
//
#include <hip/hip_runtime.h>
#include <math.h>

#define BB 2
#define TT 24
#define DD 32
#define HWp 4096            // 64*64
#define NN (BB*TT)          // 48
#define PIX (NN*HWp)        // 196608
#define C2 (2*DD)           // 64

// d_out offsets (floats)
#define MAIN_RE 0
#define MAIN_IM (NN*DD*HWp)              // 6291456
#define HOUT_RE (2*NN*DD*HWp)            // 12582912
#define HOUT_IM (HOUT_RE + BB*HWp*DD)    // 12845056
#define FLUX_RE (HOUT_RE + 2*BB*HWp*DD)  // 13107200
#define FLUX_IM (FLUX_RE + BB*DD)        // 13107264

// ws offsets (floats)
#define WS_XN   0                        // PIX*64   xn (LN output), later: dec (channels-last)
#define WS_XE   (WS_XN + PIX*C2)         // PIX*64   x_eig -> u_t -> u_out (channels-last)
#define WS_G1   (WS_XE + PIX*C2)         // PIX*32   g1 -> sp_gate
#define WS_G2   (WS_G1 + PIX*DD)         // PIX*32   g2
#define WS_WINV (WS_G2 + PIX*DD)         // 2048 (re 1024, im 1024)
#define WS_SUMS (WS_WINV + 2048)         // 3072  per-(n) channel sums
#define WS_GATE (WS_SUMS + 3072)         // 1536
#define WS_SRCR (WS_GATE + 1536)
#define WS_SRCI (WS_SRCR + 1536)
#define WS_ODR  (WS_SRCI + 1536)
#define WS_ODI  (WS_ODR + 1536)
#define WS_OFR  (WS_ODI + 1536)
#define WS_OFI  (WS_OFR + 1536)

__device__ __forceinline__ float sigmoidf_(float x) { return 1.f / (1.f + expf(-x)); }
__device__ __forceinline__ float softplusf_(float x) { return log1pf(expf(x)); }

// ---------------- Gauss-Jordan inverse of Wb (32x32 complex), partial pivoting ----------------
__global__ void k_invert(const float* __restrict__ Wre, const float* __restrict__ Wim,
                         float* __restrict__ ws) {
  __shared__ float Mre[32][64];
  __shared__ float Mim[32][64];
  __shared__ float fre[32], fim[32];
  __shared__ float pr_s, pi_s;
  __shared__ int piv_s;
  int tid = threadIdx.x;  // 256 threads
  for (int idx = tid; idx < 2048; idx += 256) {
    int i = idx >> 6, j = idx & 63;
    if (j < 32) { Mre[i][j] = Wre[i * 32 + j]; Mim[i][j] = Wim[i * 32 + j]; }
    else        { Mre[i][j] = (j - 32 == i) ? 1.f : 0.f; Mim[i][j] = 0.f; }
  }
  __syncthreads();
  for (int k = 0; k < 32; ++k) {
    if (tid == 0) {
      int best = k; float bm = fabsf(Mre[k][k]) + fabsf(Mim[k][k]);
      for (int r = k + 1; r < 32; ++r) {
        float m = fabsf(Mre[r][k]) + fabsf(Mim[r][k]);
        if (m > bm) { bm = m; best = r; }
      }
      piv_s = best;
    }
    __syncthreads();
    int pv = piv_s;
    if (pv != k && tid < 64) {
      float tr = Mre[k][tid], ti = Mim[k][tid];
      Mre[k][tid] = Mre[pv][tid]; Mim[k][tid] = Mim[pv][tid];
      Mre[pv][tid] = tr; Mim[pv][tid] = ti;
    }
    __syncthreads();
    if (tid == 0) {
      float a = Mre[k][k], b = Mim[k][k];
      float d = a * a + b * b;
      pr_s = a / d; pi_s = -b / d;
    }
    __syncthreads();
    float pr = pr_s, pi = pi_s;
    if (tid < 64) {
      float a = Mre[k][tid], b = Mim[k][tid];
      Mre[k][tid] = a * pr - b * pi;
      Mim[k][tid] = a * pi + b * pr;
    }
    __syncthreads();
    if (tid < 32) { fre[tid] = Mre[tid][k]; fim[tid] = Mim[tid][k]; }
    __syncthreads();
    for (int idx = tid; idx < 2048; idx += 256) {
      int i = idx >> 6, j = idx & 63;
      if (i != k) {
        float fr = fre[i], fi = fim[i];
        float ar = Mre[k][j], ai = Mim[k][j];
        Mre[i][j] -= fr * ar - fi * ai;
        Mim[i][j] -= fr * ai + fi * ar;
      }
    }
    __syncthreads();
  }
  for (int idx = tid; idx < 1024; idx += 256) {
    int e = idx >> 5, d = idx & 31;
    ws[WS_WINV + e * 32 + d] = Mre[e][32 + d];
    ws[WS_WINV + 1024 + e * 32 + d] = Mim[e][32 + d];
  }
}

// ---------------- spatial LayerNorm over 64 (re,im) channels -> xn (NCHW) ----------------
__global__ void k_ln_s(const float* __restrict__ xre, const float* __restrict__ xim,
                       const float* __restrict__ g, const float* __restrict__ b,
                       float* __restrict__ ws) {
  int gid = blockIdx.x * 256 + threadIdx.x;
  if (gid >= PIX) return;
  int n = gid >> 12, p = gid & 4095;
  float v[64];
  float s = 0.f;
#pragma unroll
  for (int c = 0; c < 32; ++c) { v[c] = xre[(n * 32 + c) * 4096 + p]; s += v[c]; }
#pragma unroll
  for (int c = 0; c < 32; ++c) { v[32 + c] = xim[(n * 32 + c) * 4096 + p]; s += v[32 + c]; }
  float m = s * (1.f / 64.f);
  float vs = 0.f;
#pragma unroll
  for (int c = 0; c < 64; ++c) { float d = v[c] - m; vs += d * d; }
  float rs = rsqrtf(vs * (1.f / 64.f) + 1e-5f);
#pragma unroll
  for (int c = 0; c < 64; ++c)
    ws[WS_XN + (n * 64 + c) * 4096 + p] = (v[c] - m) * rs * g[c] + b[c];
}

// ---------------- 3x3 conv 64->64, LDS-tiled + register-blocked ----------------
__global__ void __launch_bounds__(256) k_conv(
    const float* __restrict__ ws, const float* __restrict__ wconv,
    const float* __restrict__ bconv,
    const float* __restrict__ xre, const float* __restrict__ xim,
    float* __restrict__ out) {
  __shared__ float in_lds[34][4][64];   // [local row][ci in chunk][col]
  int bid = blockIdx.x;
  int n = bid >> 4;
  int rem = bid & 15;
  int ocg = rem >> 1;         // 0..7 : oc = ocg*8 .. +7
  int yt = rem & 1;           // 0..1 : rows yt*32 .. +31
  int tid = threadIdx.x;
  int tx = tid & 63;          // col
  int rg = tid >> 6;          // 0..3 row group (8 rows each); also ci-lane for staging
  int y0 = yt * 32;
  int ybase = rg * 8;

  float acc[8][8];
#pragma unroll
  for (int r = 0; r < 8; ++r)
#pragma unroll
    for (int o = 0; o < 8; ++o) acc[r][o] = 0.f;

  const float* xn = ws + WS_XN + n * 64 * 4096;

  for (int cc = 0; cc < 16; ++cc) {
    int ci0 = cc * 4;
    __syncthreads();
#pragma unroll
    for (int r = 0; r < 34; ++r) {
      int gy = y0 - 1 + r;
      float v = 0.f;
      if ((unsigned)gy < 64u) v = xn[(ci0 + rg) * 4096 + gy * 64 + tx];
      in_lds[r][rg][tx] = v;
    }
    __syncthreads();

#pragma unroll
    for (int j = 0; j < 4; ++j) {
      float win[10][3];
#pragma unroll
      for (int rl = 0; rl < 10; ++rl) {
        const float* row = &in_lds[ybase + rl][j][0];
        win[rl][0] = (tx > 0) ? row[tx - 1] : 0.f;
        win[rl][1] = row[tx];
        win[rl][2] = (tx < 63) ? row[tx + 1] : 0.f;
      }
      int ci = ci0 + j;
#pragma unroll
      for (int o = 0; o < 8; ++o) {
        const float* wp = wconv + ((ocg * 8 + o) * 64 + ci) * 9;  // block-uniform -> s_load
        float w0 = wp[0], w1 = wp[1], w2 = wp[2];
        float w3 = wp[3], w4 = wp[4], w5 = wp[5];
        float w6 = wp[6], w7 = wp[7], w8 = wp[8];
#pragma unroll
        for (int r = 0; r < 8; ++r) {
          float s = acc[r][o];
          s = fmaf(win[r][0], w0, s);
          s = fmaf(win[r][1], w1, s);
          s = fmaf(win[r][2], w2, s);
          s = fmaf(win[r + 1][0], w3, s);
          s = fmaf(win[r + 1][1], w4, s);
          s = fmaf(win[r + 1][2], w5, s);
          s = fmaf(win[r + 2][0], w6, s);
          s = fmaf(win[r + 2][1], w7, s);
          s = fmaf(win[r + 2][2], w8, s);
          acc[r][o] = s;
        }
      }
    }
  }

#pragma unroll
  for (int o = 0; o < 8; ++o) {
    int oc = ocg * 8 + o;
    float bias = bconv[oc];
    int d = (oc < 32) ? oc : oc - 32;
    long base = ((oc < 32) ? (long)MAIN_RE : (long)MAIN_IM) + (long)(n * 32 + d) * 4096;
    const float* resid = (oc < 32) ? xre : xim;
#pragma unroll
    for (int r = 0; r < 8; ++r) {
      int p = (y0 + ybase + r) * 64 + tx;
      int oi = (n * 32 + d) * 4096 + p;
      out[base + p] = resid[oi] + acc[r][o] + bias;
    }
  }
}

// ---------------- x_eig = x_upd @ Wb (complex, per pixel) -> channels-last ----------------
__global__ void k_xeig(const float* __restrict__ out,
                       const float* __restrict__ Wre, const float* __restrict__ Wim,
                       float* __restrict__ ws) {
  int gid = blockIdx.x * 256 + threadIdx.x;
  if (gid >= PIX * 32) return;
  int e = gid & 31;
  int g = gid >> 5;
  int n = g >> 12, p = g & 4095;
  float ar = 0.f, ai = 0.f;
#pragma unroll 8
  for (int d = 0; d < 32; ++d) {
    float xr = out[MAIN_RE + (n * 32 + d) * 4096 + p];
    float xi = out[MAIN_IM + (n * 32 + d) * 4096 + p];
    float wr = Wre[d * 32 + e], wi = Wim[d * 32 + e];
    ar += xr * wr - xi * wi;
    ai += xr * wi + xi * wr;
  }
  ws[WS_XE + g * 64 + e] = ar;
  ws[WS_XE + g * 64 + 32 + e] = ai;
}

// ---------------- spatial sums of x_eig per (n, channel) ----------------
__global__ void k_mean(float* __restrict__ ws) {
  __shared__ float red[256];
  int n = blockIdx.x;
  int tid = threadIdx.x;
  int c = tid & 63, pg = tid >> 6;
  float s = 0.f;
  for (int p = pg; p < 4096; p += 4)
    s += ws[WS_XE + (n * 4096 + p) * 64 + c];
  red[tid] = s;
  __syncthreads();
  if (tid < 64)
    ws[WS_SUMS + n * 64 + tid] = red[tid] + red[64 + tid] + red[128 + tid] + red[192 + tid];
  (void)c;
}

// ---------------- flux scan (T=24) + all per-(b,t,d) coefficients ----------------
__global__ void k_flux(float* __restrict__ ws, float* __restrict__ out,
                       const float* __restrict__ dt_seq,
                       const float* __restrict__ flux_re, const float* __restrict__ flux_im,
                       const float* __restrict__ lam_flux,
                       const float* __restrict__ bf_re, const float* __restrict__ bf_im,
                       const float* __restrict__ c_re, const float* __restrict__ c_im,
                       const float* __restrict__ g_w, const float* __restrict__ g_b,
                       const float* __restrict__ a_decay, const float* __restrict__ b_freq) {
  int tid = threadIdx.x;
  if (tid >= 64) return;
  int b = tid >> 5, e = tid & 31;
  float sp_lf = softplusf_(lam_flux[e]);
  float lr = -softplusf_(a_decay[e]);
  float li = b_freq[e];
  float den = lr * lr + li * li;
  float bfr = bf_re[e], bfi = bf_im[e];
  float cr = c_re[e], ci = c_im[e];
  float fr = flux_re[b * 32 + e], fi = flux_im[b * 32 + e];
  for (int t = 0; t < 24; ++t) {
    int n = b * 24 + t;
    float dt = dt_seq[n];
    float A = expf(-sp_lf * dt);
    float xmr = ws[WS_SUMS + n * 64 + e] * (1.f / 4096.f);
    float xmi = ws[WS_SUMS + n * 64 + 32 + e] * (1.f / 4096.f);
    float Xr = (bfr * xmr - bfi * xmi) * dt;
    float Xi = (bfr * xmi + bfi * xmr) * dt;
    fr = A * fr + Xr;
    fi = A * fi + Xi;
    ws[WS_GATE + n * 32 + e] = sigmoidf_(fr * g_w[e] + g_b[e]);
    ws[WS_SRCR + n * 32 + e] = fr * cr - fi * ci;
    ws[WS_SRCI + n * 32 + e] = fr * ci + fi * cr;
    float er = expf(lr * dt);
    float odr = er * cosf(li * dt);
    float odi = er * sinf(li * dt);
    ws[WS_ODR + n * 32 + e] = odr;
    ws[WS_ODI + n * 32 + e] = odi;
    float nr = odr - 1.f, ni = odi;
    ws[WS_OFR + n * 32 + e] = (nr * lr + ni * li) / den;
    ws[WS_OFI + n * 32 + e] = (ni * lr - nr * li) / den;
  }
  out[FLUX_RE + b * 32 + e] = fr;
  out[FLUX_IM + b * 32 + e] = fi;
}

// ---------------- spatial gate: 1x1 conv 64->32 + silu ----------------
__global__ void k_sg1(float* __restrict__ ws, const float* __restrict__ w1, const float* __restrict__ b1) {
  int gid = blockIdx.x * 256 + threadIdx.x;
  if (gid >= PIX * 32) return;
  int oc = gid & 31, g = gid >> 5;
  float acc = b1[oc];
#pragma unroll 8
  for (int c = 0; c < 64; ++c)
    acc = fmaf(ws[WS_XE + g * 64 + c], w1[oc * 64 + c], acc);
  ws[WS_G1 + g * 32 + oc] = acc * sigmoidf_(acc);
}

// ---------------- spatial gate: depthwise 3x3 ----------------
__global__ void k_sgdw(float* __restrict__ ws, const float* __restrict__ dw) {
  int gid = blockIdx.x * 256 + threadIdx.x;
  if (gid >= PIX * 32) return;
  int oc = gid & 31, g = gid >> 5;
  int n = g >> 12, p = g & 4095;
  int y = p >> 6, x = p & 63;
  float acc = 0.f;
#pragma unroll
  for (int ky = 0; ky < 3; ++ky) {
    int yy = y + ky - 1;
    if ((unsigned)yy < 64u) {
#pragma unroll
      for (int kx = 0; kx < 3; ++kx) {
        int xx = x + kx - 1;
        if ((unsigned)xx < 64u)
          acc = fmaf(ws[WS_G1 + (n * 4096 + yy * 64 + xx) * 32 + oc], dw[oc * 9 + ky * 3 + kx], acc);
      }
    }
  }
  ws[WS_G2 + g * 32 + oc] = acc;
}

// ---------------- spatial gate: 1x1 conv 32->32 + sigmoid (overwrites g1 buffer) ----------------
__global__ void k_sg3(float* __restrict__ ws, const float* __restrict__ w2, const float* __restrict__ b2) {
  int gid = blockIdx.x * 256 + threadIdx.x;
  if (gid >= PIX * 32) return;
  int oc = gid & 31, g = gid >> 5;
  float acc = b2[oc];
#pragma unroll 8
  for (int c = 0; c < 32; ++c)
    acc = fmaf(ws[WS_G2 + g * 32 + c], w2[oc * 32 + c], acc);
  ws[WS_G1 + g * 32 + oc] = sigmoidf_(acc);
}

// ---------------- forcing -> u_t (in place over x_eig buffer) ----------------
__global__ void k_force(float* __restrict__ ws,
                        const float* __restrict__ hre, const float* __restrict__ him) {
  int gid = blockIdx.x * 256 + threadIdx.x;
  if (gid >= PIX * 32) return;
  int e = gid & 31, g = gid >> 5;
  int n = g >> 12, p = g & 4095;
  int b = (n >= 24) ? 1 : 0;
  int t = n - b * 24;
  int ie = n * 32 + e;
  float gc = ws[WS_GATE + ie] * ws[WS_G1 + g * 32 + e];
  float xr = ws[WS_XE + g * 64 + e];
  float xi = ws[WS_XE + g * 64 + 32 + e];
  float om = 1.f - gc;
  float fr2 = xr * gc + ws[WS_SRCR + ie] * om;
  float fi2 = xi * gc + ws[WS_SRCI + ie] * om;
  float ofr = ws[WS_OFR + ie], ofi = ws[WS_OFI + ie];
  float ur = fr2 * ofr - fi2 * ofi;
  float ui = fr2 * ofi + fi2 * ofr;
  if (t == 0) {
    int hb = (b * 4096 + p) * 32 + e;
    float hr = hre[hb], hi = him[hb];
    float odr = ws[WS_ODR + (b * 24) * 32 + e], odi = ws[WS_ODI + (b * 24) * 32 + e];
    ur += hr * odr - hi * odi;
    ui += hr * odi + hi * odr;
  }
  ws[WS_XE + g * 64 + e] = ur;
  ws[WS_XE + g * 64 + 32 + e] = ui;
}

// ---------------- temporal scan over T=24 (in place), emit h_out ----------------
__global__ void k_scan(float* __restrict__ ws, float* __restrict__ out) {
  int gid = blockIdx.x * 256 + threadIdx.x;
  if (gid >= BB * HWp * 32) return;
  int e = gid & 31;
  int p = (gid >> 5) & 4095;
  int b = gid >> 17;
  float ur = 0.f, ui = 0.f;
  for (int t = 0; t < 24; ++t) {
    int n = b * 24 + t;
    int idx = WS_XE + (n * 4096 + p) * 64 + e;
    float ar = ws[WS_ODR + n * 32 + e], ai = ws[WS_ODI + n * 32 + e];
    float xr = ws[idx], xi = ws[idx + 32];
    float nr = ar * ur - ai * ui + xr;
    float ni = ar * ui + ai * ur + xi;
    ur = nr; ui = ni;
    ws[idx] = ur;
    ws[idx + 32] = ui;
  }
  int hb = (b * 4096 + p) * 32 + e;
  out[HOUT_RE + hb] = ur;
  out[HOUT_IM + hb] = ui;
}

// ---------------- dec = u_out @ Wb_inv (complex, per pixel) -> channels-last in WS_XN ----------------
__global__ void k_dec(float* __restrict__ ws) {
  int gid = blockIdx.x * 256 + threadIdx.x;
  if (gid >= PIX * 32) return;
  int d = gid & 31, g = gid >> 5;
  float ar = 0.f, ai = 0.f;
#pragma unroll 8
  for (int e = 0; e < 32; ++e) {
    float ur = ws[WS_XE + g * 64 + e], ui = ws[WS_XE + g * 64 + 32 + e];
    float wr = ws[WS_WINV + e * 32 + d], wi = ws[WS_WINV + 1024 + e * 32 + d];
    ar += ur * wr - ui * wi;
    ai += ur * wi + ui * wr;
  }
  ws[WS_XN + g * 64 + d] = ar;
  ws[WS_XN + g * 64 + 32 + d] = ai;
}

// ---------------- LN_t + FFN (64->128->64) + z = x_upd + dec + delta ----------------
// k blocked by 16: hid[16] independent accumulators (no serial reduction chain),
// w1/w2 rows loaded as contiguous float4 at block-uniform addresses (-> s_load).
__global__ void __launch_bounds__(256) k_final(
    float* __restrict__ ws, float* __restrict__ out,
    const float* __restrict__ lg, const float* __restrict__ lb,
    const float* __restrict__ w1, const float* __restrict__ b1,
    const float* __restrict__ w2, const float* __restrict__ b2) {
  int gid = blockIdx.x * 256 + threadIdx.x;
  if (gid >= PIX) return;
  int n = gid >> 12, p = gid & 4095;
  float dn[64];
  float s = 0.f;
#pragma unroll
  for (int c = 0; c < 64; ++c) { dn[c] = ws[WS_XN + gid * 64 + c]; s += dn[c]; }
  float m = s * (1.f / 64.f);
  float vs = 0.f;
#pragma unroll
  for (int c = 0; c < 64; ++c) { float d = dn[c] - m; vs += d * d; }
  float rs = rsqrtf(vs * (1.f / 64.f) + 1e-5f);
#pragma unroll
  for (int c = 0; c < 64; ++c) dn[c] = (dn[c] - m) * rs * lg[c] + lb[c];

  float o2[64];
#pragma unroll
  for (int c = 0; c < 64; ++c) o2[c] = b2[c];

  for (int kc = 0; kc < 8; ++kc) {           // 8 chunks of 16 k
    float hid[16];
    {
      const float4* bp = (const float4*)(b1 + kc * 16);
      float4 h0 = bp[0], h1 = bp[1], h2 = bp[2], h3 = bp[3];
      hid[0] = h0.x; hid[1] = h0.y; hid[2] = h0.z; hid[3] = h0.w;
      hid[4] = h1.x; hid[5] = h1.y; hid[6] = h1.z; hid[7] = h1.w;
      hid[8] = h2.x; hid[9] = h2.y; hid[10] = h2.z; hid[11] = h2.w;
      hid[12] = h3.x; hid[13] = h3.y; hid[14] = h3.z; hid[15] = h3.w;
    }
#pragma unroll
    for (int c = 0; c < 64; ++c) {
      const float4* wp = (const float4*)(w1 + c * 128 + kc * 16);
      float4 a0 = wp[0], a1 = wp[1], a2 = wp[2], a3 = wp[3];
      float d = dn[c];
      hid[0]  = fmaf(d, a0.x, hid[0]);  hid[1]  = fmaf(d, a0.y, hid[1]);
      hid[2]  = fmaf(d, a0.z, hid[2]);  hid[3]  = fmaf(d, a0.w, hid[3]);
      hid[4]  = fmaf(d, a1.x, hid[4]);  hid[5]  = fmaf(d, a1.y, hid[5]);
      hid[6]  = fmaf(d, a1.z, hid[6]);  hid[7]  = fmaf(d, a1.w, hid[7]);
      hid[8]  = fmaf(d, a2.x, hid[8]);  hid[9]  = fmaf(d, a2.y, hid[9]);
      hid[10] = fmaf(d, a2.z, hid[10]); hid[11] = fmaf(d, a2.w, hid[11]);
      hid[12] = fmaf(d, a3.x, hid[12]); hid[13] = fmaf(d, a3.y, hid[13]);
      hid[14] = fmaf(d, a3.z, hid[14]); hid[15] = fmaf(d, a3.w, hid[15]);
    }
#pragma unroll
    for (int j = 0; j < 16; ++j) hid[j] = hid[j] * sigmoidf_(hid[j]);
#pragma unroll
    for (int j = 0; j < 16; ++j) {
      const float4* wq = (const float4*)(w2 + (kc * 16 + j) * 64);
      float h = hid[j];
#pragma unroll
      for (int c4 = 0; c4 < 16; ++c4) {
        float4 w = wq[c4];
        o2[4 * c4 + 0] = fmaf(h, w.x, o2[4 * c4 + 0]);
        o2[4 * c4 + 1] = fmaf(h, w.y, o2[4 * c4 + 1]);
        o2[4 * c4 + 2] = fmaf(h, w.z, o2[4 * c4 + 2]);
        o2[4 * c4 + 3] = fmaf(h, w.w, o2[4 * c4 + 3]);
      }
    }
  }

#pragma unroll
  for (int d = 0; d < 32; ++d) {
    int oi = (n * 32 + d) * 4096 + p;
    out[MAIN_RE + oi] += ws[WS_XN + gid * 64 + d] + o2[d];
    out[MAIN_IM + oi] += ws[WS_XN + gid * 64 + 32 + d] + o2[32 + d];
  }
}

extern "C" void kernel_launch(void* const* d_in, const int* in_sizes, int n_in,
                              void* d_out, int out_size, void* d_ws, size_t ws_size,
                              hipStream_t stream) {
  (void)in_sizes; (void)n_in; (void)out_size; (void)ws_size;
  const float* xre      = (const float*)d_in[0];
  const float* xim      = (const float*)d_in[1];
  const float* hre      = (const float*)d_in[2];
  const float* him      = (const float*)d_in[3];
  const float* flux_re  = (const float*)d_in[4];
  const float* flux_im  = (const float*)d_in[5];
  const float* dt_seq   = (const float*)d_in[6];
  const float* ln_s_g   = (const float*)d_in[7];
  const float* ln_s_b   = (const float*)d_in[8];
  const float* conv_w   = (const float*)d_in[9];
  const float* conv_b   = (const float*)d_in[10];
  const float* ln_t_g   = (const float*)d_in[11];
  const float* ln_t_b   = (const float*)d_in[12];
  const float* W_re     = (const float*)d_in[13];
  const float* W_im     = (const float*)d_in[14];
  const float* lam_flux = (const float*)d_in[15];
  const float* bf_re    = (const float*)d_in[16];
  const float* bf_im    = (const float*)d_in[17];
  const float* c_re     = (const float*)d_in[18];
  const float* c_im     = (const float*)d_in[19];
  const float* g_w      = (const float*)d_in[20];
  const float* g_b      = (const float*)d_in[21];
  const float* a_decay  = (const float*)d_in[22];
  const float* b_freq   = (const float*)d_in[23];
  const float* ffn_w1   = (const float*)d_in[24];
  const float* ffn_b1   = (const float*)d_in[25];
  const float* ffn_w2   = (const float*)d_in[26];
  const float* ffn_b2   = (const float*)d_in[27];
  const float* sg_w1    = (const float*)d_in[28];
  const float* sg_b1    = (const float*)d_in[29];
  const float* sg_dw    = (const float*)d_in[30];
  const float* sg_w2    = (const float*)d_in[31];
  const float* sg_b2    = (const float*)d_in[32];
  float* out = (float*)d_out;
  float* ws  = (float*)d_ws;

  k_invert<<<1, 256, 0, stream>>>(W_re, W_im, ws);
  k_ln_s<<<PIX / 256, 256, 0, stream>>>(xre, xim, ln_s_g, ln_s_b, ws);
  k_conv<<<768, 256, 0, stream>>>(ws, conv_w, conv_b, xre, xim, out);
  k_xeig<<<(PIX * 32) / 256, 256, 0, stream>>>(out, W_re, W_im, ws);
  k_mean<<<NN, 256, 0, stream>>>(ws);
  k_flux<<<1, 64, 0, stream>>>(ws, out, dt_seq, flux_re, flux_im, lam_flux,
                               bf_re, bf_im, c_re, c_im, g_w, g_b, a_decay, b_freq);
  k_sg1<<<(PIX * 32) / 256, 256, 0, stream>>>(ws, sg_w1, sg_b1);
  k_sgdw<<<(PIX * 32) / 256, 256, 0, stream>>>(ws, sg_dw);
  k_sg3<<<(PIX * 32) / 256, 256, 0, stream>>>(ws, sg_w2, sg_b2);
  k_force<<<(PIX * 32) / 256, 256, 0, stream>>>(ws, hre, him);
  k_scan<<<(BB * HWp * 32) / 256, 256, 0, stream>>>(ws, out);
  k_dec<<<(PIX * 32) / 256, 256, 0, stream>>>(ws);
  k_final<<<PIX / 256, 256, 0, stream>>>(ws, out, ln_t_g, ln_t_b,
                                         ffn_w1, ffn_b1, ffn_w2, ffn_b2);
}

// Round 4
// 1013.714 us; speedup vs baseline: 2.8976x; 1.5226x over previous
//
#include <hip/hip_runtime.h>
#include <math.h>

#define BB 2
#define TT 24
#define DD 32
#define HWp 4096            // 64*64
#define NN (BB*TT)          // 48
#define PIX (NN*HWp)        // 196608
#define C2 (2*DD)           // 64

// d_out offsets (floats)
#define MAIN_RE 0
#define MAIN_IM (NN*DD*HWp)              // 6291456
#define HOUT_RE (2*NN*DD*HWp)            // 12582912
#define HOUT_IM (HOUT_RE + BB*HWp*DD)    // 12845056
#define FLUX_RE (HOUT_RE + 2*BB*HWp*DD)  // 13107200
#define FLUX_IM (FLUX_RE + BB*DD)        // 13107264

// ws offsets (floats)
// WS_XN: first used as LN output xn in NCHW ((n*64+c)*4096+p) for k_conv;
//        later reused as dec planes (c*PIX + g).
// WS_XE: xe/u planes (c*PIX + g); c in [0,32) = re of e=c, [32,64) = im.
#define WS_XN   0                        // PIX*64
#define WS_XE   (WS_XN + PIX*C2)         // PIX*64
#define WS_G1   (WS_XE + PIX*C2)         // PIX*32  g1 planes
#define WS_G2   (WS_G1 + PIX*DD)         // PIX*32  g2 planes
#define WS_WINV (WS_G2 + PIX*DD)         // 2048 (re 1024, im 1024)
#define WS_SUMS (WS_WINV + 2048)         // 3072
#define WS_GATE (WS_SUMS + 3072)         // 1536
#define WS_SRCR (WS_GATE + 1536)
#define WS_SRCI (WS_SRCR + 1536)
#define WS_ODR  (WS_SRCI + 1536)
#define WS_ODI  (WS_ODR + 1536)
#define WS_OFR  (WS_ODI + 1536)
#define WS_OFI  (WS_OFR + 1536)

__device__ __forceinline__ float sigmoidf_(float x) { return 1.f / (1.f + expf(-x)); }
__device__ __forceinline__ float softplusf_(float x) { return log1pf(expf(x)); }

// ---------------- Gauss-Jordan inverse of Wb (32x32 complex), partial pivoting ----------------
__global__ void k_invert(const float* __restrict__ Wre, const float* __restrict__ Wim,
                         float* __restrict__ ws) {
  __shared__ float Mre[32][64];
  __shared__ float Mim[32][64];
  __shared__ float fre[32], fim[32];
  __shared__ float pr_s, pi_s;
  __shared__ int piv_s;
  int tid = threadIdx.x;  // 256 threads
  for (int idx = tid; idx < 2048; idx += 256) {
    int i = idx >> 6, j = idx & 63;
    if (j < 32) { Mre[i][j] = Wre[i * 32 + j]; Mim[i][j] = Wim[i * 32 + j]; }
    else        { Mre[i][j] = (j - 32 == i) ? 1.f : 0.f; Mim[i][j] = 0.f; }
  }
  __syncthreads();
  for (int k = 0; k < 32; ++k) {
    if (tid == 0) {
      int best = k; float bm = fabsf(Mre[k][k]) + fabsf(Mim[k][k]);
      for (int r = k + 1; r < 32; ++r) {
        float m = fabsf(Mre[r][k]) + fabsf(Mim[r][k]);
        if (m > bm) { bm = m; best = r; }
      }
      piv_s = best;
    }
    __syncthreads();
    int pv = piv_s;
    if (pv != k && tid < 64) {
      float tr = Mre[k][tid], ti = Mim[k][tid];
      Mre[k][tid] = Mre[pv][tid]; Mim[k][tid] = Mim[pv][tid];
      Mre[pv][tid] = tr; Mim[pv][tid] = ti;
    }
    __syncthreads();
    if (tid == 0) {
      float a = Mre[k][k], b = Mim[k][k];
      float d = a * a + b * b;
      pr_s = a / d; pi_s = -b / d;
    }
    __syncthreads();
    float pr = pr_s, pi = pi_s;
    if (tid < 64) {
      float a = Mre[k][tid], b = Mim[k][tid];
      Mre[k][tid] = a * pr - b * pi;
      Mim[k][tid] = a * pi + b * pr;
    }
    __syncthreads();
    if (tid < 32) { fre[tid] = Mre[tid][k]; fim[tid] = Mim[tid][k]; }
    __syncthreads();
    for (int idx = tid; idx < 2048; idx += 256) {
      int i = idx >> 6, j = idx & 63;
      if (i != k) {
        float fr = fre[i], fi = fim[i];
        float ar = Mre[k][j], ai = Mim[k][j];
        Mre[i][j] -= fr * ar - fi * ai;
        Mim[i][j] -= fr * ai + fi * ar;
      }
    }
    __syncthreads();
  }
  for (int idx = tid; idx < 1024; idx += 256) {
    int e = idx >> 5, d = idx & 31;
    ws[WS_WINV + e * 32 + d] = Mre[e][32 + d];
    ws[WS_WINV + 1024 + e * 32 + d] = Mim[e][32 + d];
  }
}

// ---------------- spatial LayerNorm over 64 (re,im) channels -> xn (NCHW) ----------------
__global__ void k_ln_s(const float* __restrict__ xre, const float* __restrict__ xim,
                       const float* __restrict__ g, const float* __restrict__ b,
                       float* __restrict__ ws) {
  int gid = blockIdx.x * 256 + threadIdx.x;
  if (gid >= PIX) return;
  int n = gid >> 12, p = gid & 4095;
  float v[64];
  float s = 0.f;
#pragma unroll
  for (int c = 0; c < 32; ++c) { v[c] = xre[(n * 32 + c) * 4096 + p]; s += v[c]; }
#pragma unroll
  for (int c = 0; c < 32; ++c) { v[32 + c] = xim[(n * 32 + c) * 4096 + p]; s += v[32 + c]; }
  float m = s * (1.f / 64.f);
  float vs = 0.f;
#pragma unroll
  for (int c = 0; c < 64; ++c) { float d = v[c] - m; vs += d * d; }
  float rs = rsqrtf(vs * (1.f / 64.f) + 1e-5f);
#pragma unroll
  for (int c = 0; c < 64; ++c)
    ws[WS_XN + (n * 64 + c) * 4096 + p] = (v[c] - m) * rs * g[c] + b[c];
}

// ---------------- 3x3 conv 64->64, LDS-tiled + register-blocked (16-row tiles) ----------------
// grid: 48 n * 8 ocg * 4 yt = 1536 blocks (6/CU). LDS 18KB. acc 4 rows x 8 oc.
__global__ void __launch_bounds__(256) k_conv(
    const float* __restrict__ xn, const float* __restrict__ wconv,
    const float* __restrict__ bconv,
    const float* __restrict__ xre, const float* __restrict__ xim,
    float* __restrict__ out) {
  __shared__ float in_lds[18][4][64];   // [local row][ci in chunk][col]
  int bid = blockIdx.x;
  int n = bid >> 5;
  int rem = bid & 31;
  int ocg = rem >> 2;         // 0..7 : oc = ocg*8 .. +7
  int yt = rem & 3;           // 0..3 : rows yt*16 .. +15
  int tid = threadIdx.x;
  int tx = tid & 63;          // col
  int rg = tid >> 6;          // 0..3 row group (4 rows each); also ci-lane for staging
  int y0 = yt * 16;
  int ybase = rg * 4;

  float acc[4][8];
#pragma unroll
  for (int r = 0; r < 4; ++r)
#pragma unroll
    for (int o = 0; o < 8; ++o) acc[r][o] = 0.f;

  const float* xnn = xn + n * 64 * 4096;

  for (int cc = 0; cc < 16; ++cc) {
    int ci0 = cc * 4;
    __syncthreads();
#pragma unroll
    for (int r = 0; r < 18; ++r) {
      int gy = y0 - 1 + r;
      float v = 0.f;
      if ((unsigned)gy < 64u) v = xnn[(ci0 + rg) * 4096 + gy * 64 + tx];
      in_lds[r][rg][tx] = v;
    }
    __syncthreads();

#pragma unroll
    for (int j = 0; j < 4; ++j) {
      float win[6][3];
#pragma unroll
      for (int rl = 0; rl < 6; ++rl) {
        const float* row = &in_lds[ybase + rl][j][0];
        win[rl][0] = (tx > 0) ? row[tx - 1] : 0.f;
        win[rl][1] = row[tx];
        win[rl][2] = (tx < 63) ? row[tx + 1] : 0.f;
      }
      int ci = ci0 + j;
#pragma unroll
      for (int o = 0; o < 8; ++o) {
        const float* wp = wconv + ((ocg * 8 + o) * 64 + ci) * 9;  // block-uniform -> s_load
        float w0 = wp[0], w1 = wp[1], w2 = wp[2];
        float w3 = wp[3], w4 = wp[4], w5 = wp[5];
        float w6 = wp[6], w7 = wp[7], w8 = wp[8];
#pragma unroll
        for (int r = 0; r < 4; ++r) {
          float s = acc[r][o];
          s = fmaf(win[r][0], w0, s);
          s = fmaf(win[r][1], w1, s);
          s = fmaf(win[r][2], w2, s);
          s = fmaf(win[r + 1][0], w3, s);
          s = fmaf(win[r + 1][1], w4, s);
          s = fmaf(win[r + 1][2], w5, s);
          s = fmaf(win[r + 2][0], w6, s);
          s = fmaf(win[r + 2][1], w7, s);
          s = fmaf(win[r + 2][2], w8, s);
          acc[r][o] = s;
        }
      }
    }
  }

#pragma unroll
  for (int o = 0; o < 8; ++o) {
    int oc = ocg * 8 + o;
    float bias = bconv[oc];
    int d = (oc < 32) ? oc : oc - 32;
    long base = ((oc < 32) ? (long)MAIN_RE : (long)MAIN_IM) + (long)(n * 32 + d) * 4096;
    const float* resid = (oc < 32) ? xre : xim;
#pragma unroll
    for (int r = 0; r < 4; ++r) {
      int p = (y0 + ybase + r) * 64 + tx;
      int oi = (n * 32 + d) * 4096 + p;
      out[base + p] = resid[oi] + acc[r][o] + bias;
    }
  }
}

// ---------------- x_eig: thread-per-pixel, write channel planes ----------------
__global__ void __launch_bounds__(256) k_xeig(
    const float* __restrict__ out, const float* __restrict__ Wre,
    const float* __restrict__ Wim, float* __restrict__ xe) {
  int g = blockIdx.x * 256 + threadIdx.x;
  int n = g >> 12, p = g & 4095;
  float xr[32], xi[32];
#pragma unroll
  for (int d = 0; d < 32; ++d) xr[d] = out[MAIN_RE + (n * 32 + d) * 4096 + p];
#pragma unroll
  for (int d = 0; d < 32; ++d) xi[d] = out[MAIN_IM + (n * 32 + d) * 4096 + p];
#pragma unroll
  for (int e0 = 0; e0 < 32; e0 += 4) {
    float ar[4] = {0.f, 0.f, 0.f, 0.f}, ai[4] = {0.f, 0.f, 0.f, 0.f};
#pragma unroll
    for (int d = 0; d < 32; ++d) {
      float r = xr[d], im = xi[d];
#pragma unroll
      for (int j = 0; j < 4; ++j) {
        float wr = Wre[d * 32 + e0 + j], wi = Wim[d * 32 + e0 + j];  // uniform -> s_load
        ar[j] += r * wr - im * wi;
        ai[j] += r * wi + im * wr;
      }
    }
#pragma unroll
    for (int j = 0; j < 4; ++j) {
      xe[(e0 + j) * PIX + g] = ar[j];
      xe[(32 + e0 + j) * PIX + g] = ai[j];
    }
  }
}

// ---------------- spatial sums of xe planes per (n, channel) ----------------
__global__ void k_mean(const float* __restrict__ xe, float* __restrict__ sums) {
  __shared__ float red[256];
  int n = blockIdx.x, c = blockIdx.y;
  int tid = threadIdx.x;
  const float* src = xe + c * PIX + n * 4096;
  float s = 0.f;
#pragma unroll
  for (int i = 0; i < 16; ++i) s += src[tid + i * 256];
  red[tid] = s;
  __syncthreads();
  for (int w = 128; w > 0; w >>= 1) {
    if (tid < w) red[tid] += red[tid + w];
    __syncthreads();
  }
  if (tid == 0) sums[n * 64 + c] = red[0];
}

// ---------------- flux scan (T=24) + all per-(b,t,d) coefficients ----------------
__global__ void k_flux(float* __restrict__ ws, float* __restrict__ out,
                       const float* __restrict__ dt_seq,
                       const float* __restrict__ flux_re, const float* __restrict__ flux_im,
                       const float* __restrict__ lam_flux,
                       const float* __restrict__ bf_re, const float* __restrict__ bf_im,
                       const float* __restrict__ c_re, const float* __restrict__ c_im,
                       const float* __restrict__ g_w, const float* __restrict__ g_b,
                       const float* __restrict__ a_decay, const float* __restrict__ b_freq) {
  int tid = threadIdx.x;
  if (tid >= 64) return;
  int b = tid >> 5, e = tid & 31;
  float sp_lf = softplusf_(lam_flux[e]);
  float lr = -softplusf_(a_decay[e]);
  float li = b_freq[e];
  float den = lr * lr + li * li;
  float bfr = bf_re[e], bfi = bf_im[e];
  float cr = c_re[e], ci = c_im[e];
  float fr = flux_re[b * 32 + e], fi = flux_im[b * 32 + e];
  for (int t = 0; t < 24; ++t) {
    int n = b * 24 + t;
    float dt = dt_seq[n];
    float A = expf(-sp_lf * dt);
    float xmr = ws[WS_SUMS + n * 64 + e] * (1.f / 4096.f);
    float xmi = ws[WS_SUMS + n * 64 + 32 + e] * (1.f / 4096.f);
    float Xr = (bfr * xmr - bfi * xmi) * dt;
    float Xi = (bfr * xmi + bfi * xmr) * dt;
    fr = A * fr + Xr;
    fi = A * fi + Xi;
    ws[WS_GATE + n * 32 + e] = sigmoidf_(fr * g_w[e] + g_b[e]);
    ws[WS_SRCR + n * 32 + e] = fr * cr - fi * ci;
    ws[WS_SRCI + n * 32 + e] = fr * ci + fi * cr;
    float er = expf(lr * dt);
    float odr = er * cosf(li * dt);
    float odi = er * sinf(li * dt);
    ws[WS_ODR + n * 32 + e] = odr;
    ws[WS_ODI + n * 32 + e] = odi;
    float nr = odr - 1.f, ni = odi;
    ws[WS_OFR + n * 32 + e] = (nr * lr + ni * li) / den;
    ws[WS_OFI + n * 32 + e] = (ni * lr - nr * li) / den;
  }
  out[FLUX_RE + b * 32 + e] = fr;
  out[FLUX_IM + b * 32 + e] = fi;
}

// ---------------- spatial gate 1: 1x1 conv 64->32 + silu, thread-per-pixel ----------------
__global__ void __launch_bounds__(256) k_sg1(
    const float* __restrict__ xe, float* __restrict__ g1,
    const float* __restrict__ w1, const float* __restrict__ b1) {
  int g = blockIdx.x * 256 + threadIdx.x;
  float v[64];
#pragma unroll
  for (int c = 0; c < 64; ++c) v[c] = xe[c * PIX + g];
#pragma unroll
  for (int o0 = 0; o0 < 32; o0 += 4) {
    float acc[4] = {b1[o0], b1[o0 + 1], b1[o0 + 2], b1[o0 + 3]};
#pragma unroll
    for (int c = 0; c < 64; ++c) {
#pragma unroll
      for (int j = 0; j < 4; ++j)
        acc[j] = fmaf(v[c], w1[(o0 + j) * 64 + c], acc[j]);   // uniform -> s_load
    }
#pragma unroll
    for (int j = 0; j < 4; ++j)
      g1[(o0 + j) * PIX + g] = acc[j] * sigmoidf_(acc[j]);
  }
}

// ---------------- spatial gate 2: depthwise 3x3 on planes ----------------
__global__ void __launch_bounds__(256) k_sgdw(
    const float* __restrict__ g1, float* __restrict__ g2, const float* __restrict__ dw) {
  int g = blockIdx.x * 256 + threadIdx.x;
  int oc = blockIdx.y;                  // block-uniform
  int n = g >> 12, p = g & 4095;
  int y = p >> 6, x = p & 63;
  const float* src = g1 + oc * PIX + n * 4096;
  const float* w = dw + oc * 9;         // uniform -> s_load
  float acc = 0.f;
#pragma unroll
  for (int ky = 0; ky < 3; ++ky) {
    int yy = y + ky - 1;
    if ((unsigned)yy < 64u) {
#pragma unroll
      for (int kx = 0; kx < 3; ++kx) {
        int xx = x + kx - 1;
        if ((unsigned)xx < 64u)
          acc = fmaf(src[yy * 64 + xx], w[ky * 3 + kx], acc);
      }
    }
  }
  g2[oc * PIX + g] = acc;
}

// ---------------- sg3 (1x1 32->32 + sigmoid) fused with forcing -> u_t ----------------
__global__ void __launch_bounds__(256) k_force(
    const float* __restrict__ g2p, float* __restrict__ xe,
    const float* __restrict__ gate, const float* __restrict__ srcr,
    const float* __restrict__ srci, const float* __restrict__ ofr_p,
    const float* __restrict__ ofi_p, const float* __restrict__ odr_p,
    const float* __restrict__ odi_p,
    const float* __restrict__ hre, const float* __restrict__ him,
    const float* __restrict__ w2, const float* __restrict__ b2) {
  int g = blockIdx.x * 256 + threadIdx.x;
  int n = g >> 12, p = g & 4095;
  int b = (n >= 24) ? 1 : 0;
  int t = n - b * 24;
  float v[32];
#pragma unroll
  for (int c = 0; c < 32; ++c) v[c] = g2p[c * PIX + g];
  float spg[32];
#pragma unroll
  for (int o0 = 0; o0 < 32; o0 += 4) {
    float acc[4] = {b2[o0], b2[o0 + 1], b2[o0 + 2], b2[o0 + 3]};
#pragma unroll
    for (int c = 0; c < 32; ++c) {
#pragma unroll
      for (int j = 0; j < 4; ++j)
        acc[j] = fmaf(v[c], w2[(o0 + j) * 32 + c], acc[j]);   // uniform -> s_load
    }
#pragma unroll
    for (int j = 0; j < 4; ++j) spg[o0 + j] = sigmoidf_(acc[j]);
  }
#pragma unroll
  for (int e = 0; e < 32; ++e) {
    int ie = n * 32 + e;
    float gc = gate[ie] * spg[e];
    float xr = xe[e * PIX + g];
    float xi = xe[(32 + e) * PIX + g];
    float om = 1.f - gc;
    float fr2 = xr * gc + srcr[ie] * om;
    float fi2 = xi * gc + srci[ie] * om;
    float ofr = ofr_p[ie], ofi = ofi_p[ie];
    float ur = fr2 * ofr - fi2 * ofi;
    float ui = fr2 * ofi + fi2 * ofr;
    if (t == 0) {                       // wave-uniform branch
      int hb = (b * 4096 + p) * 32 + e;
      float hr = hre[hb], hi = him[hb];
      float odr = odr_p[(b * 24) * 32 + e], odi = odi_p[(b * 24) * 32 + e];
      ur += hr * odr - hi * odi;
      ui += hr * odi + hi * odr;
    }
    xe[e * PIX + g] = ur;
    xe[(32 + e) * PIX + g] = ui;
  }
}

// ---------------- temporal scan over T=24 on planes (in place), emit h_out ----------------
__global__ void __launch_bounds__(256) k_scan(
    float* __restrict__ u, const float* __restrict__ odr_p,
    const float* __restrict__ odi_p, float* __restrict__ out) {
  int p = blockIdx.x * 256 + threadIdx.x;   // 0..4095
  int e = blockIdx.y;                        // 0..31 (block-uniform)
  int b = blockIdx.z;                        // 0..1
  float ur = 0.f, ui = 0.f;
  for (int t = 0; t < 24; ++t) {
    int n = b * 24 + t;
    int idx  = e * PIX + n * 4096 + p;
    int idxi = (32 + e) * PIX + n * 4096 + p;
    float ar = odr_p[n * 32 + e];            // uniform -> s_load
    float ai = odi_p[n * 32 + e];
    float xr = u[idx], xi = u[idxi];
    float nr = ar * ur - ai * ui + xr;
    float ni = ar * ui + ai * ur + xi;
    ur = nr; ui = ni;
    u[idx] = ur;
    u[idxi] = ui;
  }
  out[HOUT_RE + (b * 4096 + p) * 32 + e] = ur;
  out[HOUT_IM + (b * 4096 + p) * 32 + e] = ui;
}

// ---------------- dec = u_out @ Wb_inv : thread-per-pixel, planes -> planes ----------------
__global__ void __launch_bounds__(256) k_dec(
    const float* __restrict__ u, const float* __restrict__ winv,
    float* __restrict__ dec) {
  int g = blockIdx.x * 256 + threadIdx.x;
  float ur[32], ui[32];
#pragma unroll
  for (int e = 0; e < 32; ++e) ur[e] = u[e * PIX + g];
#pragma unroll
  for (int e = 0; e < 32; ++e) ui[e] = u[(32 + e) * PIX + g];
#pragma unroll
  for (int d0 = 0; d0 < 32; d0 += 4) {
    float ar[4] = {0.f, 0.f, 0.f, 0.f}, ai[4] = {0.f, 0.f, 0.f, 0.f};
#pragma unroll
    for (int e = 0; e < 32; ++e) {
      float r = ur[e], im = ui[e];
#pragma unroll
      for (int j = 0; j < 4; ++j) {
        float wr = winv[e * 32 + d0 + j];         // uniform -> s_load
        float wi = winv[1024 + e * 32 + d0 + j];
        ar[j] += r * wr - im * wi;
        ai[j] += r * wi + im * wr;
      }
    }
#pragma unroll
    for (int j = 0; j < 4; ++j) {
      dec[(d0 + j) * PIX + g] = ar[j];
      dec[(32 + d0 + j) * PIX + g] = ai[j];
    }
  }
}

// ---------------- LN_t + FFN (64->128->64) + z = x_upd + dec + delta ----------------
__global__ void __launch_bounds__(256) k_final(
    const float* __restrict__ dec, float* __restrict__ out,
    const float* __restrict__ lg, const float* __restrict__ lb,
    const float* __restrict__ w1, const float* __restrict__ b1,
    const float* __restrict__ w2, const float* __restrict__ b2) {
  int g = blockIdx.x * 256 + threadIdx.x;
  int n = g >> 12, p = g & 4095;
  float dn[64];
  float s = 0.f;
#pragma unroll
  for (int c = 0; c < 64; ++c) { dn[c] = dec[c * PIX + g]; s += dn[c]; }
  float m = s * (1.f / 64.f);
  float vs = 0.f;
#pragma unroll
  for (int c = 0; c < 64; ++c) { float d = dn[c] - m; vs += d * d; }
  float rs = rsqrtf(vs * (1.f / 64.f) + 1e-5f);
#pragma unroll
  for (int c = 0; c < 64; ++c) dn[c] = (dn[c] - m) * rs * lg[c] + lb[c];

  float o2[64];
#pragma unroll
  for (int c = 0; c < 64; ++c) o2[c] = b2[c];

  for (int kc = 0; kc < 8; ++kc) {           // 8 chunks of 16 k
    float hid[16];
    {
      const float4* bp = (const float4*)(b1 + kc * 16);
      float4 h0 = bp[0], h1 = bp[1], h2 = bp[2], h3 = bp[3];
      hid[0] = h0.x; hid[1] = h0.y; hid[2] = h0.z; hid[3] = h0.w;
      hid[4] = h1.x; hid[5] = h1.y; hid[6] = h1.z; hid[7] = h1.w;
      hid[8] = h2.x; hid[9] = h2.y; hid[10] = h2.z; hid[11] = h2.w;
      hid[12] = h3.x; hid[13] = h3.y; hid[14] = h3.z; hid[15] = h3.w;
    }
#pragma unroll
    for (int c = 0; c < 64; ++c) {
      const float4* wp = (const float4*)(w1 + c * 128 + kc * 16);
      float4 a0 = wp[0], a1 = wp[1], a2 = wp[2], a3 = wp[3];
      float d = dn[c];
      hid[0]  = fmaf(d, a0.x, hid[0]);  hid[1]  = fmaf(d, a0.y, hid[1]);
      hid[2]  = fmaf(d, a0.z, hid[2]);  hid[3]  = fmaf(d, a0.w, hid[3]);
      hid[4]  = fmaf(d, a1.x, hid[4]);  hid[5]  = fmaf(d, a1.y, hid[5]);
      hid[6]  = fmaf(d, a1.z, hid[6]);  hid[7]  = fmaf(d, a1.w, hid[7]);
      hid[8]  = fmaf(d, a2.x, hid[8]);  hid[9]  = fmaf(d, a2.y, hid[9]);
      hid[10] = fmaf(d, a2.z, hid[10]); hid[11] = fmaf(d, a2.w, hid[11]);
      hid[12] = fmaf(d, a3.x, hid[12]); hid[13] = fmaf(d, a3.y, hid[13]);
      hid[14] = fmaf(d, a3.z, hid[14]); hid[15] = fmaf(d, a3.w, hid[15]);
    }
#pragma unroll
    for (int j = 0; j < 16; ++j) hid[j] = hid[j] * sigmoidf_(hid[j]);
#pragma unroll
    for (int j = 0; j < 16; ++j) {
      const float4* wq = (const float4*)(w2 + (kc * 16 + j) * 64);
      float h = hid[j];
#pragma unroll
      for (int c4 = 0; c4 < 16; ++c4) {
        float4 w = wq[c4];
        o2[4 * c4 + 0] = fmaf(h, w.x, o2[4 * c4 + 0]);
        o2[4 * c4 + 1] = fmaf(h, w.y, o2[4 * c4 + 1]);
        o2[4 * c4 + 2] = fmaf(h, w.z, o2[4 * c4 + 2]);
        o2[4 * c4 + 3] = fmaf(h, w.w, o2[4 * c4 + 3]);
      }
    }
  }

#pragma unroll
  for (int d = 0; d < 32; ++d) {
    int oi = (n * 32 + d) * 4096 + p;
    out[MAIN_RE + oi] += dec[d * PIX + g] + o2[d];
    out[MAIN_IM + oi] += dec[(32 + d) * PIX + g] + o2[32 + d];
  }
}

extern "C" void kernel_launch(void* const* d_in, const int* in_sizes, int n_in,
                              void* d_out, int out_size, void* d_ws, size_t ws_size,
                              hipStream_t stream) {
  (void)in_sizes; (void)n_in; (void)out_size; (void)ws_size;
  const float* xre      = (const float*)d_in[0];
  const float* xim      = (const float*)d_in[1];
  const float* hre      = (const float*)d_in[2];
  const float* him      = (const float*)d_in[3];
  const float* flux_re  = (const float*)d_in[4];
  const float* flux_im  = (const float*)d_in[5];
  const float* dt_seq   = (const float*)d_in[6];
  const float* ln_s_g   = (const float*)d_in[7];
  const float* ln_s_b   = (const float*)d_in[8];
  const float* conv_w   = (const float*)d_in[9];
  const float* conv_b   = (const float*)d_in[10];
  const float* ln_t_g   = (const float*)d_in[11];
  const float* ln_t_b   = (const float*)d_in[12];
  const float* W_re     = (const float*)d_in[13];
  const float* W_im     = (const float*)d_in[14];
  const float* lam_flux = (const float*)d_in[15];
  const float* bf_re    = (const float*)d_in[16];
  const float* bf_im    = (const float*)d_in[17];
  const float* c_re     = (const float*)d_in[18];
  const float* c_im     = (const float*)d_in[19];
  const float* g_w      = (const float*)d_in[20];
  const float* g_b      = (const float*)d_in[21];
  const float* a_decay  = (const float*)d_in[22];
  const float* b_freq   = (const float*)d_in[23];
  const float* ffn_w1   = (const float*)d_in[24];
  const float* ffn_b1   = (const float*)d_in[25];
  const float* ffn_w2   = (const float*)d_in[26];
  const float* ffn_b2   = (const float*)d_in[27];
  const float* sg_w1    = (const float*)d_in[28];
  const float* sg_b1    = (const float*)d_in[29];
  const float* sg_dw    = (const float*)d_in[30];
  const float* sg_w2    = (const float*)d_in[31];
  const float* sg_b2    = (const float*)d_in[32];
  float* out = (float*)d_out;
  float* ws  = (float*)d_ws;

  k_invert<<<1, 256, 0, stream>>>(W_re, W_im, ws);
  k_ln_s<<<PIX / 256, 256, 0, stream>>>(xre, xim, ln_s_g, ln_s_b, ws);
  k_conv<<<1536, 256, 0, stream>>>(ws + WS_XN, conv_w, conv_b, xre, xim, out);
  k_xeig<<<PIX / 256, 256, 0, stream>>>(out, W_re, W_im, ws + WS_XE);
  k_mean<<<dim3(NN, 64), 256, 0, stream>>>(ws + WS_XE, ws + WS_SUMS);
  k_flux<<<1, 64, 0, stream>>>(ws, out, dt_seq, flux_re, flux_im, lam_flux,
                               bf_re, bf_im, c_re, c_im, g_w, g_b, a_decay, b_freq);
  k_sg1<<<PIX / 256, 256, 0, stream>>>(ws + WS_XE, ws + WS_G1, sg_w1, sg_b1);
  k_sgdw<<<dim3(PIX / 256, 32), 256, 0, stream>>>(ws + WS_G1, ws + WS_G2, sg_dw);
  k_force<<<PIX / 256, 256, 0, stream>>>(ws + WS_G2, ws + WS_XE,
                                         ws + WS_GATE, ws + WS_SRCR, ws + WS_SRCI,
                                         ws + WS_OFR, ws + WS_OFI, ws + WS_ODR, ws + WS_ODI,
                                         hre, him, sg_w2, sg_b2);
  k_scan<<<dim3(4096 / 256, 32, 2), 256, 0, stream>>>(ws + WS_XE, ws + WS_ODR, ws + WS_ODI, out);
  k_dec<<<PIX / 256, 256, 0, stream>>>(ws + WS_XE, ws + WS_WINV, ws + WS_XN);
  k_final<<<PIX / 256, 256, 0, stream>>>(ws + WS_XN, out, ln_t_g, ln_t_b,
                                         ffn_w1, ffn_b1, ffn_w2, ffn_b2);
}

// Round 5
// 999.055 us; speedup vs baseline: 2.9401x; 1.0147x over previous
//
#include <hip/hip_runtime.h>
#include <math.h>

#define BB 2
#define TT 24
#define DD 32
#define HWp 4096            // 64*64
#define NN (BB*TT)          // 48
#define PIX (NN*HWp)        // 196608
#define C2 (2*DD)           // 64

// d_out offsets (floats)
#define MAIN_RE 0
#define MAIN_IM (NN*DD*HWp)              // 6291456
#define HOUT_RE (2*NN*DD*HWp)            // 12582912
#define HOUT_IM (HOUT_RE + BB*HWp*DD)    // 12845056
#define FLUX_RE (HOUT_RE + 2*BB*HWp*DD)  // 13107200
#define FLUX_IM (FLUX_RE + BB*DD)        // 13107264

// ws offsets (floats)
#define WS_XN   0                        // PIX*64
#define WS_XE   (WS_XN + PIX*C2)         // PIX*64
#define WS_G1   (WS_XE + PIX*C2)         // PIX*32  g1 planes
#define WS_G2   (WS_G1 + PIX*DD)         // PIX*32  g2 planes
#define WS_WINV (WS_G2 + PIX*DD)         // 2048 (re 1024, im 1024)
#define WS_SUMS (WS_WINV + 2048)         // 3072
#define WS_GATE (WS_SUMS + 3072)         // 1536
#define WS_SRCR (WS_GATE + 1536)
#define WS_SRCI (WS_SRCR + 1536)
#define WS_ODR  (WS_SRCI + 1536)
#define WS_ODI  (WS_ODR + 1536)
#define WS_OFR  (WS_ODI + 1536)
#define WS_OFI  (WS_OFR + 1536)

__device__ __forceinline__ float sigmoidf_(float x) { return 1.f / (1.f + expf(-x)); }
__device__ __forceinline__ float softplusf_(float x) { return log1pf(expf(x)); }

// ---------------- Gauss-Jordan inverse of Wb (32x32 complex), partial pivoting ----------------
__global__ void k_invert(const float* __restrict__ Wre, const float* __restrict__ Wim,
                         float* __restrict__ ws) {
  __shared__ float Mre[32][64];
  __shared__ float Mim[32][64];
  __shared__ float fre[32], fim[32];
  __shared__ float pr_s, pi_s;
  __shared__ int piv_s;
  int tid = threadIdx.x;  // 256 threads
  for (int idx = tid; idx < 2048; idx += 256) {
    int i = idx >> 6, j = idx & 63;
    if (j < 32) { Mre[i][j] = Wre[i * 32 + j]; Mim[i][j] = Wim[i * 32 + j]; }
    else        { Mre[i][j] = (j - 32 == i) ? 1.f : 0.f; Mim[i][j] = 0.f; }
  }
  __syncthreads();
  for (int k = 0; k < 32; ++k) {
    if (tid == 0) {
      int best = k; float bm = fabsf(Mre[k][k]) + fabsf(Mim[k][k]);
      for (int r = k + 1; r < 32; ++r) {
        float m = fabsf(Mre[r][k]) + fabsf(Mim[r][k]);
        if (m > bm) { bm = m; best = r; }
      }
      piv_s = best;
    }
    __syncthreads();
    int pv = piv_s;
    if (pv != k && tid < 64) {
      float tr = Mre[k][tid], ti = Mim[k][tid];
      Mre[k][tid] = Mre[pv][tid]; Mim[k][tid] = Mim[pv][tid];
      Mre[pv][tid] = tr; Mim[pv][tid] = ti;
    }
    __syncthreads();
    if (tid == 0) {
      float a = Mre[k][k], b = Mim[k][k];
      float d = a * a + b * b;
      pr_s = a / d; pi_s = -b / d;
    }
    __syncthreads();
    float pr = pr_s, pi = pi_s;
    if (tid < 64) {
      float a = Mre[k][tid], b = Mim[k][tid];
      Mre[k][tid] = a * pr - b * pi;
      Mim[k][tid] = a * pi + b * pr;
    }
    __syncthreads();
    if (tid < 32) { fre[tid] = Mre[tid][k]; fim[tid] = Mim[tid][k]; }
    __syncthreads();
    for (int idx = tid; idx < 2048; idx += 256) {
      int i = idx >> 6, j = idx & 63;
      if (i != k) {
        float fr = fre[i], fi = fim[i];
        float ar = Mre[k][j], ai = Mim[k][j];
        Mre[i][j] -= fr * ar - fi * ai;
        Mim[i][j] -= fr * ai + fi * ar;
      }
    }
    __syncthreads();
  }
  for (int idx = tid; idx < 1024; idx += 256) {
    int e = idx >> 5, d = idx & 31;
    ws[WS_WINV + e * 32 + d] = Mre[e][32 + d];
    ws[WS_WINV + 1024 + e * 32 + d] = Mim[e][32 + d];
  }
}

// ---------------- spatial LayerNorm over 64 (re,im) channels -> xn (NCHW) ----------------
__global__ void k_ln_s(const float* __restrict__ xre, const float* __restrict__ xim,
                       const float* __restrict__ g, const float* __restrict__ b,
                       float* __restrict__ ws) {
  int gid = blockIdx.x * 256 + threadIdx.x;
  if (gid >= PIX) return;
  int n = gid >> 12, p = gid & 4095;
  float v[64];
  float s = 0.f;
#pragma unroll
  for (int c = 0; c < 32; ++c) { v[c] = xre[(n * 32 + c) * 4096 + p]; s += v[c]; }
#pragma unroll
  for (int c = 0; c < 32; ++c) { v[32 + c] = xim[(n * 32 + c) * 4096 + p]; s += v[32 + c]; }
  float m = s * (1.f / 64.f);
  float vs = 0.f;
#pragma unroll
  for (int c = 0; c < 64; ++c) { float d = v[c] - m; vs += d * d; }
  float rs = rsqrtf(vs * (1.f / 64.f) + 1e-5f);
#pragma unroll
  for (int c = 0; c < 64; ++c)
    ws[WS_XN + (n * 64 + c) * 4096 + p] = (v[c] - m) * rs * g[c] + b[c];
}

// ---------------- 3x3 conv 64->64, LDS-tiled + register-blocked (16-row tiles) ----------------
__global__ void __launch_bounds__(256) k_conv(
    const float* __restrict__ xn, const float* __restrict__ wconv,
    const float* __restrict__ bconv,
    const float* __restrict__ xre, const float* __restrict__ xim,
    float* __restrict__ out) {
  __shared__ float in_lds[18][4][64];   // [local row][ci in chunk][col]
  int bid = blockIdx.x;
  int n = bid >> 5;
  int rem = bid & 31;
  int ocg = rem >> 2;         // 0..7 : oc = ocg*8 .. +7
  int yt = rem & 3;           // 0..3 : rows yt*16 .. +15
  int tid = threadIdx.x;
  int tx = tid & 63;          // col
  int rg = tid >> 6;          // 0..3 row group (4 rows each); also ci-lane for staging
  int y0 = yt * 16;
  int ybase = rg * 4;

  float acc[4][8];
#pragma unroll
  for (int r = 0; r < 4; ++r)
#pragma unroll
    for (int o = 0; o < 8; ++o) acc[r][o] = 0.f;

  const float* xnn = xn + n * 64 * 4096;

  for (int cc = 0; cc < 16; ++cc) {
    int ci0 = cc * 4;
    __syncthreads();
#pragma unroll
    for (int r = 0; r < 18; ++r) {
      int gy = y0 - 1 + r;
      float v = 0.f;
      if ((unsigned)gy < 64u) v = xnn[(ci0 + rg) * 4096 + gy * 64 + tx];
      in_lds[r][rg][tx] = v;
    }
    __syncthreads();

#pragma unroll
    for (int j = 0; j < 4; ++j) {
      float win[6][3];
#pragma unroll
      for (int rl = 0; rl < 6; ++rl) {
        const float* row = &in_lds[ybase + rl][j][0];
        win[rl][0] = (tx > 0) ? row[tx - 1] : 0.f;
        win[rl][1] = row[tx];
        win[rl][2] = (tx < 63) ? row[tx + 1] : 0.f;
      }
      int ci = ci0 + j;
#pragma unroll
      for (int o = 0; o < 8; ++o) {
        const float* wp = wconv + ((ocg * 8 + o) * 64 + ci) * 9;  // block-uniform -> s_load
        float w0 = wp[0], w1 = wp[1], w2 = wp[2];
        float w3 = wp[3], w4 = wp[4], w5 = wp[5];
        float w6 = wp[6], w7 = wp[7], w8 = wp[8];
#pragma unroll
        for (int r = 0; r < 4; ++r) {
          float s = acc[r][o];
          s = fmaf(win[r][0], w0, s);
          s = fmaf(win[r][1], w1, s);
          s = fmaf(win[r][2], w2, s);
          s = fmaf(win[r + 1][0], w3, s);
          s = fmaf(win[r + 1][1], w4, s);
          s = fmaf(win[r + 1][2], w5, s);
          s = fmaf(win[r + 2][0], w6, s);
          s = fmaf(win[r + 2][1], w7, s);
          s = fmaf(win[r + 2][2], w8, s);
          acc[r][o] = s;
        }
      }
    }
  }

#pragma unroll
  for (int o = 0; o < 8; ++o) {
    int oc = ocg * 8 + o;
    float bias = bconv[oc];
    int d = (oc < 32) ? oc : oc - 32;
    long base = ((oc < 32) ? (long)MAIN_RE : (long)MAIN_IM) + (long)(n * 32 + d) * 4096;
    const float* resid = (oc < 32) ? xre : xim;
#pragma unroll
    for (int r = 0; r < 4; ++r) {
      int p = (y0 + ybase + r) * 64 + tx;
      int oi = (n * 32 + d) * 4096 + p;
      out[base + p] = resid[oi] + acc[r][o] + bias;
    }
  }
}

// ---------------- x_eig: thread-per-pixel, write channel planes ----------------
__global__ void __launch_bounds__(256) k_xeig(
    const float* __restrict__ out, const float* __restrict__ Wre,
    const float* __restrict__ Wim, float* __restrict__ xe) {
  int g = blockIdx.x * 256 + threadIdx.x;
  int n = g >> 12, p = g & 4095;
  float xr[32], xi[32];
#pragma unroll
  for (int d = 0; d < 32; ++d) xr[d] = out[MAIN_RE + (n * 32 + d) * 4096 + p];
#pragma unroll
  for (int d = 0; d < 32; ++d) xi[d] = out[MAIN_IM + (n * 32 + d) * 4096 + p];
#pragma unroll
  for (int e0 = 0; e0 < 32; e0 += 4) {
    float ar[4] = {0.f, 0.f, 0.f, 0.f}, ai[4] = {0.f, 0.f, 0.f, 0.f};
#pragma unroll
    for (int d = 0; d < 32; ++d) {
      float r = xr[d], im = xi[d];
#pragma unroll
      for (int j = 0; j < 4; ++j) {
        float wr = Wre[d * 32 + e0 + j], wi = Wim[d * 32 + e0 + j];  // uniform -> s_load
        ar[j] += r * wr - im * wi;
        ai[j] += r * wi + im * wr;
      }
    }
#pragma unroll
    for (int j = 0; j < 4; ++j) {
      xe[(e0 + j) * PIX + g] = ar[j];
      xe[(32 + e0 + j) * PIX + g] = ai[j];
    }
  }
}

// ---------------- spatial sums of xe planes per (n, channel) ----------------
__global__ void k_mean(const float* __restrict__ xe, float* __restrict__ sums) {
  __shared__ float red[256];
  int n = blockIdx.x, c = blockIdx.y;
  int tid = threadIdx.x;
  const float* src = xe + c * PIX + n * 4096;
  float s = 0.f;
#pragma unroll
  for (int i = 0; i < 16; ++i) s += src[tid + i * 256];
  red[tid] = s;
  __syncthreads();
  for (int w = 128; w > 0; w >>= 1) {
    if (tid < w) red[tid] += red[tid + w];
    __syncthreads();
  }
  if (tid == 0) sums[n * 64 + c] = red[0];
}

// ---------------- flux scan (T=24) + all per-(b,t,d) coefficients ----------------
__global__ void k_flux(float* __restrict__ ws, float* __restrict__ out,
                       const float* __restrict__ dt_seq,
                       const float* __restrict__ flux_re, const float* __restrict__ flux_im,
                       const float* __restrict__ lam_flux,
                       const float* __restrict__ bf_re, const float* __restrict__ bf_im,
                       const float* __restrict__ c_re, const float* __restrict__ c_im,
                       const float* __restrict__ g_w, const float* __restrict__ g_b,
                       const float* __restrict__ a_decay, const float* __restrict__ b_freq) {
  int tid = threadIdx.x;
  if (tid >= 64) return;
  int b = tid >> 5, e = tid & 31;
  float sp_lf = softplusf_(lam_flux[e]);
  float lr = -softplusf_(a_decay[e]);
  float li = b_freq[e];
  float den = lr * lr + li * li;
  float bfr = bf_re[e], bfi = bf_im[e];
  float cr = c_re[e], ci = c_im[e];
  float fr = flux_re[b * 32 + e], fi = flux_im[b * 32 + e];
  for (int t = 0; t < 24; ++t) {
    int n = b * 24 + t;
    float dt = dt_seq[n];
    float A = expf(-sp_lf * dt);
    float xmr = ws[WS_SUMS + n * 64 + e] * (1.f / 4096.f);
    float xmi = ws[WS_SUMS + n * 64 + 32 + e] * (1.f / 4096.f);
    float Xr = (bfr * xmr - bfi * xmi) * dt;
    float Xi = (bfr * xmi + bfi * xmr) * dt;
    fr = A * fr + Xr;
    fi = A * fi + Xi;
    ws[WS_GATE + n * 32 + e] = sigmoidf_(fr * g_w[e] + g_b[e]);
    ws[WS_SRCR + n * 32 + e] = fr * cr - fi * ci;
    ws[WS_SRCI + n * 32 + e] = fr * ci + fi * cr;
    float er = expf(lr * dt);
    float odr = er * cosf(li * dt);
    float odi = er * sinf(li * dt);
    ws[WS_ODR + n * 32 + e] = odr;
    ws[WS_ODI + n * 32 + e] = odi;
    float nr = odr - 1.f, ni = odi;
    ws[WS_OFR + n * 32 + e] = (nr * lr + ni * li) / den;
    ws[WS_OFI + n * 32 + e] = (ni * lr - nr * li) / den;
  }
  out[FLUX_RE + b * 32 + e] = fr;
  out[FLUX_IM + b * 32 + e] = fi;
}

// ---------------- spatial gate 1: 1x1 conv 64->32 + silu, thread-per-pixel ----------------
__global__ void __launch_bounds__(256) k_sg1(
    const float* __restrict__ xe, float* __restrict__ g1,
    const float* __restrict__ w1, const float* __restrict__ b1) {
  int g = blockIdx.x * 256 + threadIdx.x;
  float v[64];
#pragma unroll
  for (int c = 0; c < 64; ++c) v[c] = xe[c * PIX + g];
#pragma unroll
  for (int o0 = 0; o0 < 32; o0 += 4) {
    float acc[4] = {b1[o0], b1[o0 + 1], b1[o0 + 2], b1[o0 + 3]};
#pragma unroll
    for (int c = 0; c < 64; ++c) {
#pragma unroll
      for (int j = 0; j < 4; ++j)
        acc[j] = fmaf(v[c], w1[(o0 + j) * 64 + c], acc[j]);   // uniform -> s_load
    }
#pragma unroll
    for (int j = 0; j < 4; ++j)
      g1[(o0 + j) * PIX + g] = acc[j] * sigmoidf_(acc[j]);
  }
}

// ---------------- spatial gate 2: depthwise 3x3 on planes ----------------
__global__ void __launch_bounds__(256) k_sgdw(
    const float* __restrict__ g1, float* __restrict__ g2, const float* __restrict__ dw) {
  int g = blockIdx.x * 256 + threadIdx.x;
  int oc = blockIdx.y;                  // block-uniform
  int n = g >> 12, p = g & 4095;
  int y = p >> 6, x = p & 63;
  const float* src = g1 + oc * PIX + n * 4096;
  const float* w = dw + oc * 9;         // uniform -> s_load
  float acc = 0.f;
#pragma unroll
  for (int ky = 0; ky < 3; ++ky) {
    int yy = y + ky - 1;
    if ((unsigned)yy < 64u) {
#pragma unroll
      for (int kx = 0; kx < 3; ++kx) {
        int xx = x + kx - 1;
        if ((unsigned)xx < 64u)
          acc = fmaf(src[yy * 64 + xx], w[ky * 3 + kx], acc);
      }
    }
  }
  g2[oc * PIX + g] = acc;
}

// ---------------- sg3 (1x1 32->32 + sigmoid) fused with forcing -> u_t ----------------
__global__ void __launch_bounds__(256) k_force(
    const float* __restrict__ g2p, float* __restrict__ xe,
    const float* __restrict__ gate, const float* __restrict__ srcr,
    const float* __restrict__ srci, const float* __restrict__ ofr_p,
    const float* __restrict__ ofi_p, const float* __restrict__ odr_p,
    const float* __restrict__ odi_p,
    const float* __restrict__ hre, const float* __restrict__ him,
    const float* __restrict__ w2, const float* __restrict__ b2) {
  int g = blockIdx.x * 256 + threadIdx.x;
  int n = g >> 12, p = g & 4095;
  int b = (n >= 24) ? 1 : 0;
  int t = n - b * 24;
  float v[32];
#pragma unroll
  for (int c = 0; c < 32; ++c) v[c] = g2p[c * PIX + g];
  float spg[32];
#pragma unroll
  for (int o0 = 0; o0 < 32; o0 += 4) {
    float acc[4] = {b2[o0], b2[o0 + 1], b2[o0 + 2], b2[o0 + 3]};
#pragma unroll
    for (int c = 0; c < 32; ++c) {
#pragma unroll
      for (int j = 0; j < 4; ++j)
        acc[j] = fmaf(v[c], w2[(o0 + j) * 32 + c], acc[j]);   // uniform -> s_load
    }
#pragma unroll
    for (int j = 0; j < 4; ++j) spg[o0 + j] = sigmoidf_(acc[j]);
  }
#pragma unroll
  for (int e = 0; e < 32; ++e) {
    int ie = n * 32 + e;
    float gc = gate[ie] * spg[e];
    float xr = xe[e * PIX + g];
    float xi = xe[(32 + e) * PIX + g];
    float om = 1.f - gc;
    float fr2 = xr * gc + srcr[ie] * om;
    float fi2 = xi * gc + srci[ie] * om;
    float ofr = ofr_p[ie], ofi = ofi_p[ie];
    float ur = fr2 * ofr - fi2 * ofi;
    float ui = fr2 * ofi + fi2 * ofr;
    if (t == 0) {                       // wave-uniform branch
      int hb = (b * 4096 + p) * 32 + e;
      float hr = hre[hb], hi = him[hb];
      float odr = odr_p[(b * 24) * 32 + e], odi = odi_p[(b * 24) * 32 + e];
      ur += hr * odr - hi * odi;
      ui += hr * odi + hi * odr;
    }
    xe[e * PIX + g] = ur;
    xe[(32 + e) * PIX + g] = ui;
  }
}

// ---------------- temporal scan over T=24 on planes (in place), emit h_out ----------------
__global__ void __launch_bounds__(256) k_scan(
    float* __restrict__ u, const float* __restrict__ odr_p,
    const float* __restrict__ odi_p, float* __restrict__ out) {
  int p = blockIdx.x * 256 + threadIdx.x;   // 0..4095
  int e = blockIdx.y;                        // 0..31 (block-uniform)
  int b = blockIdx.z;                        // 0..1
  float ur = 0.f, ui = 0.f;
  for (int t = 0; t < 24; ++t) {
    int n = b * 24 + t;
    int idx  = e * PIX + n * 4096 + p;
    int idxi = (32 + e) * PIX + n * 4096 + p;
    float ar = odr_p[n * 32 + e];            // uniform -> s_load
    float ai = odi_p[n * 32 + e];
    float xr = u[idx], xi = u[idxi];
    float nr = ar * ur - ai * ui + xr;
    float ni = ar * ui + ai * ur + xi;
    ur = nr; ui = ni;
    u[idx] = ur;
    u[idxi] = ui;
  }
  out[HOUT_RE + (b * 4096 + p) * 32 + e] = ur;
  out[HOUT_IM + (b * 4096 + p) * 32 + e] = ui;
}

// ---------------- dec = u_out @ Wb_inv : thread-per-pixel, planes -> planes ----------------
__global__ void __launch_bounds__(256) k_dec(
    const float* __restrict__ u, const float* __restrict__ winv,
    float* __restrict__ dec) {
  int g = blockIdx.x * 256 + threadIdx.x;
  float ur[32], ui[32];
#pragma unroll
  for (int e = 0; e < 32; ++e) ur[e] = u[e * PIX + g];
#pragma unroll
  for (int e = 0; e < 32; ++e) ui[e] = u[(32 + e) * PIX + g];
#pragma unroll
  for (int d0 = 0; d0 < 32; d0 += 4) {
    float ar[4] = {0.f, 0.f, 0.f, 0.f}, ai[4] = {0.f, 0.f, 0.f, 0.f};
#pragma unroll
    for (int e = 0; e < 32; ++e) {
      float r = ur[e], im = ui[e];
#pragma unroll
      for (int j = 0; j < 4; ++j) {
        float wr = winv[e * 32 + d0 + j];         // uniform -> s_load
        float wi = winv[1024 + e * 32 + d0 + j];
        ar[j] += r * wr - im * wi;
        ai[j] += r * wi + im * wr;
      }
    }
#pragma unroll
    for (int j = 0; j < 4; ++j) {
      dec[(d0 + j) * PIX + g] = ar[j];
      dec[(32 + d0 + j) * PIX + g] = ai[j];
    }
  }
}

// ---------------- LN_t + FFN (64->128->64) + z = x_upd + dec + delta ----------------
// FFN weights staged per-kc-chunk in LDS (8KB), read via broadcast ds_read_b128.
__global__ void __launch_bounds__(256) k_final(
    const float* __restrict__ dec, float* __restrict__ out,
    const float* __restrict__ lg, const float* __restrict__ lb,
    const float* __restrict__ w1, const float* __restrict__ b1,
    const float* __restrict__ w2, const float* __restrict__ b2) {
  __shared__ float4 lw1[64][4];   // [c][j4]  : w1[c][kc*16 + j4*4 ..]
  __shared__ float4 lw2[16][16];  // [j][c4]  : w2[kc*16+j][c4*4 ..]
  int tid = threadIdx.x;
  int g = blockIdx.x * 256 + tid;
  int n = g >> 12, p = g & 4095;
  float dn[64];
  float s = 0.f;
#pragma unroll
  for (int c = 0; c < 64; ++c) { dn[c] = dec[c * PIX + g]; s += dn[c]; }
  float m = s * (1.f / 64.f);
  float vs = 0.f;
#pragma unroll
  for (int c = 0; c < 64; ++c) { float d = dn[c] - m; vs += d * d; }
  float rs = rsqrtf(vs * (1.f / 64.f) + 1e-5f);
#pragma unroll
  for (int c = 0; c < 64; ++c) dn[c] = (dn[c] - m) * rs * lg[c] + lb[c];

  float o2[64];
#pragma unroll
  for (int c = 0; c < 64; ++c) o2[c] = b2[c];

  // staging indices (fixed per thread)
  int sc = tid >> 2, sq = tid & 3;     // w1: c=sc, quad=sq
  int sj = tid >> 4, sr = tid & 15;    // w2: j=sj, c4=sr

  for (int kc = 0; kc < 8; ++kc) {     // 8 chunks of 16 k
    __syncthreads();
    lw1[sc][sq] = *(const float4*)(w1 + sc * 128 + kc * 16 + sq * 4);
    lw2[sj][sr] = *(const float4*)(w2 + (kc * 16 + sj) * 64 + sr * 4);
    __syncthreads();

    float hid[16];
    {
      const float4* bp = (const float4*)(b1 + kc * 16);
      float4 h0 = bp[0], h1 = bp[1], h2 = bp[2], h3 = bp[3];
      hid[0] = h0.x; hid[1] = h0.y; hid[2] = h0.z; hid[3] = h0.w;
      hid[4] = h1.x; hid[5] = h1.y; hid[6] = h1.z; hid[7] = h1.w;
      hid[8] = h2.x; hid[9] = h2.y; hid[10] = h2.z; hid[11] = h2.w;
      hid[12] = h3.x; hid[13] = h3.y; hid[14] = h3.z; hid[15] = h3.w;
    }
#pragma unroll
    for (int c = 0; c < 64; ++c) {
      float4 a0 = lw1[c][0], a1 = lw1[c][1], a2 = lw1[c][2], a3 = lw1[c][3];
      float d = dn[c];
      hid[0]  = fmaf(d, a0.x, hid[0]);  hid[1]  = fmaf(d, a0.y, hid[1]);
      hid[2]  = fmaf(d, a0.z, hid[2]);  hid[3]  = fmaf(d, a0.w, hid[3]);
      hid[4]  = fmaf(d, a1.x, hid[4]);  hid[5]  = fmaf(d, a1.y, hid[5]);
      hid[6]  = fmaf(d, a1.z, hid[6]);  hid[7]  = fmaf(d, a1.w, hid[7]);
      hid[8]  = fmaf(d, a2.x, hid[8]);  hid[9]  = fmaf(d, a2.y, hid[9]);
      hid[10] = fmaf(d, a2.z, hid[10]); hid[11] = fmaf(d, a2.w, hid[11]);
      hid[12] = fmaf(d, a3.x, hid[12]); hid[13] = fmaf(d, a3.y, hid[13]);
      hid[14] = fmaf(d, a3.z, hid[14]); hid[15] = fmaf(d, a3.w, hid[15]);
    }
#pragma unroll
    for (int j = 0; j < 16; ++j) hid[j] = hid[j] * sigmoidf_(hid[j]);
#pragma unroll
    for (int j = 0; j < 16; ++j) {
      float h = hid[j];
#pragma unroll
      for (int c4 = 0; c4 < 16; ++c4) {
        float4 w = lw2[j][c4];
        o2[4 * c4 + 0] = fmaf(h, w.x, o2[4 * c4 + 0]);
        o2[4 * c4 + 1] = fmaf(h, w.y, o2[4 * c4 + 1]);
        o2[4 * c4 + 2] = fmaf(h, w.z, o2[4 * c4 + 2]);
        o2[4 * c4 + 3] = fmaf(h, w.w, o2[4 * c4 + 3]);
      }
    }
  }

#pragma unroll
  for (int d = 0; d < 32; ++d) {
    int oi = (n * 32 + d) * 4096 + p;
    out[MAIN_RE + oi] += dec[d * PIX + g] + o2[d];
    out[MAIN_IM + oi] += dec[(32 + d) * PIX + g] + o2[32 + d];
  }
}

extern "C" void kernel_launch(void* const* d_in, const int* in_sizes, int n_in,
                              void* d_out, int out_size, void* d_ws, size_t ws_size,
                              hipStream_t stream) {
  (void)in_sizes; (void)n_in; (void)out_size; (void)ws_size;
  const float* xre      = (const float*)d_in[0];
  const float* xim      = (const float*)d_in[1];
  const float* hre      = (const float*)d_in[2];
  const float* him      = (const float*)d_in[3];
  const float* flux_re  = (const float*)d_in[4];
  const float* flux_im  = (const float*)d_in[5];
  const float* dt_seq   = (const float*)d_in[6];
  const float* ln_s_g   = (const float*)d_in[7];
  const float* ln_s_b   = (const float*)d_in[8];
  const float* conv_w   = (const float*)d_in[9];
  const float* conv_b   = (const float*)d_in[10];
  const float* ln_t_g   = (const float*)d_in[11];
  const float* ln_t_b   = (const float*)d_in[12];
  const float* W_re     = (const float*)d_in[13];
  const float* W_im     = (const float*)d_in[14];
  const float* lam_flux = (const float*)d_in[15];
  const float* bf_re    = (const float*)d_in[16];
  const float* bf_im    = (const float*)d_in[17];
  const float* c_re     = (const float*)d_in[18];
  const float* c_im     = (const float*)d_in[19];
  const float* g_w      = (const float*)d_in[20];
  const float* g_b      = (const float*)d_in[21];
  const float* a_decay  = (const float*)d_in[22];
  const float* b_freq   = (const float*)d_in[23];
  const float* ffn_w1   = (const float*)d_in[24];
  const float* ffn_b1   = (const float*)d_in[25];
  const float* ffn_w2   = (const float*)d_in[26];
  const float* ffn_b2   = (const float*)d_in[27];
  const float* sg_w1    = (const float*)d_in[28];
  const float* sg_b1    = (const float*)d_in[29];
  const float* sg_dw    = (const float*)d_in[30];
  const float* sg_w2    = (const float*)d_in[31];
  const float* sg_b2    = (const float*)d_in[32];
  float* out = (float*)d_out;
  float* ws  = (float*)d_ws;

  k_invert<<<1, 256, 0, stream>>>(W_re, W_im, ws);
  k_ln_s<<<PIX / 256, 256, 0, stream>>>(xre, xim, ln_s_g, ln_s_b, ws);
  k_conv<<<1536, 256, 0, stream>>>(ws + WS_XN, conv_w, conv_b, xre, xim, out);
  k_xeig<<<PIX / 256, 256, 0, stream>>>(out, W_re, W_im, ws + WS_XE);
  k_mean<<<dim3(NN, 64), 256, 0, stream>>>(ws + WS_XE, ws + WS_SUMS);
  k_flux<<<1, 64, 0, stream>>>(ws, out, dt_seq, flux_re, flux_im, lam_flux,
                               bf_re, bf_im, c_re, c_im, g_w, g_b, a_decay, b_freq);
  k_sg1<<<PIX / 256, 256, 0, stream>>>(ws + WS_XE, ws + WS_G1, sg_w1, sg_b1);
  k_sgdw<<<dim3(PIX / 256, 32), 256, 0, stream>>>(ws + WS_G1, ws + WS_G2, sg_dw);
  k_force<<<PIX / 256, 256, 0, stream>>>(ws + WS_G2, ws + WS_XE,
                                         ws + WS_GATE, ws + WS_SRCR, ws + WS_SRCI,
                                         ws + WS_OFR, ws + WS_OFI, ws + WS_ODR, ws + WS_ODI,
                                         hre, him, sg_w2, sg_b2);
  k_scan<<<dim3(4096 / 256, 32, 2), 256, 0, stream>>>(ws + WS_XE, ws + WS_ODR, ws + WS_ODI, out);
  k_dec<<<PIX / 256, 256, 0, stream>>>(ws + WS_XE, ws + WS_WINV, ws + WS_XN);
  k_final<<<PIX / 256, 256, 0, stream>>>(ws + WS_XN, out, ln_t_g, ln_t_b,
                                         ffn_w1, ffn_b1, ffn_w2, ffn_b2);
}

// Round 7
// 805.535 us; speedup vs baseline: 3.6464x; 1.2402x over previous
//
#include <hip/hip_runtime.h>
#include <math.h>

#define BB 2
#define TT 24
#define DD 32
#define HWp 4096            // 64*64
#define NN (BB*TT)          // 48
#define PIX (NN*HWp)        // 196608
#define C2 (2*DD)           // 64

// d_out offsets (floats)
#define MAIN_RE 0
#define MAIN_IM (NN*DD*HWp)              // 6291456
#define HOUT_RE (2*NN*DD*HWp)            // 12582912
#define HOUT_IM (HOUT_RE + BB*HWp*DD)    // 12845056
#define FLUX_RE (HOUT_RE + 2*BB*HWp*DD)  // 13107200
#define FLUX_IM (FLUX_RE + BB*DD)        // 13107264

// ws offsets (floats)
#define WS_XN   0                        // PIX*64
#define WS_XE   (WS_XN + PIX*C2)         // PIX*64
#define WS_G1   (WS_XE + PIX*C2)         // PIX*32  g1 planes
#define WS_G2   (WS_G1 + PIX*DD)         // PIX*32  g2 planes
#define WS_WINV (WS_G2 + PIX*DD)         // 2048 (re 1024, im 1024)
#define WS_SUMS (WS_WINV + 2048)         // 3072
#define WS_GATE (WS_SUMS + 3072)         // 1536
#define WS_SRCR (WS_GATE + 1536)
#define WS_SRCI (WS_SRCR + 1536)
#define WS_ODR  (WS_SRCI + 1536)
#define WS_ODI  (WS_ODR + 1536)
#define WS_OFR  (WS_ODI + 1536)
#define WS_OFI  (WS_OFR + 1536)

typedef __attribute__((ext_vector_type(8))) short bf16x8;
typedef __attribute__((ext_vector_type(4))) float f32x4;
union FU { unsigned u[4]; bf16x8 f; };

__device__ __forceinline__ float sigmoidf_(float x) { return 1.f / (1.f + expf(-x)); }
__device__ __forceinline__ float softplusf_(float x) { return log1pf(expf(x)); }
__device__ __forceinline__ unsigned short f2bf(float f) {
  unsigned u = __float_as_uint(f);
  return (unsigned short)((u + 0x7FFFu + ((u >> 16) & 1u)) >> 16);   // RNE
}
__device__ __forceinline__ unsigned pk2(float lo, float hi) {
  return (unsigned)f2bf(lo) | ((unsigned)f2bf(hi) << 16);
}

// ---------------- Gauss-Jordan inverse of Wb (32x32 complex), partial pivoting ----------------
__global__ void k_invert(const float* __restrict__ Wre, const float* __restrict__ Wim,
                         float* __restrict__ ws) {
  __shared__ float Mre[32][64];
  __shared__ float Mim[32][64];
  __shared__ float fre[32], fim[32];
  __shared__ float pr_s, pi_s;
  __shared__ int piv_s;
  int tid = threadIdx.x;  // 256 threads
  for (int idx = tid; idx < 2048; idx += 256) {
    int i = idx >> 6, j = idx & 63;
    if (j < 32) { Mre[i][j] = Wre[i * 32 + j]; Mim[i][j] = Wim[i * 32 + j]; }
    else        { Mre[i][j] = (j - 32 == i) ? 1.f : 0.f; Mim[i][j] = 0.f; }
  }
  __syncthreads();
  for (int k = 0; k < 32; ++k) {
    if (tid == 0) {
      int best = k; float bm = fabsf(Mre[k][k]) + fabsf(Mim[k][k]);
      for (int r = k + 1; r < 32; ++r) {
        float m = fabsf(Mre[r][k]) + fabsf(Mim[r][k]);
        if (m > bm) { bm = m; best = r; }
      }
      piv_s = best;
    }
    __syncthreads();
    int pv = piv_s;
    if (pv != k && tid < 64) {
      float tr = Mre[k][tid], ti = Mim[k][tid];
      Mre[k][tid] = Mre[pv][tid]; Mim[k][tid] = Mim[pv][tid];
      Mre[pv][tid] = tr; Mim[pv][tid] = ti;
    }
    __syncthreads();
    if (tid == 0) {
      float a = Mre[k][k], b = Mim[k][k];
      float d = a * a + b * b;
      pr_s = a / d; pi_s = -b / d;
    }
    __syncthreads();
    float pr = pr_s, pi = pi_s;
    if (tid < 64) {
      float a = Mre[k][tid], b = Mim[k][tid];
      Mre[k][tid] = a * pr - b * pi;
      Mim[k][tid] = a * pi + b * pr;
    }
    __syncthreads();
    if (tid < 32) { fre[tid] = Mre[tid][k]; fim[tid] = Mim[tid][k]; }
    __syncthreads();
    for (int idx = tid; idx < 2048; idx += 256) {
      int i = idx >> 6, j = idx & 63;
      if (i != k) {
        float fr = fre[i], fi = fim[i];
        float ar = Mre[k][j], ai = Mim[k][j];
        Mre[i][j] -= fr * ar - fi * ai;
        Mim[i][j] -= fr * ai + fi * ar;
      }
    }
    __syncthreads();
  }
  for (int idx = tid; idx < 1024; idx += 256) {
    int e = idx >> 5, d = idx & 31;
    ws[WS_WINV + e * 32 + d] = Mre[e][32 + d];
    ws[WS_WINV + 1024 + e * 32 + d] = Mim[e][32 + d];
  }
}

// ---------------- spatial LayerNorm over 64 (re,im) channels -> xn (NCHW) ----------------
__global__ void k_ln_s(const float* __restrict__ xre, const float* __restrict__ xim,
                       const float* __restrict__ g, const float* __restrict__ b,
                       float* __restrict__ ws) {
  int gid = blockIdx.x * 256 + threadIdx.x;
  if (gid >= PIX) return;
  int n = gid >> 12, p = gid & 4095;
  float v[64];
  float s = 0.f;
#pragma unroll
  for (int c = 0; c < 32; ++c) { v[c] = xre[(n * 32 + c) * 4096 + p]; s += v[c]; }
#pragma unroll
  for (int c = 0; c < 32; ++c) { v[32 + c] = xim[(n * 32 + c) * 4096 + p]; s += v[32 + c]; }
  float m = s * (1.f / 64.f);
  float vs = 0.f;
#pragma unroll
  for (int c = 0; c < 64; ++c) { float d = v[c] - m; vs += d * d; }
  float rs = rsqrtf(vs * (1.f / 64.f) + 1e-5f);
#pragma unroll
  for (int c = 0; c < 64; ++c)
    ws[WS_XN + (n * 64 + c) * 4096 + p] = (v[c] - m) * rs * g[c] + b[c];
}

// ---------------- 3x3 conv 64->64, LDS-tiled + register-blocked (16-row tiles) ----------------
__global__ void __launch_bounds__(256) k_conv(
    const float* __restrict__ xn, const float* __restrict__ wconv,
    const float* __restrict__ bconv,
    const float* __restrict__ xre, const float* __restrict__ xim,
    float* __restrict__ out) {
  __shared__ float in_lds[18][4][64];   // [local row][ci in chunk][col]
  int bid = blockIdx.x;
  int n = bid >> 5;
  int rem = bid & 31;
  int ocg = rem >> 2;         // 0..7 : oc = ocg*8 .. +7
  int yt = rem & 3;           // 0..3 : rows yt*16 .. +15
  int tid = threadIdx.x;
  int tx = tid & 63;          // col
  int rg = tid >> 6;          // 0..3 row group (4 rows each); also ci-lane for staging
  int y0 = yt * 16;
  int ybase = rg * 4;

  float acc[4][8];
#pragma unroll
  for (int r = 0; r < 4; ++r)
#pragma unroll
    for (int o = 0; o < 8; ++o) acc[r][o] = 0.f;

  const float* xnn = xn + n * 64 * 4096;

  for (int cc = 0; cc < 16; ++cc) {
    int ci0 = cc * 4;
    __syncthreads();
#pragma unroll
    for (int r = 0; r < 18; ++r) {
      int gy = y0 - 1 + r;
      float v = 0.f;
      if ((unsigned)gy < 64u) v = xnn[(ci0 + rg) * 4096 + gy * 64 + tx];
      in_lds[r][rg][tx] = v;
    }
    __syncthreads();

#pragma unroll
    for (int j = 0; j < 4; ++j) {
      float win[6][3];
#pragma unroll
      for (int rl = 0; rl < 6; ++rl) {
        const float* row = &in_lds[ybase + rl][j][0];
        win[rl][0] = (tx > 0) ? row[tx - 1] : 0.f;
        win[rl][1] = row[tx];
        win[rl][2] = (tx < 63) ? row[tx + 1] : 0.f;
      }
      int ci = ci0 + j;
#pragma unroll
      for (int o = 0; o < 8; ++o) {
        const float* wp = wconv + ((ocg * 8 + o) * 64 + ci) * 9;  // block-uniform -> s_load
        float w0 = wp[0], w1 = wp[1], w2 = wp[2];
        float w3 = wp[3], w4 = wp[4], w5 = wp[5];
        float w6 = wp[6], w7 = wp[7], w8 = wp[8];
#pragma unroll
        for (int r = 0; r < 4; ++r) {
          float s = acc[r][o];
          s = fmaf(win[r][0], w0, s);
          s = fmaf(win[r][1], w1, s);
          s = fmaf(win[r][2], w2, s);
          s = fmaf(win[r + 1][0], w3, s);
          s = fmaf(win[r + 1][1], w4, s);
          s = fmaf(win[r + 1][2], w5, s);
          s = fmaf(win[r + 2][0], w6, s);
          s = fmaf(win[r + 2][1], w7, s);
          s = fmaf(win[r + 2][2], w8, s);
          acc[r][o] = s;
        }
      }
    }
  }

#pragma unroll
  for (int o = 0; o < 8; ++o) {
    int oc = ocg * 8 + o;
    float bias = bconv[oc];
    int d = (oc < 32) ? oc : oc - 32;
    long base = ((oc < 32) ? (long)MAIN_RE : (long)MAIN_IM) + (long)(n * 32 + d) * 4096;
    const float* resid = (oc < 32) ? xre : xim;
#pragma unroll
    for (int r = 0; r < 4; ++r) {
      int p = (y0 + ybase + r) * 64 + tx;
      int oi = (n * 32 + d) * 4096 + p;
      out[base + p] = resid[oi] + acc[r][o] + bias;
    }
  }
}

// ---------------- x_eig: thread-per-pixel, write channel planes ----------------
__global__ void __launch_bounds__(256) k_xeig(
    const float* __restrict__ out, const float* __restrict__ Wre,
    const float* __restrict__ Wim, float* __restrict__ xe) {
  int g = blockIdx.x * 256 + threadIdx.x;
  int n = g >> 12, p = g & 4095;
  float xr[32], xi[32];
#pragma unroll
  for (int d = 0; d < 32; ++d) xr[d] = out[MAIN_RE + (n * 32 + d) * 4096 + p];
#pragma unroll
  for (int d = 0; d < 32; ++d) xi[d] = out[MAIN_IM + (n * 32 + d) * 4096 + p];
#pragma unroll
  for (int e0 = 0; e0 < 32; e0 += 4) {
    float ar[4] = {0.f, 0.f, 0.f, 0.f}, ai[4] = {0.f, 0.f, 0.f, 0.f};
#pragma unroll
    for (int d = 0; d < 32; ++d) {
      float r = xr[d], im = xi[d];
#pragma unroll
      for (int j = 0; j < 4; ++j) {
        float wr = Wre[d * 32 + e0 + j], wi = Wim[d * 32 + e0 + j];  // uniform -> s_load
        ar[j] += r * wr - im * wi;
        ai[j] += r * wi + im * wr;
      }
    }
#pragma unroll
    for (int j = 0; j < 4; ++j) {
      xe[(e0 + j) * PIX + g] = ar[j];
      xe[(32 + e0 + j) * PIX + g] = ai[j];
    }
  }
}

// ---------------- spatial sums of xe planes per (n, channel) ----------------
__global__ void k_mean(const float* __restrict__ xe, float* __restrict__ sums) {
  __shared__ float red[256];
  int n = blockIdx.x, c = blockIdx.y;
  int tid = threadIdx.x;
  const float* src = xe + c * PIX + n * 4096;
  float s = 0.f;
#pragma unroll
  for (int i = 0; i < 16; ++i) s += src[tid + i * 256];
  red[tid] = s;
  __syncthreads();
  for (int w = 128; w > 0; w >>= 1) {
    if (tid < w) red[tid] += red[tid + w];
    __syncthreads();
  }
  if (tid == 0) sums[n * 64 + c] = red[0];
}

// ---------------- flux scan (T=24) + all per-(b,t,d) coefficients ----------------
__global__ void k_flux(float* __restrict__ ws, float* __restrict__ out,
                       const float* __restrict__ dt_seq,
                       const float* __restrict__ flux_re, const float* __restrict__ flux_im,
                       const float* __restrict__ lam_flux,
                       const float* __restrict__ bf_re, const float* __restrict__ bf_im,
                       const float* __restrict__ c_re, const float* __restrict__ c_im,
                       const float* __restrict__ g_w, const float* __restrict__ g_b,
                       const float* __restrict__ a_decay, const float* __restrict__ b_freq) {
  int tid = threadIdx.x;
  if (tid >= 64) return;
  int b = tid >> 5, e = tid & 31;
  float sp_lf = softplusf_(lam_flux[e]);
  float lr = -softplusf_(a_decay[e]);
  float li = b_freq[e];
  float den = lr * lr + li * li;
  float bfr = bf_re[e], bfi = bf_im[e];
  float cr = c_re[e], ci = c_im[e];
  float fr = flux_re[b * 32 + e], fi = flux_im[b * 32 + e];
  for (int t = 0; t < 24; ++t) {
    int n = b * 24 + t;
    float dt = dt_seq[n];
    float A = expf(-sp_lf * dt);
    float xmr = ws[WS_SUMS + n * 64 + e] * (1.f / 4096.f);
    float xmi = ws[WS_SUMS + n * 64 + 32 + e] * (1.f / 4096.f);
    float Xr = (bfr * xmr - bfi * xmi) * dt;
    float Xi = (bfr * xmi + bfi * xmr) * dt;
    fr = A * fr + Xr;
    fi = A * fi + Xi;
    ws[WS_GATE + n * 32 + e] = sigmoidf_(fr * g_w[e] + g_b[e]);
    ws[WS_SRCR + n * 32 + e] = fr * cr - fi * ci;
    ws[WS_SRCI + n * 32 + e] = fr * ci + fi * cr;
    float er = expf(lr * dt);
    float odr = er * cosf(li * dt);
    float odi = er * sinf(li * dt);
    ws[WS_ODR + n * 32 + e] = odr;
    ws[WS_ODI + n * 32 + e] = odi;
    float nr = odr - 1.f, ni = odi;
    ws[WS_OFR + n * 32 + e] = (nr * lr + ni * li) / den;
    ws[WS_OFI + n * 32 + e] = (ni * lr - nr * li) / den;
  }
  out[FLUX_RE + b * 32 + e] = fr;
  out[FLUX_IM + b * 32 + e] = fi;
}

// ---------------- spatial gate 1: 1x1 conv 64->32 + silu, thread-per-pixel ----------------
__global__ void __launch_bounds__(256) k_sg1(
    const float* __restrict__ xe, float* __restrict__ g1,
    const float* __restrict__ w1, const float* __restrict__ b1) {
  int g = blockIdx.x * 256 + threadIdx.x;
  float v[64];
#pragma unroll
  for (int c = 0; c < 64; ++c) v[c] = xe[c * PIX + g];
#pragma unroll
  for (int o0 = 0; o0 < 32; o0 += 4) {
    float acc[4] = {b1[o0], b1[o0 + 1], b1[o0 + 2], b1[o0 + 3]};
#pragma unroll
    for (int c = 0; c < 64; ++c) {
#pragma unroll
      for (int j = 0; j < 4; ++j)
        acc[j] = fmaf(v[c], w1[(o0 + j) * 64 + c], acc[j]);   // uniform -> s_load
    }
#pragma unroll
    for (int j = 0; j < 4; ++j)
      g1[(o0 + j) * PIX + g] = acc[j] * sigmoidf_(acc[j]);
  }
}

// ---------------- spatial gate 2: depthwise 3x3 on planes ----------------
__global__ void __launch_bounds__(256) k_sgdw(
    const float* __restrict__ g1, float* __restrict__ g2, const float* __restrict__ dw) {
  int g = blockIdx.x * 256 + threadIdx.x;
  int oc = blockIdx.y;                  // block-uniform
  int n = g >> 12, p = g & 4095;
  int y = p >> 6, x = p & 63;
  const float* src = g1 + oc * PIX + n * 4096;
  const float* w = dw + oc * 9;         // uniform -> s_load
  float acc = 0.f;
#pragma unroll
  for (int ky = 0; ky < 3; ++ky) {
    int yy = y + ky - 1;
    if ((unsigned)yy < 64u) {
#pragma unroll
      for (int kx = 0; kx < 3; ++kx) {
        int xx = x + kx - 1;
        if ((unsigned)xx < 64u)
          acc = fmaf(src[yy * 64 + xx], w[ky * 3 + kx], acc);
      }
    }
  }
  g2[oc * PIX + g] = acc;
}

// ---------------- sg3 (1x1 32->32 + sigmoid) fused with forcing -> u_t ----------------
__global__ void __launch_bounds__(256) k_force(
    const float* __restrict__ g2p, float* __restrict__ xe,
    const float* __restrict__ gate, const float* __restrict__ srcr,
    const float* __restrict__ srci, const float* __restrict__ ofr_p,
    const float* __restrict__ ofi_p, const float* __restrict__ odr_p,
    const float* __restrict__ odi_p,
    const float* __restrict__ hre, const float* __restrict__ him,
    const float* __restrict__ w2, const float* __restrict__ b2) {
  int g = blockIdx.x * 256 + threadIdx.x;
  int n = g >> 12, p = g & 4095;
  int b = (n >= 24) ? 1 : 0;
  int t = n - b * 24;
  float v[32];
#pragma unroll
  for (int c = 0; c < 32; ++c) v[c] = g2p[c * PIX + g];
  float spg[32];
#pragma unroll
  for (int o0 = 0; o0 < 32; o0 += 4) {
    float acc[4] = {b2[o0], b2[o0 + 1], b2[o0 + 2], b2[o0 + 3]};
#pragma unroll
    for (int c = 0; c < 32; ++c) {
#pragma unroll
      for (int j = 0; j < 4; ++j)
        acc[j] = fmaf(v[c], w2[(o0 + j) * 32 + c], acc[j]);   // uniform -> s_load
    }
#pragma unroll
    for (int j = 0; j < 4; ++j) spg[o0 + j] = sigmoidf_(acc[j]);
  }
#pragma unroll
  for (int e = 0; e < 32; ++e) {
    int ie = n * 32 + e;
    float gc = gate[ie] * spg[e];
    float xr = xe[e * PIX + g];
    float xi = xe[(32 + e) * PIX + g];
    float om = 1.f - gc;
    float fr2 = xr * gc + srcr[ie] * om;
    float fi2 = xi * gc + srci[ie] * om;
    float ofr = ofr_p[ie], ofi = ofi_p[ie];
    float ur = fr2 * ofr - fi2 * ofi;
    float ui = fr2 * ofi + fi2 * ofr;
    if (t == 0) {                       // wave-uniform branch
      int hb = (b * 4096 + p) * 32 + e;
      float hr = hre[hb], hi = him[hb];
      float odr = odr_p[(b * 24) * 32 + e], odi = odi_p[(b * 24) * 32 + e];
      ur += hr * odr - hi * odi;
      ui += hr * odi + hi * odr;
    }
    xe[e * PIX + g] = ur;
    xe[(32 + e) * PIX + g] = ui;
  }
}

// ---------------- temporal scan over T=24 on planes (in place), emit h_out ----------------
__global__ void __launch_bounds__(256) k_scan(
    float* __restrict__ u, const float* __restrict__ odr_p,
    const float* __restrict__ odi_p, float* __restrict__ out) {
  int p = blockIdx.x * 256 + threadIdx.x;   // 0..4095
  int e = blockIdx.y;                        // 0..31 (block-uniform)
  int b = blockIdx.z;                        // 0..1
  float ur = 0.f, ui = 0.f;
  for (int t = 0; t < 24; ++t) {
    int n = b * 24 + t;
    int idx  = e * PIX + n * 4096 + p;
    int idxi = (32 + e) * PIX + n * 4096 + p;
    float ar = odr_p[n * 32 + e];            // uniform -> s_load
    float ai = odi_p[n * 32 + e];
    float xr = u[idx], xi = u[idxi];
    float nr = ar * ur - ai * ui + xr;
    float ni = ar * ui + ai * ur + xi;
    ur = nr; ui = ni;
    u[idx] = ur;
    u[idxi] = ui;
  }
  out[HOUT_RE + (b * 4096 + p) * 32 + e] = ur;
  out[HOUT_IM + (b * 4096 + p) * 32 + e] = ui;
}

// ---------------- dec = u_out @ Wb_inv : thread-per-pixel, planes -> planes ----------------
__global__ void __launch_bounds__(256) k_dec(
    const float* __restrict__ u, const float* __restrict__ winv,
    float* __restrict__ dec) {
  int g = blockIdx.x * 256 + threadIdx.x;
  float ur[32], ui[32];
#pragma unroll
  for (int e = 0; e < 32; ++e) ur[e] = u[e * PIX + g];
#pragma unroll
  for (int e = 0; e < 32; ++e) ui[e] = u[(32 + e) * PIX + g];
#pragma unroll
  for (int d0 = 0; d0 < 32; d0 += 4) {
    float ar[4] = {0.f, 0.f, 0.f, 0.f}, ai[4] = {0.f, 0.f, 0.f, 0.f};
#pragma unroll
    for (int e = 0; e < 32; ++e) {
      float r = ur[e], im = ui[e];
#pragma unroll
      for (int j = 0; j < 4; ++j) {
        float wr = winv[e * 32 + d0 + j];         // uniform -> s_load
        float wi = winv[1024 + e * 32 + d0 + j];
        ar[j] += r * wr - im * wi;
        ai[j] += r * wi + im * wr;
      }
    }
#pragma unroll
    for (int j = 0; j < 4; ++j) {
      dec[(d0 + j) * PIX + g] = ar[j];
      dec[(32 + d0 + j) * PIX + g] = ai[j];
    }
  }
}

// ---------------- LN_t + FFN (64->128->64) via bf16 MFMA + z = x_upd + dec + delta ----------
// 4 phases x 64 pixels; wave w owns pixel-tile w (16 pix). Weights staged once as bf16-pair
// LDS transposes; hid staged bf16; o2 staged f32 (overlaid on hid, same 264B row stride).
// NOTE: hid_o2 is written as ushort (hidb) then read as unsigned (a2) — cross-type LDS
// reuse REQUIRES the __syncthreads() fence between them (TBAA would otherwise allow the
// read to bypass the write -> garbage/NaN; round-6 failure).
__global__ void __launch_bounds__(256) k_final(
    const float* __restrict__ dec, float* __restrict__ out,
    const float* __restrict__ lg, const float* __restrict__ lb,
    const float* __restrict__ w1, const float* __restrict__ b1,
    const float* __restrict__ w2, const float* __restrict__ b2) {
  __shared__ unsigned w1T[128][33];   // [hid][c-pair]  bf16x2, +1 pad
  __shared__ unsigned w2T[64][65];    // [out][h-pair]  bf16x2, +1 pad
  __shared__ unsigned dnp[64][33];    // [pix][c-pair]  bf16x2
  __shared__ unsigned hid_o2[64][66]; // union: ushort[64][132] hid bf16  /  float[64][66] o2

  int tid = threadIdx.x;
  int gbase = blockIdx.x * 256;
  int l = tid & 63, wv = tid >> 6;
  int l15 = l & 15, l4 = l >> 4;

  // ---- stage w1^T, w2^T as bf16 pairs (once per block) ----
  {
    int hid = tid & 127, half = tid >> 7;
#pragma unroll
    for (int i = 0; i < 16; ++i) {
      int cp = half * 16 + i;
      w1T[hid][cp] = pk2(w1[(2 * cp) * 128 + hid], w1[(2 * cp + 1) * 128 + hid]);
    }
    int o = tid & 63, q = tid >> 6;
#pragma unroll
    for (int i = 0; i < 16; ++i) {
      int hp = q * 16 + i;
      w2T[o][hp] = pk2(w2[(2 * hp) * 64 + o], w2[(2 * hp + 1) * 64 + o]);
    }
  }
  // biases per lane (fragment column = l&15)
  float bb1v[8], bb2v[4];
#pragma unroll
  for (int Hn = 0; Hn < 8; ++Hn) bb1v[Hn] = b1[Hn * 16 + l15];
#pragma unroll
  for (int On = 0; On < 4; ++On) bb2v[On] = b2[On * 16 + l15];
  __syncthreads();

  for (int ph = 0; ph < 4; ++ph) {
    int bp = ph * 64;

    // ---- LN for this phase's 64 pixels (threads 0..63) ----
    if (tid < 64) {
      int gg = gbase + bp + tid;
      float dn[64];
      float s = 0.f;
#pragma unroll
      for (int c = 0; c < 64; ++c) { dn[c] = dec[c * PIX + gg]; s += dn[c]; }
      float m = s * (1.f / 64.f);
      float vs = 0.f;
#pragma unroll
      for (int c = 0; c < 64; ++c) { float d = dn[c] - m; vs += d * d; }
      float rs = rsqrtf(vs * (1.f / 64.f) + 1e-5f);
#pragma unroll
      for (int c = 0; c < 64; ++c) dn[c] = (dn[c] - m) * rs * lg[c] + lb[c];
#pragma unroll
      for (int cp = 0; cp < 32; ++cp)
        dnp[tid][cp] = pk2(dn[2 * cp], dn[2 * cp + 1]);
    }
    __syncthreads();

    // ---- layer 1: per wave, its 16-pixel tile ----
    int arow = wv * 16 + l15;
    FU a0, a1;
#pragma unroll
    for (int jj = 0; jj < 4; ++jj) {
      a0.u[jj] = dnp[arow][l4 * 4 + jj];
      a1.u[jj] = dnp[arow][16 + l4 * 4 + jj];
    }
    f32x4 acc[8];
#pragma unroll
    for (int Hn = 0; Hn < 8; ++Hn) {
      float bb = bb1v[Hn];
      acc[Hn] = (f32x4){bb, bb, bb, bb};
      FU b0f, b1f;
      int brow = Hn * 16 + l15;
#pragma unroll
      for (int jj = 0; jj < 4; ++jj) {
        b0f.u[jj] = w1T[brow][l4 * 4 + jj];
        b1f.u[jj] = w1T[brow][16 + l4 * 4 + jj];
      }
      acc[Hn] = __builtin_amdgcn_mfma_f32_16x16x32_bf16(a0.f, b0f.f, acc[Hn], 0, 0, 0);
      acc[Hn] = __builtin_amdgcn_mfma_f32_16x16x32_bf16(a1.f, b1f.f, acc[Hn], 0, 0, 0);
    }
    // silu -> bf16 hid staging (rows owned by this wave)
    unsigned short (*hidb)[132] = (unsigned short(*)[132])hid_o2;
#pragma unroll
    for (int Hn = 0; Hn < 8; ++Hn) {
#pragma unroll
      for (int r = 0; r < 4; ++r) {
        float v = acc[Hn][r];
        v = v * sigmoidf_(v);
        hidb[wv * 16 + l4 * 4 + r][Hn * 16 + l15] = f2bf(v);
      }
    }
    __syncthreads();   // FENCE: ushort hid stores must complete before unsigned a2 loads

    // ---- layer 2 ----
    FU a2[4];
#pragma unroll
    for (int kk = 0; kk < 4; ++kk)
#pragma unroll
      for (int jj = 0; jj < 4; ++jj)
        a2[kk].u[jj] = ((unsigned(*)[66])hid_o2)[arow][kk * 16 + l4 * 4 + jj];
    f32x4 acc2[4];
#pragma unroll
    for (int On = 0; On < 4; ++On) {
      float bb = bb2v[On];
      acc2[On] = (f32x4){bb, bb, bb, bb};
#pragma unroll
      for (int kk = 0; kk < 4; ++kk) {
        FU b2f;
#pragma unroll
        for (int jj = 0; jj < 4; ++jj)
          b2f.u[jj] = w2T[On * 16 + l15][kk * 16 + l4 * 4 + jj];
        acc2[On] = __builtin_amdgcn_mfma_f32_16x16x32_bf16(a2[kk].f, b2f.f, acc2[On], 0, 0, 0);
      }
    }
    // o2 f32 staging (same rows / same 264B stride as hidb -> per-wave ownership)
    float (*o2f)[66] = (float(*)[66])hid_o2;
#pragma unroll
    for (int On = 0; On < 4; ++On)
#pragma unroll
      for (int r = 0; r < 4; ++r)
        o2f[wv * 16 + l4 * 4 + r][On * 16 + l15] = acc2[On][r];
    __syncthreads();

    // ---- epilogue: all 256 threads; thread t -> pixel t&63, channel quarter t>>6 ----
    {
      int p = tid & 63, cq = tid >> 6;
      int gg = gbase + bp + p;
      int nn = gg >> 12, pim = gg & 4095;
#pragma unroll
      for (int i = 0; i < 16; ++i) {
        int c = cq * 16 + i;
        float val = o2f[p][c] + dec[c * PIX + gg];
        int d = c & 31;
        long off = ((c < 32) ? (long)MAIN_RE : (long)MAIN_IM) + (long)(nn * 32 + d) * 4096 + pim;
        out[off] += val;
      }
    }
    __syncthreads();   // protect dnp/hid_o2 reuse next phase
  }
}

extern "C" void kernel_launch(void* const* d_in, const int* in_sizes, int n_in,
                              void* d_out, int out_size, void* d_ws, size_t ws_size,
                              hipStream_t stream) {
  (void)in_sizes; (void)n_in; (void)out_size; (void)ws_size;
  const float* xre      = (const float*)d_in[0];
  const float* xim      = (const float*)d_in[1];
  const float* hre      = (const float*)d_in[2];
  const float* him      = (const float*)d_in[3];
  const float* flux_re  = (const float*)d_in[4];
  const float* flux_im  = (const float*)d_in[5];
  const float* dt_seq   = (const float*)d_in[6];
  const float* ln_s_g   = (const float*)d_in[7];
  const float* ln_s_b   = (const float*)d_in[8];
  const float* conv_w   = (const float*)d_in[9];
  const float* conv_b   = (const float*)d_in[10];
  const float* ln_t_g   = (const float*)d_in[11];
  const float* ln_t_b   = (const float*)d_in[12];
  const float* W_re     = (const float*)d_in[13];
  const float* W_im     = (const float*)d_in[14];
  const float* lam_flux = (const float*)d_in[15];
  const float* bf_re    = (const float*)d_in[16];
  const float* bf_im    = (const float*)d_in[17];
  const float* c_re     = (const float*)d_in[18];
  const float* c_im     = (const float*)d_in[19];
  const float* g_w      = (const float*)d_in[20];
  const float* g_b      = (const float*)d_in[21];
  const float* a_decay  = (const float*)d_in[22];
  const float* b_freq   = (const float*)d_in[23];
  const float* ffn_w1   = (const float*)d_in[24];
  const float* ffn_b1   = (const float*)d_in[25];
  const float* ffn_w2   = (const float*)d_in[26];
  const float* ffn_b2   = (const float*)d_in[27];
  const float* sg_w1    = (const float*)d_in[28];
  const float* sg_b1    = (const float*)d_in[29];
  const float* sg_dw    = (const float*)d_in[30];
  const float* sg_w2    = (const float*)d_in[31];
  const float* sg_b2    = (const float*)d_in[32];
  float* out = (float*)d_out;
  float* ws  = (float*)d_ws;

  k_invert<<<1, 256, 0, stream>>>(W_re, W_im, ws);
  k_ln_s<<<PIX / 256, 256, 0, stream>>>(xre, xim, ln_s_g, ln_s_b, ws);
  k_conv<<<1536, 256, 0, stream>>>(ws + WS_XN, conv_w, conv_b, xre, xim, out);
  k_xeig<<<PIX / 256, 256, 0, stream>>>(out, W_re, W_im, ws + WS_XE);
  k_mean<<<dim3(NN, 64), 256, 0, stream>>>(ws + WS_XE, ws + WS_SUMS);
  k_flux<<<1, 64, 0, stream>>>(ws, out, dt_seq, flux_re, flux_im, lam_flux,
                               bf_re, bf_im, c_re, c_im, g_w, g_b, a_decay, b_freq);
  k_sg1<<<PIX / 256, 256, 0, stream>>>(ws + WS_XE, ws + WS_G1, sg_w1, sg_b1);
  k_sgdw<<<dim3(PIX / 256, 32), 256, 0, stream>>>(ws + WS_G1, ws + WS_G2, sg_dw);
  k_force<<<PIX / 256, 256, 0, stream>>>(ws + WS_G2, ws + WS_XE,
                                         ws + WS_GATE, ws + WS_SRCR, ws + WS_SRCI,
                                         ws + WS_OFR, ws + WS_OFI, ws + WS_ODR, ws + WS_ODI,
                                         hre, him, sg_w2, sg_b2);
  k_scan<<<dim3(4096 / 256, 32, 2), 256, 0, stream>>>(ws + WS_XE, ws + WS_ODR, ws + WS_ODI, out);
  k_dec<<<PIX / 256, 256, 0, stream>>>(ws + WS_XE, ws + WS_WINV, ws + WS_XN);
  k_final<<<PIX / 256, 256, 0, stream>>>(ws + WS_XN, out, ln_t_g, ln_t_b,
                                         ffn_w1, ffn_b1, ffn_w2, ffn_b2);
}

// Round 8
// 579.602 us; speedup vs baseline: 5.0678x; 1.3898x over previous
//
#include <hip/hip_runtime.h>
#include <math.h>

#define BB 2
#define TT 24
#define DD 32
#define HWp 4096            // 64*64
#define NN (BB*TT)          // 48
#define PIX (NN*HWp)        // 196608
#define C2 (2*DD)           // 64

// d_out offsets (floats)
#define MAIN_RE 0
#define MAIN_IM (NN*DD*HWp)              // 6291456
#define HOUT_RE (2*NN*DD*HWp)            // 12582912
#define HOUT_IM (HOUT_RE + BB*HWp*DD)    // 12845056
#define FLUX_RE (HOUT_RE + 2*BB*HWp*DD)  // 13107200
#define FLUX_IM (FLUX_RE + BB*DD)        // 13107264

// ws offsets (floats)
// WS_XN: first 25MB used as bf16 channels-last xn [n][pix][64] for k_conv;
//        later reused as dec planes (c*PIX + g) f32.
#define WS_XN   0                        // PIX*64
#define WS_XE   (WS_XN + PIX*C2)         // PIX*64
#define WS_G1   (WS_XE + PIX*C2)         // PIX*32  g1 planes
#define WS_G2   (WS_G1 + PIX*DD)         // PIX*32  g2 planes
#define WS_WINV (WS_G2 + PIX*DD)         // 2048 (re 1024, im 1024)
#define WS_SUMS (WS_WINV + 2048)         // 3072
#define WS_GATE (WS_SUMS + 3072)         // 1536
#define WS_SRCR (WS_GATE + 1536)
#define WS_SRCI (WS_SRCR + 1536)
#define WS_ODR  (WS_SRCI + 1536)
#define WS_ODI  (WS_ODR + 1536)
#define WS_OFR  (WS_ODI + 1536)
#define WS_OFI  (WS_OFR + 1536)
#define WS_WPK  (WS_OFI + 1536)          // 36864 ushorts = 18432 floats

typedef __attribute__((ext_vector_type(8))) short bf16x8;
typedef __attribute__((ext_vector_type(4))) float f32x4;
union FU { unsigned u[4]; bf16x8 f; };
union FU4 { uint4 v; unsigned u[4]; bf16x8 f; };

__device__ __forceinline__ float sigmoidf_(float x) { return 1.f / (1.f + expf(-x)); }
__device__ __forceinline__ float softplusf_(float x) { return log1pf(expf(x)); }
__device__ __forceinline__ unsigned short f2bf(float f) {
  unsigned u = __float_as_uint(f);
  return (unsigned short)((u + 0x7FFFu + ((u >> 16) & 1u)) >> 16);   // RNE
}
__device__ __forceinline__ unsigned pk2(float lo, float hi) {
  return (unsigned)f2bf(lo) | ((unsigned)f2bf(hi) << 16);
}

// ---------------- Gauss-Jordan inverse of Wb (32x32 complex), partial pivoting ----------------
__global__ void k_invert(const float* __restrict__ Wre, const float* __restrict__ Wim,
                         float* __restrict__ ws) {
  __shared__ float Mre[32][64];
  __shared__ float Mim[32][64];
  __shared__ float fre[32], fim[32];
  __shared__ float pr_s, pi_s;
  __shared__ int piv_s;
  int tid = threadIdx.x;  // 256 threads
  for (int idx = tid; idx < 2048; idx += 256) {
    int i = idx >> 6, j = idx & 63;
    if (j < 32) { Mre[i][j] = Wre[i * 32 + j]; Mim[i][j] = Wim[i * 32 + j]; }
    else        { Mre[i][j] = (j - 32 == i) ? 1.f : 0.f; Mim[i][j] = 0.f; }
  }
  __syncthreads();
  for (int k = 0; k < 32; ++k) {
    if (tid == 0) {
      int best = k; float bm = fabsf(Mre[k][k]) + fabsf(Mim[k][k]);
      for (int r = k + 1; r < 32; ++r) {
        float m = fabsf(Mre[r][k]) + fabsf(Mim[r][k]);
        if (m > bm) { bm = m; best = r; }
      }
      piv_s = best;
    }
    __syncthreads();
    int pv = piv_s;
    if (pv != k && tid < 64) {
      float tr = Mre[k][tid], ti = Mim[k][tid];
      Mre[k][tid] = Mre[pv][tid]; Mim[k][tid] = Mim[pv][tid];
      Mre[pv][tid] = tr; Mim[pv][tid] = ti;
    }
    __syncthreads();
    if (tid == 0) {
      float a = Mre[k][k], b = Mim[k][k];
      float d = a * a + b * b;
      pr_s = a / d; pi_s = -b / d;
    }
    __syncthreads();
    float pr = pr_s, pi = pi_s;
    if (tid < 64) {
      float a = Mre[k][tid], b = Mim[k][tid];
      Mre[k][tid] = a * pr - b * pi;
      Mim[k][tid] = a * pi + b * pr;
    }
    __syncthreads();
    if (tid < 32) { fre[tid] = Mre[tid][k]; fim[tid] = Mim[tid][k]; }
    __syncthreads();
    for (int idx = tid; idx < 2048; idx += 256) {
      int i = idx >> 6, j = idx & 63;
      if (i != k) {
        float fr = fre[i], fi = fim[i];
        float ar = Mre[k][j], ai = Mim[k][j];
        Mre[i][j] -= fr * ar - fi * ai;
        Mim[i][j] -= fr * ai + fi * ar;
      }
    }
    __syncthreads();
  }
  for (int idx = tid; idx < 1024; idx += 256) {
    int e = idx >> 5, d = idx & 31;
    ws[WS_WINV + e * 32 + d] = Mre[e][32 + d];
    ws[WS_WINV + 1024 + e * 32 + d] = Mim[e][32 + d];
  }
}

// ---------------- weight pre-pack: wpack[tap][oc][ci] bf16 <- conv_w[oc][ci][tap] f32 ----
__global__ void k_wprep(const float* __restrict__ w, unsigned short* __restrict__ wpk) {
  int idx = blockIdx.x * 256 + threadIdx.x;
  if (idx >= 9 * 64 * 64) return;
  int tap = idx >> 12;
  int rem = idx & 4095;
  int oc = rem >> 6, ci = rem & 63;
  wpk[idx] = f2bf(w[(oc * 64 + ci) * 9 + tap]);
}

// ---------------- spatial LayerNorm -> xn bf16 channels-last [n][pix][64] ----------------
__global__ void k_ln_s(const float* __restrict__ xre, const float* __restrict__ xim,
                       const float* __restrict__ g, const float* __restrict__ b,
                       float* __restrict__ ws) {
  int gid = blockIdx.x * 256 + threadIdx.x;
  if (gid >= PIX) return;
  int n = gid >> 12, p = gid & 4095;
  float v[64];
  float s = 0.f;
#pragma unroll
  for (int c = 0; c < 32; ++c) { v[c] = xre[(n * 32 + c) * 4096 + p]; s += v[c]; }
#pragma unroll
  for (int c = 0; c < 32; ++c) { v[32 + c] = xim[(n * 32 + c) * 4096 + p]; s += v[32 + c]; }
  float m = s * (1.f / 64.f);
  float vs = 0.f;
#pragma unroll
  for (int c = 0; c < 64; ++c) { float d = v[c] - m; vs += d * d; }
  float rs = rsqrtf(vs * (1.f / 64.f) + 1e-5f);
#pragma unroll
  for (int c = 0; c < 64; ++c) v[c] = (v[c] - m) * rs * g[c] + b[c];
  uint4* dst = (uint4*)ws + gid * 8;   // xnb at WS_XN, 128B per pixel
#pragma unroll
  for (int q = 0; q < 8; ++q) {
    uint4 u;
    u.x = pk2(v[q * 8 + 0], v[q * 8 + 1]);
    u.y = pk2(v[q * 8 + 2], v[q * 8 + 3]);
    u.z = pk2(v[q * 8 + 4], v[q * 8 + 5]);
    u.w = pk2(v[q * 8 + 6], v[q * 8 + 7]);
    dst[q] = u;
  }
}

// ---------------- 3x3 conv 64->64 as 9 shifted bf16 MFMA GEMMs ----------------
// block = (n, 4-row strip). LDS: 6x66 haloed pixels x 72-pad ci bf16 (57KB, zeroed halo).
// wave wv owns output row y0+wv; 4 Mtiles (16 cols) x 4 Ntiles (16 oc); K = 9 taps x 64 ci.
__global__ void __launch_bounds__(256) k_conv(
    const unsigned* __restrict__ xnb_u, const unsigned short* __restrict__ wpk,
    const float* __restrict__ bconv,
    const float* __restrict__ xre, const float* __restrict__ xim,
    float* __restrict__ out) {
  __shared__ unsigned xls[6 * 66 * 36];   // 36 dwords (=72 bf16) per pixel, ci 0..63 valid
  int bid = blockIdx.x;
  int n = bid >> 4;
  int y0 = (bid & 15) * 4;
  int tid = threadIdx.x;
  int wv = tid >> 6, l = tid & 63;
  int l15 = l & 15, l4 = l >> 4;

  // ---- stage 6x66 pixels x 64 ci (zero halo) ----
  const uint4* xnb4 = (const uint4*)xnb_u;
  for (int idx = tid; idx < 396; idx += 256) {
    int r = idx / 66, c = idx - r * 66;
    int y = y0 - 1 + r, x = c - 1;
    bool valid = ((unsigned)y < 64u) & ((unsigned)x < 64u);
    int pg = n * 4096 + y * 64 + x;
    uint4 z; z.x = z.y = z.z = z.w = 0u;
#pragma unroll
    for (int q = 0; q < 8; ++q) {
      uint4 v = valid ? xnb4[pg * 8 + q] : z;
      *(uint4*)&xls[idx * 36 + q * 4] = v;
    }
  }
  __syncthreads();

  // ---- accumulators init with bias (C col = oc = Nt*16+l15) ----
  f32x4 acc[4][4];
#pragma unroll
  for (int Nt = 0; Nt < 4; ++Nt) {
    float bb = bconv[Nt * 16 + l15];
#pragma unroll
    for (int mt = 0; mt < 4; ++mt) acc[mt][Nt] = (f32x4){bb, bb, bb, bb};
  }

  const uint4* wq = (const uint4*)wpk;   // uint4 idx = tap*512 + oc*8 + ks*4 + l4
#pragma unroll
  for (int tap = 0; tap < 9; ++tap) {
    int ky = tap / 3, kx = tap - ky * 3;
    int rowbase = (wv + ky) * 66 + kx + l15;
#pragma unroll
    for (int ks = 0; ks < 2; ++ks) {
      FU4 B[4];
#pragma unroll
      for (int Nt = 0; Nt < 4; ++Nt)
        B[Nt].v = wq[tap * 512 + (Nt * 16 + l15) * 8 + ks * 4 + l4];
#pragma unroll
      for (int mt = 0; mt < 4; ++mt) {
        FU4 A;
        A.v = *(const uint4*)&xls[(rowbase + mt * 16) * 36 + ks * 16 + l4 * 4];
#pragma unroll
        for (int Nt = 0; Nt < 4; ++Nt)
          acc[mt][Nt] = __builtin_amdgcn_mfma_f32_16x16x32_bf16(A.f, B[Nt].f, acc[mt][Nt], 0, 0, 0);
      }
    }
  }

  // ---- epilogue: out = resid + acc (+bias already in acc) ----
#pragma unroll
  for (int Nt = 0; Nt < 4; ++Nt) {
    int oc = Nt * 16 + l15;
    int d = oc & 31;
    const float* resid = (oc < 32) ? xre : xim;
    float* dst = out + ((oc < 32) ? MAIN_RE : MAIN_IM) + (n * 32 + d) * 4096;
    const float* rsd = resid + (n * 32 + d) * 4096;
#pragma unroll
    for (int mt = 0; mt < 4; ++mt) {
      int pixbase = (y0 + wv) * 64 + mt * 16 + l4 * 4;
#pragma unroll
      for (int r = 0; r < 4; ++r)
        dst[pixbase + r] = rsd[pixbase + r] + acc[mt][Nt][r];
    }
  }
}

// ---------------- x_eig: thread-per-pixel, write channel planes ----------------
__global__ void __launch_bounds__(256) k_xeig(
    const float* __restrict__ out, const float* __restrict__ Wre,
    const float* __restrict__ Wim, float* __restrict__ xe) {
  int g = blockIdx.x * 256 + threadIdx.x;
  int n = g >> 12, p = g & 4095;
  float xr[32], xi[32];
#pragma unroll
  for (int d = 0; d < 32; ++d) xr[d] = out[MAIN_RE + (n * 32 + d) * 4096 + p];
#pragma unroll
  for (int d = 0; d < 32; ++d) xi[d] = out[MAIN_IM + (n * 32 + d) * 4096 + p];
#pragma unroll
  for (int e0 = 0; e0 < 32; e0 += 4) {
    float ar[4] = {0.f, 0.f, 0.f, 0.f}, ai[4] = {0.f, 0.f, 0.f, 0.f};
#pragma unroll
    for (int d = 0; d < 32; ++d) {
      float r = xr[d], im = xi[d];
#pragma unroll
      for (int j = 0; j < 4; ++j) {
        float wr = Wre[d * 32 + e0 + j], wi = Wim[d * 32 + e0 + j];  // uniform -> s_load
        ar[j] += r * wr - im * wi;
        ai[j] += r * wi + im * wr;
      }
    }
#pragma unroll
    for (int j = 0; j < 4; ++j) {
      xe[(e0 + j) * PIX + g] = ar[j];
      xe[(32 + e0 + j) * PIX + g] = ai[j];
    }
  }
}

// ---------------- spatial sums of xe planes per (n, channel) ----------------
__global__ void k_mean(const float* __restrict__ xe, float* __restrict__ sums) {
  __shared__ float red[256];
  int n = blockIdx.x, c = blockIdx.y;
  int tid = threadIdx.x;
  const float* src = xe + c * PIX + n * 4096;
  float s = 0.f;
#pragma unroll
  for (int i = 0; i < 16; ++i) s += src[tid + i * 256];
  red[tid] = s;
  __syncthreads();
  for (int w = 128; w > 0; w >>= 1) {
    if (tid < w) red[tid] += red[tid + w];
    __syncthreads();
  }
  if (tid == 0) sums[n * 64 + c] = red[0];
}

// ---------------- flux scan (T=24) + all per-(b,t,d) coefficients ----------------
__global__ void k_flux(float* __restrict__ ws, float* __restrict__ out,
                       const float* __restrict__ dt_seq,
                       const float* __restrict__ flux_re, const float* __restrict__ flux_im,
                       const float* __restrict__ lam_flux,
                       const float* __restrict__ bf_re, const float* __restrict__ bf_im,
                       const float* __restrict__ c_re, const float* __restrict__ c_im,
                       const float* __restrict__ g_w, const float* __restrict__ g_b,
                       const float* __restrict__ a_decay, const float* __restrict__ b_freq) {
  int tid = threadIdx.x;
  if (tid >= 64) return;
  int b = tid >> 5, e = tid & 31;
  float sp_lf = softplusf_(lam_flux[e]);
  float lr = -softplusf_(a_decay[e]);
  float li = b_freq[e];
  float den = lr * lr + li * li;
  float bfr = bf_re[e], bfi = bf_im[e];
  float cr = c_re[e], ci = c_im[e];
  float fr = flux_re[b * 32 + e], fi = flux_im[b * 32 + e];
  for (int t = 0; t < 24; ++t) {
    int n = b * 24 + t;
    float dt = dt_seq[n];
    float A = expf(-sp_lf * dt);
    float xmr = ws[WS_SUMS + n * 64 + e] * (1.f / 4096.f);
    float xmi = ws[WS_SUMS + n * 64 + 32 + e] * (1.f / 4096.f);
    float Xr = (bfr * xmr - bfi * xmi) * dt;
    float Xi = (bfr * xmi + bfi * xmr) * dt;
    fr = A * fr + Xr;
    fi = A * fi + Xi;
    ws[WS_GATE + n * 32 + e] = sigmoidf_(fr * g_w[e] + g_b[e]);
    ws[WS_SRCR + n * 32 + e] = fr * cr - fi * ci;
    ws[WS_SRCI + n * 32 + e] = fr * ci + fi * cr;
    float er = expf(lr * dt);
    float odr = er * cosf(li * dt);
    float odi = er * sinf(li * dt);
    ws[WS_ODR + n * 32 + e] = odr;
    ws[WS_ODI + n * 32 + e] = odi;
    float nr = odr - 1.f, ni = odi;
    ws[WS_OFR + n * 32 + e] = (nr * lr + ni * li) / den;
    ws[WS_OFI + n * 32 + e] = (ni * lr - nr * li) / den;
  }
  out[FLUX_RE + b * 32 + e] = fr;
  out[FLUX_IM + b * 32 + e] = fi;
}

// ---------------- spatial gate 1: 1x1 conv 64->32 + silu, thread-per-pixel ----------------
__global__ void __launch_bounds__(256) k_sg1(
    const float* __restrict__ xe, float* __restrict__ g1,
    const float* __restrict__ w1, const float* __restrict__ b1) {
  int g = blockIdx.x * 256 + threadIdx.x;
  float v[64];
#pragma unroll
  for (int c = 0; c < 64; ++c) v[c] = xe[c * PIX + g];
#pragma unroll
  for (int o0 = 0; o0 < 32; o0 += 4) {
    float acc[4] = {b1[o0], b1[o0 + 1], b1[o0 + 2], b1[o0 + 3]};
#pragma unroll
    for (int c = 0; c < 64; ++c) {
#pragma unroll
      for (int j = 0; j < 4; ++j)
        acc[j] = fmaf(v[c], w1[(o0 + j) * 64 + c], acc[j]);   // uniform -> s_load
    }
#pragma unroll
    for (int j = 0; j < 4; ++j)
      g1[(o0 + j) * PIX + g] = acc[j] * sigmoidf_(acc[j]);
  }
}

// ---------------- spatial gate 2: depthwise 3x3 on planes ----------------
__global__ void __launch_bounds__(256) k_sgdw(
    const float* __restrict__ g1, float* __restrict__ g2, const float* __restrict__ dw) {
  int g = blockIdx.x * 256 + threadIdx.x;
  int oc = blockIdx.y;                  // block-uniform
  int n = g >> 12, p = g & 4095;
  int y = p >> 6, x = p & 63;
  const float* src = g1 + oc * PIX + n * 4096;
  const float* w = dw + oc * 9;         // uniform -> s_load
  float acc = 0.f;
#pragma unroll
  for (int ky = 0; ky < 3; ++ky) {
    int yy = y + ky - 1;
    if ((unsigned)yy < 64u) {
#pragma unroll
      for (int kx = 0; kx < 3; ++kx) {
        int xx = x + kx - 1;
        if ((unsigned)xx < 64u)
          acc = fmaf(src[yy * 64 + xx], w[ky * 3 + kx], acc);
      }
    }
  }
  g2[oc * PIX + g] = acc;
}

// ---------------- sg3 (1x1 32->32 + sigmoid) fused with forcing -> u_t ----------------
__global__ void __launch_bounds__(256) k_force(
    const float* __restrict__ g2p, float* __restrict__ xe,
    const float* __restrict__ gate, const float* __restrict__ srcr,
    const float* __restrict__ srci, const float* __restrict__ ofr_p,
    const float* __restrict__ ofi_p, const float* __restrict__ odr_p,
    const float* __restrict__ odi_p,
    const float* __restrict__ hre, const float* __restrict__ him,
    const float* __restrict__ w2, const float* __restrict__ b2) {
  int g = blockIdx.x * 256 + threadIdx.x;
  int n = g >> 12, p = g & 4095;
  int b = (n >= 24) ? 1 : 0;
  int t = n - b * 24;
  float v[32];
#pragma unroll
  for (int c = 0; c < 32; ++c) v[c] = g2p[c * PIX + g];
  float spg[32];
#pragma unroll
  for (int o0 = 0; o0 < 32; o0 += 4) {
    float acc[4] = {b2[o0], b2[o0 + 1], b2[o0 + 2], b2[o0 + 3]};
#pragma unroll
    for (int c = 0; c < 32; ++c) {
#pragma unroll
      for (int j = 0; j < 4; ++j)
        acc[j] = fmaf(v[c], w2[(o0 + j) * 32 + c], acc[j]);   // uniform -> s_load
    }
#pragma unroll
    for (int j = 0; j < 4; ++j) spg[o0 + j] = sigmoidf_(acc[j]);
  }
#pragma unroll
  for (int e = 0; e < 32; ++e) {
    int ie = n * 32 + e;
    float gc = gate[ie] * spg[e];
    float xr = xe[e * PIX + g];
    float xi = xe[(32 + e) * PIX + g];
    float om = 1.f - gc;
    float fr2 = xr * gc + srcr[ie] * om;
    float fi2 = xi * gc + srci[ie] * om;
    float ofr = ofr_p[ie], ofi = ofi_p[ie];
    float ur = fr2 * ofr - fi2 * ofi;
    float ui = fr2 * ofi + fi2 * ofr;
    if (t == 0) {                       // wave-uniform branch
      int hb = (b * 4096 + p) * 32 + e;
      float hr = hre[hb], hi = him[hb];
      float odr = odr_p[(b * 24) * 32 + e], odi = odi_p[(b * 24) * 32 + e];
      ur += hr * odr - hi * odi;
      ui += hr * odi + hi * odr;
    }
    xe[e * PIX + g] = ur;
    xe[(32 + e) * PIX + g] = ui;
  }
}

// ---------------- temporal scan over T=24 on planes (in place), emit h_out ----------------
__global__ void __launch_bounds__(256) k_scan(
    float* __restrict__ u, const float* __restrict__ odr_p,
    const float* __restrict__ odi_p, float* __restrict__ out) {
  int p = blockIdx.x * 256 + threadIdx.x;   // 0..4095
  int e = blockIdx.y;                        // 0..31 (block-uniform)
  int b = blockIdx.z;                        // 0..1
  float ur = 0.f, ui = 0.f;
  for (int t = 0; t < 24; ++t) {
    int n = b * 24 + t;
    int idx  = e * PIX + n * 4096 + p;
    int idxi = (32 + e) * PIX + n * 4096 + p;
    float ar = odr_p[n * 32 + e];            // uniform -> s_load
    float ai = odi_p[n * 32 + e];
    float xr = u[idx], xi = u[idxi];
    float nr = ar * ur - ai * ui + xr;
    float ni = ar * ui + ai * ur + xi;
    ur = nr; ui = ni;
    u[idx] = ur;
    u[idxi] = ui;
  }
  out[HOUT_RE + (b * 4096 + p) * 32 + e] = ur;
  out[HOUT_IM + (b * 4096 + p) * 32 + e] = ui;
}

// ---------------- dec = u_out @ Wb_inv : thread-per-pixel, planes -> planes ----------------
__global__ void __launch_bounds__(256) k_dec(
    const float* __restrict__ u, const float* __restrict__ winv,
    float* __restrict__ dec) {
  int g = blockIdx.x * 256 + threadIdx.x;
  float ur[32], ui[32];
#pragma unroll
  for (int e = 0; e < 32; ++e) ur[e] = u[e * PIX + g];
#pragma unroll
  for (int e = 0; e < 32; ++e) ui[e] = u[(32 + e) * PIX + g];
#pragma unroll
  for (int d0 = 0; d0 < 32; d0 += 4) {
    float ar[4] = {0.f, 0.f, 0.f, 0.f}, ai[4] = {0.f, 0.f, 0.f, 0.f};
#pragma unroll
    for (int e = 0; e < 32; ++e) {
      float r = ur[e], im = ui[e];
#pragma unroll
      for (int j = 0; j < 4; ++j) {
        float wr = winv[e * 32 + d0 + j];         // uniform -> s_load
        float wi = winv[1024 + e * 32 + d0 + j];
        ar[j] += r * wr - im * wi;
        ai[j] += r * wi + im * wr;
      }
    }
#pragma unroll
    for (int j = 0; j < 4; ++j) {
      dec[(d0 + j) * PIX + g] = ar[j];
      dec[(32 + d0 + j) * PIX + g] = ai[j];
    }
  }
}

// ---------------- LN_t + FFN (64->128->64) via bf16 MFMA + z = x_upd + dec + delta ----------
__global__ void __launch_bounds__(256) k_final(
    const float* __restrict__ dec, float* __restrict__ out,
    const float* __restrict__ lg, const float* __restrict__ lb,
    const float* __restrict__ w1, const float* __restrict__ b1,
    const float* __restrict__ w2, const float* __restrict__ b2) {
  __shared__ unsigned w1T[128][33];   // [hid][c-pair]  bf16x2, +1 pad
  __shared__ unsigned w2T[64][65];    // [out][h-pair]  bf16x2, +1 pad
  __shared__ unsigned dnp[64][33];    // [pix][c-pair]  bf16x2
  __shared__ unsigned hid_o2[64][66]; // union: ushort[64][132] hid bf16  /  float[64][66] o2

  int tid = threadIdx.x;
  int gbase = blockIdx.x * 256;
  int l = tid & 63, wv = tid >> 6;
  int l15 = l & 15, l4 = l >> 4;

  {
    int hid = tid & 127, half = tid >> 7;
#pragma unroll
    for (int i = 0; i < 16; ++i) {
      int cp = half * 16 + i;
      w1T[hid][cp] = pk2(w1[(2 * cp) * 128 + hid], w1[(2 * cp + 1) * 128 + hid]);
    }
    int o = tid & 63, q = tid >> 6;
#pragma unroll
    for (int i = 0; i < 16; ++i) {
      int hp = q * 16 + i;
      w2T[o][hp] = pk2(w2[(2 * hp) * 64 + o], w2[(2 * hp + 1) * 64 + o]);
    }
  }
  float bb1v[8], bb2v[4];
#pragma unroll
  for (int Hn = 0; Hn < 8; ++Hn) bb1v[Hn] = b1[Hn * 16 + l15];
#pragma unroll
  for (int On = 0; On < 4; ++On) bb2v[On] = b2[On * 16 + l15];
  __syncthreads();

  for (int ph = 0; ph < 4; ++ph) {
    int bp = ph * 64;
    if (tid < 64) {
      int gg = gbase + bp + tid;
      float dn[64];
      float s = 0.f;
#pragma unroll
      for (int c = 0; c < 64; ++c) { dn[c] = dec[c * PIX + gg]; s += dn[c]; }
      float m = s * (1.f / 64.f);
      float vs = 0.f;
#pragma unroll
      for (int c = 0; c < 64; ++c) { float d = dn[c] - m; vs += d * d; }
      float rs = rsqrtf(vs * (1.f / 64.f) + 1e-5f);
#pragma unroll
      for (int c = 0; c < 64; ++c) dn[c] = (dn[c] - m) * rs * lg[c] + lb[c];
#pragma unroll
      for (int cp = 0; cp < 32; ++cp)
        dnp[tid][cp] = pk2(dn[2 * cp], dn[2 * cp + 1]);
    }
    __syncthreads();

    int arow = wv * 16 + l15;
    FU a0, a1;
#pragma unroll
    for (int jj = 0; jj < 4; ++jj) {
      a0.u[jj] = dnp[arow][l4 * 4 + jj];
      a1.u[jj] = dnp[arow][16 + l4 * 4 + jj];
    }
    f32x4 acc[8];
#pragma unroll
    for (int Hn = 0; Hn < 8; ++Hn) {
      float bb = bb1v[Hn];
      acc[Hn] = (f32x4){bb, bb, bb, bb};
      FU b0f, b1f;
      int brow = Hn * 16 + l15;
#pragma unroll
      for (int jj = 0; jj < 4; ++jj) {
        b0f.u[jj] = w1T[brow][l4 * 4 + jj];
        b1f.u[jj] = w1T[brow][16 + l4 * 4 + jj];
      }
      acc[Hn] = __builtin_amdgcn_mfma_f32_16x16x32_bf16(a0.f, b0f.f, acc[Hn], 0, 0, 0);
      acc[Hn] = __builtin_amdgcn_mfma_f32_16x16x32_bf16(a1.f, b1f.f, acc[Hn], 0, 0, 0);
    }
    unsigned short (*hidb)[132] = (unsigned short(*)[132])hid_o2;
#pragma unroll
    for (int Hn = 0; Hn < 8; ++Hn) {
#pragma unroll
      for (int r = 0; r < 4; ++r) {
        float v = acc[Hn][r];
        v = v * sigmoidf_(v);
        hidb[wv * 16 + l4 * 4 + r][Hn * 16 + l15] = f2bf(v);
      }
    }
    __syncthreads();   // FENCE: ushort hid stores must complete before unsigned a2 loads

    FU a2[4];
#pragma unroll
    for (int kk = 0; kk < 4; ++kk)
#pragma unroll
      for (int jj = 0; jj < 4; ++jj)
        a2[kk].u[jj] = ((unsigned(*)[66])hid_o2)[arow][kk * 16 + l4 * 4 + jj];
    f32x4 acc2[4];
#pragma unroll
    for (int On = 0; On < 4; ++On) {
      float bb = bb2v[On];
      acc2[On] = (f32x4){bb, bb, bb, bb};
#pragma unroll
      for (int kk = 0; kk < 4; ++kk) {
        FU b2f;
#pragma unroll
        for (int jj = 0; jj < 4; ++jj)
          b2f.u[jj] = w2T[On * 16 + l15][kk * 16 + l4 * 4 + jj];
        acc2[On] = __builtin_amdgcn_mfma_f32_16x16x32_bf16(a2[kk].f, b2f.f, acc2[On], 0, 0, 0);
      }
    }
    float (*o2f)[66] = (float(*)[66])hid_o2;
#pragma unroll
    for (int On = 0; On < 4; ++On)
#pragma unroll
      for (int r = 0; r < 4; ++r)
        o2f[wv * 16 + l4 * 4 + r][On * 16 + l15] = acc2[On][r];
    __syncthreads();

    {
      int p = tid & 63, cq = tid >> 6;
      int gg = gbase + bp + p;
      int nn = gg >> 12, pim = gg & 4095;
#pragma unroll
      for (int i = 0; i < 16; ++i) {
        int c = cq * 16 + i;
        float val = o2f[p][c] + dec[c * PIX + gg];
        int d = c & 31;
        long off = ((c < 32) ? (long)MAIN_RE : (long)MAIN_IM) + (long)(nn * 32 + d) * 4096 + pim;
        out[off] += val;
      }
    }
    __syncthreads();
  }
}

extern "C" void kernel_launch(void* const* d_in, const int* in_sizes, int n_in,
                              void* d_out, int out_size, void* d_ws, size_t ws_size,
                              hipStream_t stream) {
  (void)in_sizes; (void)n_in; (void)out_size; (void)ws_size;
  const float* xre      = (const float*)d_in[0];
  const float* xim      = (const float*)d_in[1];
  const float* hre      = (const float*)d_in[2];
  const float* him      = (const float*)d_in[3];
  const float* flux_re  = (const float*)d_in[4];
  const float* flux_im  = (const float*)d_in[5];
  const float* dt_seq   = (const float*)d_in[6];
  const float* ln_s_g   = (const float*)d_in[7];
  const float* ln_s_b   = (const float*)d_in[8];
  const float* conv_w   = (const float*)d_in[9];
  const float* conv_b   = (const float*)d_in[10];
  const float* ln_t_g   = (const float*)d_in[11];
  const float* ln_t_b   = (const float*)d_in[12];
  const float* W_re     = (const float*)d_in[13];
  const float* W_im     = (const float*)d_in[14];
  const float* lam_flux = (const float*)d_in[15];
  const float* bf_re    = (const float*)d_in[16];
  const float* bf_im    = (const float*)d_in[17];
  const float* c_re     = (const float*)d_in[18];
  const float* c_im     = (const float*)d_in[19];
  const float* g_w      = (const float*)d_in[20];
  const float* g_b      = (const float*)d_in[21];
  const float* a_decay  = (const float*)d_in[22];
  const float* b_freq   = (const float*)d_in[23];
  const float* ffn_w1   = (const float*)d_in[24];
  const float* ffn_b1   = (const float*)d_in[25];
  const float* ffn_w2   = (const float*)d_in[26];
  const float* ffn_b2   = (const float*)d_in[27];
  const float* sg_w1    = (const float*)d_in[28];
  const float* sg_b1    = (const float*)d_in[29];
  const float* sg_dw    = (const float*)d_in[30];
  const float* sg_w2    = (const float*)d_in[31];
  const float* sg_b2    = (const float*)d_in[32];
  float* out = (float*)d_out;
  float* ws  = (float*)d_ws;

  k_invert<<<1, 256, 0, stream>>>(W_re, W_im, ws);
  k_wprep<<<144, 256, 0, stream>>>(conv_w, (unsigned short*)(ws + WS_WPK));
  k_ln_s<<<PIX / 256, 256, 0, stream>>>(xre, xim, ln_s_g, ln_s_b, ws);
  k_conv<<<768, 256, 0, stream>>>((const unsigned*)(ws + WS_XN),
                                  (const unsigned short*)(ws + WS_WPK),
                                  conv_b, xre, xim, out);
  k_xeig<<<PIX / 256, 256, 0, stream>>>(out, W_re, W_im, ws + WS_XE);
  k_mean<<<dim3(NN, 64), 256, 0, stream>>>(ws + WS_XE, ws + WS_SUMS);
  k_flux<<<1, 64, 0, stream>>>(ws, out, dt_seq, flux_re, flux_im, lam_flux,
                               bf_re, bf_im, c_re, c_im, g_w, g_b, a_decay, b_freq);
  k_sg1<<<PIX / 256, 256, 0, stream>>>(ws + WS_XE, ws + WS_G1, sg_w1, sg_b1);
  k_sgdw<<<dim3(PIX / 256, 32), 256, 0, stream>>>(ws + WS_G1, ws + WS_G2, sg_dw);
  k_force<<<PIX / 256, 256, 0, stream>>>(ws + WS_G2, ws + WS_XE,
                                         ws + WS_GATE, ws + WS_SRCR, ws + WS_SRCI,
                                         ws + WS_OFR, ws + WS_OFI, ws + WS_ODR, ws + WS_ODI,
                                         hre, him, sg_w2, sg_b2);
  k_scan<<<dim3(4096 / 256, 32, 2), 256, 0, stream>>>(ws + WS_XE, ws + WS_ODR, ws + WS_ODI, out);
  k_dec<<<PIX / 256, 256, 0, stream>>>(ws + WS_XE, ws + WS_WINV, ws + WS_XN);
  k_final<<<PIX / 256, 256, 0, stream>>>(ws + WS_XN, out, ln_t_g, ln_t_b,
                                         ffn_w1, ffn_b1, ffn_w2, ffn_b2);
}

// Round 9
// 566.145 us; speedup vs baseline: 5.1883x; 1.0238x over previous
//
#include <hip/hip_runtime.h>
#include <math.h>

#define BB 2
#define TT 24
#define DD 32
#define HWp 4096            // 64*64
#define NN (BB*TT)          // 48
#define PIX (NN*HWp)        // 196608
#define C2 (2*DD)           // 64

// d_out offsets (floats)
#define MAIN_RE 0
#define MAIN_IM (NN*DD*HWp)              // 6291456
#define HOUT_RE (2*NN*DD*HWp)            // 12582912
#define HOUT_IM (HOUT_RE + BB*HWp*DD)    // 12845056
#define FLUX_RE (HOUT_RE + 2*BB*HWp*DD)  // 13107200
#define FLUX_IM (FLUX_RE + BB*DD)        // 13107264

// ws offsets (floats)
#define WS_XN   0                        // PIX*64 (bf16 xn for conv; later dec planes f32)
#define WS_XE   (WS_XN + PIX*C2)         // PIX*64
#define WS_G1   (WS_XE + PIX*C2)         // PIX*32  g1 planes
#define WS_G2   (WS_G1 + PIX*DD)         // PIX*32  g2 planes
#define WS_WINV (WS_G2 + PIX*DD)         // 2048 (re 1024, im 1024)
#define WS_SUMS (WS_WINV + 2048)         // 3072 (unused now)
#define WS_GATE (WS_SUMS + 3072)         // 1536
#define WS_SRCR (WS_GATE + 1536)
#define WS_SRCI (WS_SRCR + 1536)
#define WS_ODR  (WS_SRCI + 1536)
#define WS_ODI  (WS_ODR + 1536)
#define WS_OFR  (WS_ODI + 1536)
#define WS_OFI  (WS_OFR + 1536)
#define WS_WPK  (WS_OFI + 1536)          // 36864 ushorts = 18432 floats
#define WS_PART (WS_WPK + 18432)         // 48*16*64 = 49152 floats (per-block channel sums)

typedef __attribute__((ext_vector_type(8))) short bf16x8;
typedef __attribute__((ext_vector_type(4))) float f32x4;
union FU { unsigned u[4]; bf16x8 f; };
union FU4 { uint4 v; unsigned u[4]; bf16x8 f; };

__device__ __forceinline__ float sigmoidf_(float x) { return 1.f / (1.f + expf(-x)); }
__device__ __forceinline__ float softplusf_(float x) { return log1pf(expf(x)); }
__device__ __forceinline__ unsigned short f2bf(float f) {
  unsigned u = __float_as_uint(f);
  return (unsigned short)((u + 0x7FFFu + ((u >> 16) & 1u)) >> 16);   // RNE
}
__device__ __forceinline__ unsigned pk2(float lo, float hi) {
  return (unsigned)f2bf(lo) | ((unsigned)f2bf(hi) << 16);
}

// ---------------- Gauss-Jordan inverse of Wb (32x32 complex), partial pivoting ----------------
__global__ void k_invert(const float* __restrict__ Wre, const float* __restrict__ Wim,
                         float* __restrict__ ws) {
  __shared__ float Mre[32][64];
  __shared__ float Mim[32][64];
  __shared__ float fre[32], fim[32];
  __shared__ float pr_s, pi_s;
  __shared__ int piv_s;
  int tid = threadIdx.x;  // 256 threads
  for (int idx = tid; idx < 2048; idx += 256) {
    int i = idx >> 6, j = idx & 63;
    if (j < 32) { Mre[i][j] = Wre[i * 32 + j]; Mim[i][j] = Wim[i * 32 + j]; }
    else        { Mre[i][j] = (j - 32 == i) ? 1.f : 0.f; Mim[i][j] = 0.f; }
  }
  __syncthreads();
  for (int k = 0; k < 32; ++k) {
    if (tid == 0) {
      int best = k; float bm = fabsf(Mre[k][k]) + fabsf(Mim[k][k]);
      for (int r = k + 1; r < 32; ++r) {
        float m = fabsf(Mre[r][k]) + fabsf(Mim[r][k]);
        if (m > bm) { bm = m; best = r; }
      }
      piv_s = best;
    }
    __syncthreads();
    int pv = piv_s;
    if (pv != k && tid < 64) {
      float tr = Mre[k][tid], ti = Mim[k][tid];
      Mre[k][tid] = Mre[pv][tid]; Mim[k][tid] = Mim[pv][tid];
      Mre[pv][tid] = tr; Mim[pv][tid] = ti;
    }
    __syncthreads();
    if (tid == 0) {
      float a = Mre[k][k], b = Mim[k][k];
      float d = a * a + b * b;
      pr_s = a / d; pi_s = -b / d;
    }
    __syncthreads();
    float pr = pr_s, pi = pi_s;
    if (tid < 64) {
      float a = Mre[k][tid], b = Mim[k][tid];
      Mre[k][tid] = a * pr - b * pi;
      Mim[k][tid] = a * pi + b * pr;
    }
    __syncthreads();
    if (tid < 32) { fre[tid] = Mre[tid][k]; fim[tid] = Mim[tid][k]; }
    __syncthreads();
    for (int idx = tid; idx < 2048; idx += 256) {
      int i = idx >> 6, j = idx & 63;
      if (i != k) {
        float fr = fre[i], fi = fim[i];
        float ar = Mre[k][j], ai = Mim[k][j];
        Mre[i][j] -= fr * ar - fi * ai;
        Mim[i][j] -= fr * ai + fi * ar;
      }
    }
    __syncthreads();
  }
  for (int idx = tid; idx < 1024; idx += 256) {
    int e = idx >> 5, d = idx & 31;
    ws[WS_WINV + e * 32 + d] = Mre[e][32 + d];
    ws[WS_WINV + 1024 + e * 32 + d] = Mim[e][32 + d];
  }
}

// ---------------- weight pre-pack: wpack[tap][oc][ci] bf16 <- conv_w[oc][ci][tap] f32 ----
__global__ void k_wprep(const float* __restrict__ w, unsigned short* __restrict__ wpk) {
  int idx = blockIdx.x * 256 + threadIdx.x;
  if (idx >= 9 * 64 * 64) return;
  int tap = idx >> 12;
  int rem = idx & 4095;
  int oc = rem >> 6, ci = rem & 63;
  wpk[idx] = f2bf(w[(oc * 64 + ci) * 9 + tap]);
}

// ---------------- spatial LayerNorm -> xn bf16 channels-last [n][pix][64] ----------------
__global__ void k_ln_s(const float* __restrict__ xre, const float* __restrict__ xim,
                       const float* __restrict__ g, const float* __restrict__ b,
                       float* __restrict__ ws) {
  int gid = blockIdx.x * 256 + threadIdx.x;
  if (gid >= PIX) return;
  int n = gid >> 12, p = gid & 4095;
  float v[64];
  float s = 0.f;
#pragma unroll
  for (int c = 0; c < 32; ++c) { v[c] = xre[(n * 32 + c) * 4096 + p]; s += v[c]; }
#pragma unroll
  for (int c = 0; c < 32; ++c) { v[32 + c] = xim[(n * 32 + c) * 4096 + p]; s += v[32 + c]; }
  float m = s * (1.f / 64.f);
  float vs = 0.f;
#pragma unroll
  for (int c = 0; c < 64; ++c) { float d = v[c] - m; vs += d * d; }
  float rs = rsqrtf(vs * (1.f / 64.f) + 1e-5f);
#pragma unroll
  for (int c = 0; c < 64; ++c) v[c] = (v[c] - m) * rs * g[c] + b[c];
  uint4* dst = (uint4*)ws + gid * 8;   // xnb at WS_XN, 128B per pixel
#pragma unroll
  for (int q = 0; q < 8; ++q) {
    uint4 u;
    u.x = pk2(v[q * 8 + 0], v[q * 8 + 1]);
    u.y = pk2(v[q * 8 + 2], v[q * 8 + 3]);
    u.z = pk2(v[q * 8 + 4], v[q * 8 + 5]);
    u.w = pk2(v[q * 8 + 6], v[q * 8 + 7]);
    dst[q] = u;
  }
}

// ---------------- 3x3 conv 64->64 as 9 shifted bf16 MFMA GEMMs ----------------
__global__ void __launch_bounds__(256) k_conv(
    const unsigned* __restrict__ xnb_u, const unsigned short* __restrict__ wpk,
    const float* __restrict__ bconv,
    const float* __restrict__ xre, const float* __restrict__ xim,
    float* __restrict__ out) {
  __shared__ unsigned xls[6 * 66 * 36];   // 36 dwords (=72 bf16) per pixel, ci 0..63 valid
  int bid = blockIdx.x;
  int n = bid >> 4;
  int y0 = (bid & 15) * 4;
  int tid = threadIdx.x;
  int wv = tid >> 6, l = tid & 63;
  int l15 = l & 15, l4 = l >> 4;

  const uint4* xnb4 = (const uint4*)xnb_u;
  for (int idx = tid; idx < 396; idx += 256) {
    int r = idx / 66, c = idx - r * 66;
    int y = y0 - 1 + r, x = c - 1;
    bool valid = ((unsigned)y < 64u) & ((unsigned)x < 64u);
    int pg = n * 4096 + y * 64 + x;
    uint4 z; z.x = z.y = z.z = z.w = 0u;
#pragma unroll
    for (int q = 0; q < 8; ++q) {
      uint4 v = valid ? xnb4[pg * 8 + q] : z;
      *(uint4*)&xls[idx * 36 + q * 4] = v;
    }
  }
  __syncthreads();

  f32x4 acc[4][4];
#pragma unroll
  for (int Nt = 0; Nt < 4; ++Nt) {
    float bb = bconv[Nt * 16 + l15];
#pragma unroll
    for (int mt = 0; mt < 4; ++mt) acc[mt][Nt] = (f32x4){bb, bb, bb, bb};
  }

  const uint4* wq = (const uint4*)wpk;   // uint4 idx = tap*512 + oc*8 + ks*4 + l4
#pragma unroll
  for (int tap = 0; tap < 9; ++tap) {
    int ky = tap / 3, kx = tap - ky * 3;
    int rowbase = (wv + ky) * 66 + kx + l15;
#pragma unroll
    for (int ks = 0; ks < 2; ++ks) {
      FU4 B[4];
#pragma unroll
      for (int Nt = 0; Nt < 4; ++Nt)
        B[Nt].v = wq[tap * 512 + (Nt * 16 + l15) * 8 + ks * 4 + l4];
#pragma unroll
      for (int mt = 0; mt < 4; ++mt) {
        FU4 A;
        A.v = *(const uint4*)&xls[(rowbase + mt * 16) * 36 + ks * 16 + l4 * 4];
#pragma unroll
        for (int Nt = 0; Nt < 4; ++Nt)
          acc[mt][Nt] = __builtin_amdgcn_mfma_f32_16x16x32_bf16(A.f, B[Nt].f, acc[mt][Nt], 0, 0, 0);
      }
    }
  }

#pragma unroll
  for (int Nt = 0; Nt < 4; ++Nt) {
    int oc = Nt * 16 + l15;
    int d = oc & 31;
    const float* resid = (oc < 32) ? xre : xim;
    float* dst = out + ((oc < 32) ? MAIN_RE : MAIN_IM) + (n * 32 + d) * 4096;
    const float* rsd = resid + (n * 32 + d) * 4096;
#pragma unroll
    for (int mt = 0; mt < 4; ++mt) {
      int pixbase = (y0 + wv) * 64 + mt * 16 + l4 * 4;
#pragma unroll
      for (int r = 0; r < 4; ++r)
        dst[pixbase + r] = rsd[pixbase + r] + acc[mt][Nt][r];
    }
  }
}

// ---------------- x_eig fused: xe planes + sg1 (silu 1x1) + per-block channel sums ---------
__global__ void __launch_bounds__(256) k_xeig(
    const float* __restrict__ out, const float* __restrict__ Wre,
    const float* __restrict__ Wim, float* __restrict__ xe,
    float* __restrict__ g1, const float* __restrict__ sgw1,
    const float* __restrict__ sgb1, float* __restrict__ part) {
  __shared__ float wred[4][64];
  int tid = threadIdx.x;
  int g = blockIdx.x * 256 + tid;
  int n = g >> 12, p = g & 4095;
  float xr[32], xi[32];
#pragma unroll
  for (int d = 0; d < 32; ++d) xr[d] = out[MAIN_RE + (n * 32 + d) * 4096 + p];
#pragma unroll
  for (int d = 0; d < 32; ++d) xi[d] = out[MAIN_IM + (n * 32 + d) * 4096 + p];
  float xc[64];
#pragma unroll
  for (int e0 = 0; e0 < 32; e0 += 4) {
    float ar[4] = {0.f, 0.f, 0.f, 0.f}, ai[4] = {0.f, 0.f, 0.f, 0.f};
#pragma unroll
    for (int d = 0; d < 32; ++d) {
      float r = xr[d], im = xi[d];
#pragma unroll
      for (int j = 0; j < 4; ++j) {
        float wr = Wre[d * 32 + e0 + j], wi = Wim[d * 32 + e0 + j];  // uniform -> s_load
        ar[j] += r * wr - im * wi;
        ai[j] += r * wi + im * wr;
      }
    }
#pragma unroll
    for (int j = 0; j < 4; ++j) {
      xe[(e0 + j) * PIX + g] = ar[j];
      xe[(32 + e0 + j) * PIX + g] = ai[j];
      xc[e0 + j] = ar[j];
      xc[32 + e0 + j] = ai[j];
    }
  }
  // sg1: g1 = silu(xc @ w1) (weights uniform -> s_load)
#pragma unroll
  for (int o0 = 0; o0 < 32; o0 += 4) {
    float acc[4] = {sgb1[o0], sgb1[o0 + 1], sgb1[o0 + 2], sgb1[o0 + 3]};
#pragma unroll
    for (int c = 0; c < 64; ++c) {
#pragma unroll
      for (int j = 0; j < 4; ++j)
        acc[j] = fmaf(xc[c], sgw1[(o0 + j) * 64 + c], acc[j]);
    }
#pragma unroll
    for (int j = 0; j < 4; ++j)
      g1[(o0 + j) * PIX + g] = acc[j] * sigmoidf_(acc[j]);
  }
  // per-block channel sums (deterministic: fixed shuffle order, per-block slot)
  int wv = tid >> 6, l = tid & 63;
#pragma unroll
  for (int c = 0; c < 64; ++c) {
    float v = xc[c];
    v += __shfl_xor(v, 1);
    v += __shfl_xor(v, 2);
    v += __shfl_xor(v, 4);
    v += __shfl_xor(v, 8);
    v += __shfl_xor(v, 16);
    v += __shfl_xor(v, 32);
    if (l == 0) wred[wv][c] = v;
  }
  __syncthreads();
  if (tid < 64)
    part[blockIdx.x * 64 + tid] =
        wred[0][tid] + wred[1][tid] + wred[2][tid] + wred[3][tid];
}

// ---------------- flux scan (T=24) + all per-(b,t,d) coefficients ----------------
__global__ void k_flux(float* __restrict__ ws, float* __restrict__ out,
                       const float* __restrict__ dt_seq,
                       const float* __restrict__ flux_re, const float* __restrict__ flux_im,
                       const float* __restrict__ lam_flux,
                       const float* __restrict__ bf_re, const float* __restrict__ bf_im,
                       const float* __restrict__ c_re, const float* __restrict__ c_im,
                       const float* __restrict__ g_w, const float* __restrict__ g_b,
                       const float* __restrict__ a_decay, const float* __restrict__ b_freq) {
  int tid = threadIdx.x;
  if (tid >= 64) return;
  int b = tid >> 5, e = tid & 31;
  float sp_lf = softplusf_(lam_flux[e]);
  float lr = -softplusf_(a_decay[e]);
  float li = b_freq[e];
  float den = lr * lr + li * li;
  float bfr = bf_re[e], bfi = bf_im[e];
  float cr = c_re[e], ci = c_im[e];
  float fr = flux_re[b * 32 + e], fi = flux_im[b * 32 + e];
  const float* part = ws + WS_PART;
  for (int t = 0; t < 24; ++t) {
    int n = b * 24 + t;
    float dt = dt_seq[n];
    float A = expf(-sp_lf * dt);
    float xmr = 0.f, xmi = 0.f;
#pragma unroll
    for (int j = 0; j < 16; ++j) {
      xmr += part[(n * 16 + j) * 64 + e];
      xmi += part[(n * 16 + j) * 64 + 32 + e];
    }
    xmr *= (1.f / 4096.f);
    xmi *= (1.f / 4096.f);
    float Xr = (bfr * xmr - bfi * xmi) * dt;
    float Xi = (bfr * xmi + bfi * xmr) * dt;
    fr = A * fr + Xr;
    fi = A * fi + Xi;
    ws[WS_GATE + n * 32 + e] = sigmoidf_(fr * g_w[e] + g_b[e]);
    ws[WS_SRCR + n * 32 + e] = fr * cr - fi * ci;
    ws[WS_SRCI + n * 32 + e] = fr * ci + fi * cr;
    float er = expf(lr * dt);
    float odr = er * cosf(li * dt);
    float odi = er * sinf(li * dt);
    ws[WS_ODR + n * 32 + e] = odr;
    ws[WS_ODI + n * 32 + e] = odi;
    float nr = odr - 1.f, ni = odi;
    ws[WS_OFR + n * 32 + e] = (nr * lr + ni * li) / den;
    ws[WS_OFI + n * 32 + e] = (ni * lr - nr * li) / den;
  }
  out[FLUX_RE + b * 32 + e] = fr;
  out[FLUX_IM + b * 32 + e] = fi;
}

// ---------------- spatial gate 2: depthwise 3x3 on planes ----------------
__global__ void __launch_bounds__(256) k_sgdw(
    const float* __restrict__ g1, float* __restrict__ g2, const float* __restrict__ dw) {
  int g = blockIdx.x * 256 + threadIdx.x;
  int oc = blockIdx.y;                  // block-uniform
  int n = g >> 12, p = g & 4095;
  int y = p >> 6, x = p & 63;
  const float* src = g1 + oc * PIX + n * 4096;
  const float* w = dw + oc * 9;         // uniform -> s_load
  float acc = 0.f;
#pragma unroll
  for (int ky = 0; ky < 3; ++ky) {
    int yy = y + ky - 1;
    if ((unsigned)yy < 64u) {
#pragma unroll
      for (int kx = 0; kx < 3; ++kx) {
        int xx = x + kx - 1;
        if ((unsigned)xx < 64u)
          acc = fmaf(src[yy * 64 + xx], w[ky * 3 + kx], acc);
      }
    }
  }
  g2[oc * PIX + g] = acc;
}

// ---------------- sg3 (1x1 32->32 + sigmoid) fused with forcing -> u_t ----------------
__global__ void __launch_bounds__(256) k_force(
    const float* __restrict__ g2p, float* __restrict__ xe,
    const float* __restrict__ gate, const float* __restrict__ srcr,
    const float* __restrict__ srci, const float* __restrict__ ofr_p,
    const float* __restrict__ ofi_p, const float* __restrict__ odr_p,
    const float* __restrict__ odi_p,
    const float* __restrict__ hre, const float* __restrict__ him,
    const float* __restrict__ w2, const float* __restrict__ b2) {
  int g = blockIdx.x * 256 + threadIdx.x;
  int n = g >> 12, p = g & 4095;
  int b = (n >= 24) ? 1 : 0;
  int t = n - b * 24;
  float v[32];
#pragma unroll
  for (int c = 0; c < 32; ++c) v[c] = g2p[c * PIX + g];
  float spg[32];
#pragma unroll
  for (int o0 = 0; o0 < 32; o0 += 4) {
    float acc[4] = {b2[o0], b2[o0 + 1], b2[o0 + 2], b2[o0 + 3]};
#pragma unroll
    for (int c = 0; c < 32; ++c) {
#pragma unroll
      for (int j = 0; j < 4; ++j)
        acc[j] = fmaf(v[c], w2[(o0 + j) * 32 + c], acc[j]);   // uniform -> s_load
    }
#pragma unroll
    for (int j = 0; j < 4; ++j) spg[o0 + j] = sigmoidf_(acc[j]);
  }
#pragma unroll
  for (int e = 0; e < 32; ++e) {
    int ie = n * 32 + e;
    float gc = gate[ie] * spg[e];
    float xr = xe[e * PIX + g];
    float xi = xe[(32 + e) * PIX + g];
    float om = 1.f - gc;
    float fr2 = xr * gc + srcr[ie] * om;
    float fi2 = xi * gc + srci[ie] * om;
    float ofr = ofr_p[ie], ofi = ofi_p[ie];
    float ur = fr2 * ofr - fi2 * ofi;
    float ui = fr2 * ofi + fi2 * ofr;
    if (t == 0) {                       // wave-uniform branch
      int hb = (b * 4096 + p) * 32 + e;
      float hr = hre[hb], hi = him[hb];
      float odr = odr_p[(b * 24) * 32 + e], odi = odi_p[(b * 24) * 32 + e];
      ur += hr * odr - hi * odi;
      ui += hr * odi + hi * odr;
    }
    xe[e * PIX + g] = ur;
    xe[(32 + e) * PIX + g] = ui;
  }
}

// ---------------- temporal scan over T=24 on planes (in place), emit h_out ----------------
__global__ void __launch_bounds__(256) k_scan(
    float* __restrict__ u, const float* __restrict__ odr_p,
    const float* __restrict__ odi_p, float* __restrict__ out) {
  int p = blockIdx.x * 256 + threadIdx.x;   // 0..4095
  int e = blockIdx.y;                        // 0..31 (block-uniform)
  int b = blockIdx.z;                        // 0..1
  float ur = 0.f, ui = 0.f;
  for (int t = 0; t < 24; ++t) {
    int n = b * 24 + t;
    int idx  = e * PIX + n * 4096 + p;
    int idxi = (32 + e) * PIX + n * 4096 + p;
    float ar = odr_p[n * 32 + e];            // uniform -> s_load
    float ai = odi_p[n * 32 + e];
    float xr = u[idx], xi = u[idxi];
    float nr = ar * ur - ai * ui + xr;
    float ni = ar * ui + ai * ur + xi;
    ur = nr; ui = ni;
    u[idx] = ur;
    u[idxi] = ui;
  }
  out[HOUT_RE + (b * 4096 + p) * 32 + e] = ur;
  out[HOUT_IM + (b * 4096 + p) * 32 + e] = ui;
}

// ---------------- dec = u_out @ Wb_inv : thread-per-pixel, planes -> planes ----------------
__global__ void __launch_bounds__(256) k_dec(
    const float* __restrict__ u, const float* __restrict__ winv,
    float* __restrict__ dec) {
  int g = blockIdx.x * 256 + threadIdx.x;
  float ur[32], ui[32];
#pragma unroll
  for (int e = 0; e < 32; ++e) ur[e] = u[e * PIX + g];
#pragma unroll
  for (int e = 0; e < 32; ++e) ui[e] = u[(32 + e) * PIX + g];
#pragma unroll
  for (int d0 = 0; d0 < 32; d0 += 4) {
    float ar[4] = {0.f, 0.f, 0.f, 0.f}, ai[4] = {0.f, 0.f, 0.f, 0.f};
#pragma unroll
    for (int e = 0; e < 32; ++e) {
      float r = ur[e], im = ui[e];
#pragma unroll
      for (int j = 0; j < 4; ++j) {
        float wr = winv[e * 32 + d0 + j];         // uniform -> s_load
        float wi = winv[1024 + e * 32 + d0 + j];
        ar[j] += r * wr - im * wi;
        ai[j] += r * wi + im * wr;
      }
    }
#pragma unroll
    for (int j = 0; j < 4; ++j) {
      dec[(d0 + j) * PIX + g] = ar[j];
      dec[(32 + d0 + j) * PIX + g] = ai[j];
    }
  }
}

// ---------------- LN_t + FFN (64->128->64) via bf16 MFMA + z = x_upd + dec + delta ----------
// v2: LN parallel across all 256 threads (thread = (pixel, channel-quarter)); raw dec kept in
// registers to the epilogue; ho stride 65 (epilogue bank = p+c, conflict-free).
__global__ void __launch_bounds__(256) k_final(
    const float* __restrict__ dec, float* __restrict__ out,
    const float* __restrict__ lg, const float* __restrict__ lb,
    const float* __restrict__ w1, const float* __restrict__ b1,
    const float* __restrict__ w2, const float* __restrict__ b2) {
  __shared__ unsigned w1T[128][33];   // [hid][c-pair]  bf16x2, +1 pad
  __shared__ unsigned w2T[64][65];    // [out][h-pair]  bf16x2, +1 pad
  __shared__ unsigned dnp[64][33];    // [pix][c-pair]  bf16x2
  __shared__ unsigned ho[64][65];     // union: ushort[64][130] hid bf16 / float[64][65] o2
  __shared__ float ps1[64][5];        // LN partial sums (stride 5 -> conflict-free)
  __shared__ float ps2[64][5];

  int tid = threadIdx.x;
  int gbase = blockIdx.x * 256;
  int l = tid & 63, wv = tid >> 6;
  int l15 = l & 15, l4 = l >> 4;
  int p64 = l, q = wv;                // LN/epilogue mapping: pixel, channel-quarter

  // ---- stage w1^T, w2^T as bf16 pairs (once per block) ----
  {
    int hid = tid & 127, half = tid >> 7;
#pragma unroll
    for (int i = 0; i < 16; ++i) {
      int cp = half * 16 + i;
      w1T[hid][cp] = pk2(w1[(2 * cp) * 128 + hid], w1[(2 * cp + 1) * 128 + hid]);
    }
#pragma unroll
    for (int i = 0; i < 16; ++i) {
      int hp = wv * 16 + i;
      w2T[l][hp] = pk2(w2[(2 * hp) * 64 + l], w2[(2 * hp + 1) * 64 + l]);
    }
  }
  float bb1v[8], bb2v[4];
#pragma unroll
  for (int Hn = 0; Hn < 8; ++Hn) bb1v[Hn] = b1[Hn * 16 + l15];
#pragma unroll
  for (int On = 0; On < 4; ++On) bb2v[On] = b2[On * 16 + l15];
  __syncthreads();

  for (int ph = 0; ph < 4; ++ph) {
    int gg = gbase + ph * 64 + p64;

    // ---- LN: all 256 threads; thread owns (pixel p64, channels q*16..q*16+15) ----
    float dv[16];
    float s1 = 0.f, s2 = 0.f;
#pragma unroll
    for (int i = 0; i < 16; ++i) {
      dv[i] = dec[(q * 16 + i) * PIX + gg];
      s1 += dv[i];
      s2 += dv[i] * dv[i];
    }
    ps1[p64][q] = s1;
    ps2[p64][q] = s2;
    __syncthreads();
    float m  = (ps1[p64][0] + ps1[p64][1] + ps1[p64][2] + ps1[p64][3]) * (1.f / 64.f);
    float e2 = (ps2[p64][0] + ps2[p64][1] + ps2[p64][2] + ps2[p64][3]) * (1.f / 64.f);
    float rs = rsqrtf(e2 - m * m + 1e-5f);
#pragma unroll
    for (int ii = 0; ii < 8; ++ii) {
      int c0 = q * 16 + 2 * ii;
      float a = (dv[2 * ii]     - m) * rs * lg[c0]     + lb[c0];
      float bvl = (dv[2 * ii + 1] - m) * rs * lg[c0 + 1] + lb[c0 + 1];
      dnp[p64][q * 8 + ii] = pk2(a, bvl);
    }
    __syncthreads();

    // ---- layer 1: per wave, its 16-pixel tile ----
    int arow = wv * 16 + l15;
    FU a0, a1;
#pragma unroll
    for (int jj = 0; jj < 4; ++jj) {
      a0.u[jj] = dnp[arow][l4 * 4 + jj];
      a1.u[jj] = dnp[arow][16 + l4 * 4 + jj];
    }
    f32x4 acc[8];
#pragma unroll
    for (int Hn = 0; Hn < 8; ++Hn) {
      float bb = bb1v[Hn];
      acc[Hn] = (f32x4){bb, bb, bb, bb};
      FU b0f, b1f;
      int brow = Hn * 16 + l15;
#pragma unroll
      for (int jj = 0; jj < 4; ++jj) {
        b0f.u[jj] = w1T[brow][l4 * 4 + jj];
        b1f.u[jj] = w1T[brow][16 + l4 * 4 + jj];
      }
      acc[Hn] = __builtin_amdgcn_mfma_f32_16x16x32_bf16(a0.f, b0f.f, acc[Hn], 0, 0, 0);
      acc[Hn] = __builtin_amdgcn_mfma_f32_16x16x32_bf16(a1.f, b1f.f, acc[Hn], 0, 0, 0);
    }
    unsigned short (*hidb)[130] = (unsigned short(*)[130])ho;
#pragma unroll
    for (int Hn = 0; Hn < 8; ++Hn) {
#pragma unroll
      for (int r = 0; r < 4; ++r) {
        float v = acc[Hn][r];
        v = v * sigmoidf_(v);
        hidb[wv * 16 + l4 * 4 + r][Hn * 16 + l15] = f2bf(v);
      }
    }
    __syncthreads();   // FENCE: ushort hid stores complete before unsigned a2 loads (TBAA)

    // ---- layer 2 ----
    FU a2[4];
#pragma unroll
    for (int kk = 0; kk < 4; ++kk)
#pragma unroll
      for (int jj = 0; jj < 4; ++jj)
        a2[kk].u[jj] = ((unsigned(*)[65])ho)[arow][kk * 16 + l4 * 4 + jj];
    f32x4 acc2[4];
#pragma unroll
    for (int On = 0; On < 4; ++On) {
      float bb = bb2v[On];
      acc2[On] = (f32x4){bb, bb, bb, bb};
#pragma unroll
      for (int kk = 0; kk < 4; ++kk) {
        FU b2f;
#pragma unroll
        for (int jj = 0; jj < 4; ++jj)
          b2f.u[jj] = w2T[On * 16 + l15][kk * 16 + l4 * 4 + jj];
        acc2[On] = __builtin_amdgcn_mfma_f32_16x16x32_bf16(a2[kk].f, b2f.f, acc2[On], 0, 0, 0);
      }
    }
    float (*o2f)[65] = (float(*)[65])ho;
#pragma unroll
    for (int On = 0; On < 4; ++On)
#pragma unroll
      for (int r = 0; r < 4; ++r)
        o2f[wv * 16 + l4 * 4 + r][On * 16 + l15] = acc2[On][r];
    __syncthreads();

    // ---- epilogue: same (p64, q) mapping; dv (raw dec) still in registers ----
    {
      int nn = gg >> 12, pim = gg & 4095;
#pragma unroll
      for (int i = 0; i < 16; ++i) {
        int c = q * 16 + i;
        float val = o2f[p64][c] + dv[i];
        int d = c & 31;
        long off = ((c < 32) ? (long)MAIN_RE : (long)MAIN_IM) + (long)(nn * 32 + d) * 4096 + pim;
        out[off] += val;
      }
    }
    // next phase's LN writes (ps/dnp) are separated from this epilogue's ho reads
    // by the post-LN barrier; hidb stores come 2 barriers later -> no end barrier needed
  }
}

extern "C" void kernel_launch(void* const* d_in, const int* in_sizes, int n_in,
                              void* d_out, int out_size, void* d_ws, size_t ws_size,
                              hipStream_t stream) {
  (void)in_sizes; (void)n_in; (void)out_size; (void)ws_size;
  const float* xre      = (const float*)d_in[0];
  const float* xim      = (const float*)d_in[1];
  const float* hre      = (const float*)d_in[2];
  const float* him      = (const float*)d_in[3];
  const float* flux_re  = (const float*)d_in[4];
  const float* flux_im  = (const float*)d_in[5];
  const float* dt_seq   = (const float*)d_in[6];
  const float* ln_s_g   = (const float*)d_in[7];
  const float* ln_s_b   = (const float*)d_in[8];
  const float* conv_w   = (const float*)d_in[9];
  const float* conv_b   = (const float*)d_in[10];
  const float* ln_t_g   = (const float*)d_in[11];
  const float* ln_t_b   = (const float*)d_in[12];
  const float* W_re     = (const float*)d_in[13];
  const float* W_im     = (const float*)d_in[14];
  const float* lam_flux = (const float*)d_in[15];
  const float* bf_re    = (const float*)d_in[16];
  const float* bf_im    = (const float*)d_in[17];
  const float* c_re     = (const float*)d_in[18];
  const float* c_im     = (const float*)d_in[19];
  const float* g_w      = (const float*)d_in[20];
  const float* g_b      = (const float*)d_in[21];
  const float* a_decay  = (const float*)d_in[22];
  const float* b_freq   = (const float*)d_in[23];
  const float* ffn_w1   = (const float*)d_in[24];
  const float* ffn_b1   = (const float*)d_in[25];
  const float* ffn_w2   = (const float*)d_in[26];
  const float* ffn_b2   = (const float*)d_in[27];
  const float* sg_w1    = (const float*)d_in[28];
  const float* sg_b1    = (const float*)d_in[29];
  const float* sg_dw    = (const float*)d_in[30];
  const float* sg_w2    = (const float*)d_in[31];
  const float* sg_b2    = (const float*)d_in[32];
  float* out = (float*)d_out;
  float* ws  = (float*)d_ws;

  k_invert<<<1, 256, 0, stream>>>(W_re, W_im, ws);
  k_wprep<<<144, 256, 0, stream>>>(conv_w, (unsigned short*)(ws + WS_WPK));
  k_ln_s<<<PIX / 256, 256, 0, stream>>>(xre, xim, ln_s_g, ln_s_b, ws);
  k_conv<<<768, 256, 0, stream>>>((const unsigned*)(ws + WS_XN),
                                  (const unsigned short*)(ws + WS_WPK),
                                  conv_b, xre, xim, out);
  k_xeig<<<PIX / 256, 256, 0, stream>>>(out, W_re, W_im, ws + WS_XE,
                                        ws + WS_G1, sg_w1, sg_b1, ws + WS_PART);
  k_flux<<<1, 64, 0, stream>>>(ws, out, dt_seq, flux_re, flux_im, lam_flux,
                               bf_re, bf_im, c_re, c_im, g_w, g_b, a_decay, b_freq);
  k_sgdw<<<dim3(PIX / 256, 32), 256, 0, stream>>>(ws + WS_G1, ws + WS_G2, sg_dw);
  k_force<<<PIX / 256, 256, 0, stream>>>(ws + WS_G2, ws + WS_XE,
                                         ws + WS_GATE, ws + WS_SRCR, ws + WS_SRCI,
                                         ws + WS_OFR, ws + WS_OFI, ws + WS_ODR, ws + WS_ODI,
                                         hre, him, sg_w2, sg_b2);
  k_scan<<<dim3(4096 / 256, 32, 2), 256, 0, stream>>>(ws + WS_XE, ws + WS_ODR, ws + WS_ODI, out);
  k_dec<<<PIX / 256, 256, 0, stream>>>(ws + WS_XE, ws + WS_WINV, ws + WS_XN);
  k_final<<<PIX / 256, 256, 0, stream>>>(ws + WS_XN, out, ln_t_g, ln_t_b,
                                         ffn_w1, ffn_b1, ffn_w2, ffn_b2);
}

// Round 10
// 477.642 us; speedup vs baseline: 6.1496x; 1.1853x over previous
//
#include <hip/hip_runtime.h>
#include <math.h>

#define BB 2
#define TT 24
#define DD 32
#define HWp 4096            // 64*64
#define NN (BB*TT)          // 48
#define PIX (NN*HWp)        // 196608
#define C2 (2*DD)           // 64

// d_out offsets (floats)
#define MAIN_RE 0
#define MAIN_IM (NN*DD*HWp)              // 6291456
#define HOUT_RE (2*NN*DD*HWp)            // 12582912
#define HOUT_IM (HOUT_RE + BB*HWp*DD)    // 12845056
#define FLUX_RE (HOUT_RE + 2*BB*HWp*DD)  // 13107200
#define FLUX_IM (FLUX_RE + BB*DD)        // 13107264

// ws offsets (floats)
#define WS_XN   0                        // PIX*64 (bf16 xn for conv; later dec planes f32)
#define WS_XE   (WS_XN + PIX*C2)         // PIX*64
#define WS_G1   (WS_XE + PIX*C2)         // PIX*32  g1 planes
#define WS_G2   (WS_G1 + PIX*DD)         // PIX*32  g2 planes
#define WS_WINV (WS_G2 + PIX*DD)         // 2048 (re 1024, im 1024)
#define WS_SUMS (WS_WINV + 2048)         // 3072 (unused now)
#define WS_GATE (WS_SUMS + 3072)         // 1536
#define WS_SRCR (WS_GATE + 1536)
#define WS_SRCI (WS_SRCR + 1536)
#define WS_ODR  (WS_SRCI + 1536)
#define WS_ODI  (WS_ODR + 1536)
#define WS_OFR  (WS_ODI + 1536)
#define WS_OFI  (WS_OFR + 1536)
#define WS_WPK  (WS_OFI + 1536)          // 36864 ushorts = 18432 floats
#define WS_PART (WS_WPK + 18432)         // 48*16*64 = 49152 floats (per-block channel sums)
#define WS_WE   (WS_PART + 49152)        // 2048 u32: eig weights [N=64][Kpair=32] bf16x2
#define WS_SG   (WS_WE + 2048)           // 1024 u32: sg1 weights [N=32][Kpair=32] bf16x2

typedef __attribute__((ext_vector_type(8))) short bf16x8;
typedef __attribute__((ext_vector_type(4))) float f32x4;
union FU { unsigned u[4]; bf16x8 f; };
union FU4 { uint4 v; unsigned u[4]; bf16x8 f; };

__device__ __forceinline__ float sigmoidf_(float x) { return 1.f / (1.f + expf(-x)); }
__device__ __forceinline__ float softplusf_(float x) { return log1pf(expf(x)); }
__device__ __forceinline__ unsigned short f2bf(float f) {
  unsigned u = __float_as_uint(f);
  return (unsigned short)((u + 0x7FFFu + ((u >> 16) & 1u)) >> 16);   // RNE
}
__device__ __forceinline__ unsigned pk2(float lo, float hi) {
  return (unsigned)f2bf(lo) | ((unsigned)f2bf(hi) << 16);
}

// ---------------- Gauss-Jordan inverse of Wb (32x32 complex), partial pivoting ----------------
__global__ void k_invert(const float* __restrict__ Wre, const float* __restrict__ Wim,
                         float* __restrict__ ws) {
  __shared__ float Mre[32][64];
  __shared__ float Mim[32][64];
  __shared__ float fre[32], fim[32];
  __shared__ float pr_s, pi_s;
  __shared__ int piv_s;
  int tid = threadIdx.x;  // 256 threads
  for (int idx = tid; idx < 2048; idx += 256) {
    int i = idx >> 6, j = idx & 63;
    if (j < 32) { Mre[i][j] = Wre[i * 32 + j]; Mim[i][j] = Wim[i * 32 + j]; }
    else        { Mre[i][j] = (j - 32 == i) ? 1.f : 0.f; Mim[i][j] = 0.f; }
  }
  __syncthreads();
  for (int k = 0; k < 32; ++k) {
    if (tid == 0) {
      int best = k; float bm = fabsf(Mre[k][k]) + fabsf(Mim[k][k]);
      for (int r = k + 1; r < 32; ++r) {
        float m = fabsf(Mre[r][k]) + fabsf(Mim[r][k]);
        if (m > bm) { bm = m; best = r; }
      }
      piv_s = best;
    }
    __syncthreads();
    int pv = piv_s;
    if (pv != k && tid < 64) {
      float tr = Mre[k][tid], ti = Mim[k][tid];
      Mre[k][tid] = Mre[pv][tid]; Mim[k][tid] = Mim[pv][tid];
      Mre[pv][tid] = tr; Mim[pv][tid] = ti;
    }
    __syncthreads();
    if (tid == 0) {
      float a = Mre[k][k], b = Mim[k][k];
      float d = a * a + b * b;
      pr_s = a / d; pi_s = -b / d;
    }
    __syncthreads();
    float pr = pr_s, pi = pi_s;
    if (tid < 64) {
      float a = Mre[k][tid], b = Mim[k][tid];
      Mre[k][tid] = a * pr - b * pi;
      Mim[k][tid] = a * pi + b * pr;
    }
    __syncthreads();
    if (tid < 32) { fre[tid] = Mre[tid][k]; fim[tid] = Mim[tid][k]; }
    __syncthreads();
    for (int idx = tid; idx < 2048; idx += 256) {
      int i = idx >> 6, j = idx & 63;
      if (i != k) {
        float fr = fre[i], fi = fim[i];
        float ar = Mre[k][j], ai = Mim[k][j];
        Mre[i][j] -= fr * ar - fi * ai;
        Mim[i][j] -= fr * ai + fi * ar;
      }
    }
    __syncthreads();
  }
  for (int idx = tid; idx < 1024; idx += 256) {
    int e = idx >> 5, d = idx & 31;
    ws[WS_WINV + e * 32 + d] = Mre[e][32 + d];
    ws[WS_WINV + 1024 + e * 32 + d] = Mim[e][32 + d];
  }
}

// ---------------- weight pre-pack: wpack[tap][oc][ci] bf16 <- conv_w[oc][ci][tap] f32 ----
__global__ void k_wprep(const float* __restrict__ w, unsigned short* __restrict__ wpk) {
  int idx = blockIdx.x * 256 + threadIdx.x;
  if (idx >= 9 * 64 * 64) return;
  int tap = idx >> 12;
  int rem = idx & 4095;
  int oc = rem >> 6, ci = rem & 63;
  wpk[idx] = f2bf(w[(oc * 64 + ci) * 9 + tap]);
}

// ---------------- eig + sg1 weight pre-pack (bf16 [N][Kpair] B-fragment layout) ----------
// eig packed real matrix Wp[k][j]: j<32: (k<32 ? Wre[k][j] : -Wim[k-32][j])
//                                  j>=32: (k<32 ? Wim[k][j-32] : Wre[k-32][j-32])
__global__ void k_eprep(const float* __restrict__ Wre, const float* __restrict__ Wim,
                        const float* __restrict__ sgw1,
                        unsigned* __restrict__ we, unsigned* __restrict__ sg) {
  int idx = blockIdx.x * 256 + threadIdx.x;
  if (idx < 2048) {
    int j = idx >> 5, kp = idx & 31;
    float v[2];
#pragma unroll
    for (int h = 0; h < 2; ++h) {
      int k = 2 * kp + h;
      float x;
      if (j < 32) x = (k < 32) ? Wre[k * 32 + j] : -Wim[(k - 32) * 32 + j];
      else        x = (k < 32) ? Wim[k * 32 + (j - 32)] : Wre[(k - 32) * 32 + (j - 32)];
      v[h] = x;
    }
    we[idx] = pk2(v[0], v[1]);
  }
  if (idx < 1024) {
    int oc = idx >> 5, kp = idx & 31;
    sg[idx] = pk2(sgw1[oc * 64 + 2 * kp], sgw1[oc * 64 + 2 * kp + 1]);
  }
}

// ---------------- spatial LayerNorm -> xn bf16 channels-last [n][pix][64] ----------------
__global__ void k_ln_s(const float* __restrict__ xre, const float* __restrict__ xim,
                       const float* __restrict__ g, const float* __restrict__ b,
                       float* __restrict__ ws) {
  int gid = blockIdx.x * 256 + threadIdx.x;
  if (gid >= PIX) return;
  int n = gid >> 12, p = gid & 4095;
  float v[64];
  float s = 0.f;
#pragma unroll
  for (int c = 0; c < 32; ++c) { v[c] = xre[(n * 32 + c) * 4096 + p]; s += v[c]; }
#pragma unroll
  for (int c = 0; c < 32; ++c) { v[32 + c] = xim[(n * 32 + c) * 4096 + p]; s += v[32 + c]; }
  float m = s * (1.f / 64.f);
  float vs = 0.f;
#pragma unroll
  for (int c = 0; c < 64; ++c) { float d = v[c] - m; vs += d * d; }
  float rs = rsqrtf(vs * (1.f / 64.f) + 1e-5f);
#pragma unroll
  for (int c = 0; c < 64; ++c) v[c] = (v[c] - m) * rs * g[c] + b[c];
  uint4* dst = (uint4*)ws + gid * 8;   // xnb at WS_XN, 128B per pixel
#pragma unroll
  for (int q = 0; q < 8; ++q) {
    uint4 u;
    u.x = pk2(v[q * 8 + 0], v[q * 8 + 1]);
    u.y = pk2(v[q * 8 + 2], v[q * 8 + 3]);
    u.z = pk2(v[q * 8 + 4], v[q * 8 + 5]);
    u.w = pk2(v[q * 8 + 6], v[q * 8 + 7]);
    dst[q] = u;
  }
}

// ---------------- 3x3 conv 64->64 as 9 shifted bf16 MFMA GEMMs ----------------
__global__ void __launch_bounds__(256) k_conv(
    const unsigned* __restrict__ xnb_u, const unsigned short* __restrict__ wpk,
    const float* __restrict__ bconv,
    const float* __restrict__ xre, const float* __restrict__ xim,
    float* __restrict__ out) {
  __shared__ unsigned xls[6 * 66 * 36];   // 36 dwords (=72 bf16) per pixel, ci 0..63 valid
  int bid = blockIdx.x;
  int n = bid >> 4;
  int y0 = (bid & 15) * 4;
  int tid = threadIdx.x;
  int wv = tid >> 6, l = tid & 63;
  int l15 = l & 15, l4 = l >> 4;

  const uint4* xnb4 = (const uint4*)xnb_u;
  for (int idx = tid; idx < 396; idx += 256) {
    int r = idx / 66, c = idx - r * 66;
    int y = y0 - 1 + r, x = c - 1;
    bool valid = ((unsigned)y < 64u) & ((unsigned)x < 64u);
    int pg = n * 4096 + y * 64 + x;
    uint4 z; z.x = z.y = z.z = z.w = 0u;
#pragma unroll
    for (int q = 0; q < 8; ++q) {
      uint4 v = valid ? xnb4[pg * 8 + q] : z;
      *(uint4*)&xls[idx * 36 + q * 4] = v;
    }
  }
  __syncthreads();

  f32x4 acc[4][4];
#pragma unroll
  for (int Nt = 0; Nt < 4; ++Nt) {
    float bb = bconv[Nt * 16 + l15];
#pragma unroll
    for (int mt = 0; mt < 4; ++mt) acc[mt][Nt] = (f32x4){bb, bb, bb, bb};
  }

  const uint4* wq = (const uint4*)wpk;   // uint4 idx = tap*512 + oc*8 + ks*4 + l4
#pragma unroll
  for (int tap = 0; tap < 9; ++tap) {
    int ky = tap / 3, kx = tap - ky * 3;
    int rowbase = (wv + ky) * 66 + kx + l15;
#pragma unroll
    for (int ks = 0; ks < 2; ++ks) {
      FU4 B[4];
#pragma unroll
      for (int Nt = 0; Nt < 4; ++Nt)
        B[Nt].v = wq[tap * 512 + (Nt * 16 + l15) * 8 + ks * 4 + l4];
#pragma unroll
      for (int mt = 0; mt < 4; ++mt) {
        FU4 A;
        A.v = *(const uint4*)&xls[(rowbase + mt * 16) * 36 + ks * 16 + l4 * 4];
#pragma unroll
        for (int Nt = 0; Nt < 4; ++Nt)
          acc[mt][Nt] = __builtin_amdgcn_mfma_f32_16x16x32_bf16(A.f, B[Nt].f, acc[mt][Nt], 0, 0, 0);
      }
    }
  }

#pragma unroll
  for (int Nt = 0; Nt < 4; ++Nt) {
    int oc = Nt * 16 + l15;
    int d = oc & 31;
    const float* resid = (oc < 32) ? xre : xim;
    float* dst = out + ((oc < 32) ? MAIN_RE : MAIN_IM) + (n * 32 + d) * 4096;
    const float* rsd = resid + (n * 32 + d) * 4096;
#pragma unroll
    for (int mt = 0; mt < 4; ++mt) {
      int pixbase = (y0 + wv) * 64 + mt * 16 + l4 * 4;
#pragma unroll
      for (int r = 0; r < 4; ++r)
        dst[pixbase + r] = rsd[pixbase + r] + acc[mt][Nt][r];
    }
  }
}

// ---------------- x_eig v2: bf16 MFMA dual-GEMM (eig 64->64, sg1 64->32) + channel sums ----
// 4 phases x 64 pixels. thread = (p64 = tid&63 pixel, q = tid>>6 channel-quarter).
// LDS aliasing: xp reused for xep; xef reused for gf — all alias pairs barrier-separated.
__global__ void __launch_bounds__(256) k_xeig(
    const float* __restrict__ out, const unsigned* __restrict__ weP,
    const unsigned* __restrict__ sgP, float* __restrict__ xe,
    float* __restrict__ g1, const float* __restrict__ sgb1,
    float* __restrict__ part) {
  __shared__ unsigned WeT[64][33];   // eig B [N=64][Kpair]
  __shared__ unsigned SgT[32][33];   // sg1 B [N=32][Kpair]
  __shared__ unsigned xp[64][33];    // x bf16 pairs [pix][Kpair]; later xep (xe bf16)
  __shared__ float xef[64][65];      // xe f32 [pix][ch]; later gf (g1 f32, ch 0..31)

  int tid = threadIdx.x;
  int gbase = blockIdx.x * 256;
  int l = tid & 63, wv = tid >> 6;
  int l15 = l & 15, l4 = l >> 4;
  int p64 = l, q = wv;

  // stage weights once
  {
#pragma unroll
    for (int i = 0; i < 8; ++i) {
      int idx = tid + i * 256;        // 0..2047
      WeT[idx >> 5][idx & 31] = weP[idx];
    }
#pragma unroll
    for (int i = 0; i < 4; ++i) {
      int idx = tid + i * 256;        // 0..1023
      SgT[idx >> 5][idx & 31] = sgP[idx];
    }
  }
  float sgb_l = sgb1[(wv & 1) * 16 + l15];  // bias for layer2 col (Nt = wv&1 unused; recompute below)
  (void)sgb_l;
  float ssum[16];
#pragma unroll
  for (int i = 0; i < 16; ++i) ssum[i] = 0.f;
  __syncthreads();

  for (int ph = 0; ph < 4; ++ph) {
    int gg = gbase + ph * 64 + p64;
    int n = gg >> 12, p = gg & 4095;

    // ---- step1: load x (k<32: re, k>=32: im), pack bf16 pairs ----
    float xv[16];
#pragma unroll
    for (int i = 0; i < 16; ++i) {
      int c = q * 16 + i;
      xv[i] = (c < 32) ? out[MAIN_RE + (n * 32 + c) * 4096 + p]
                       : out[MAIN_IM + (n * 32 + (c - 32)) * 4096 + p];
    }
#pragma unroll
    for (int ii = 0; ii < 8; ++ii)
      xp[p64][q * 8 + ii] = pk2(xv[2 * ii], xv[2 * ii + 1]);
    __syncthreads();   // A

    // ---- step2: layer1 MFMA (eig) ----
    int arow = wv * 16 + l15;
    FU a0, a1;
#pragma unroll
    for (int jj = 0; jj < 4; ++jj) {
      a0.u[jj] = xp[arow][l4 * 4 + jj];
      a1.u[jj] = xp[arow][16 + l4 * 4 + jj];
    }
#pragma unroll
    for (int Nt = 0; Nt < 4; ++Nt) {
      f32x4 acc = (f32x4){0.f, 0.f, 0.f, 0.f};
      FU b0f, b1f;
      int brow = Nt * 16 + l15;
#pragma unroll
      for (int jj = 0; jj < 4; ++jj) {
        b0f.u[jj] = WeT[brow][l4 * 4 + jj];
        b1f.u[jj] = WeT[brow][16 + l4 * 4 + jj];
      }
      acc = __builtin_amdgcn_mfma_f32_16x16x32_bf16(a0.f, b0f.f, acc, 0, 0, 0);
      acc = __builtin_amdgcn_mfma_f32_16x16x32_bf16(a1.f, b1f.f, acc, 0, 0, 0);
#pragma unroll
      for (int r = 0; r < 4; ++r)
        xef[wv * 16 + l4 * 4 + r][Nt * 16 + l15] = acc[r];
    }
    __syncthreads();   // B

    // ---- step3: read xef, write xe planes, accumulate sums, re-pack bf16 (xep=xp) ----
    float xo[16];
#pragma unroll
    for (int i = 0; i < 16; ++i) {
      xo[i] = xef[p64][q * 16 + i];
      ssum[i] += xo[i];
      xe[(q * 16 + i) * PIX + gg] = xo[i];
    }
#pragma unroll
    for (int ii = 0; ii < 8; ++ii)
      xp[p64][q * 8 + ii] = pk2(xo[2 * ii], xo[2 * ii + 1]);
    __syncthreads();   // C

    // ---- step4: layer2 MFMA (sg1) + silu -> gf (= xef cols 0..31) ----
    FU c0, c1;
#pragma unroll
    for (int jj = 0; jj < 4; ++jj) {
      c0.u[jj] = xp[arow][l4 * 4 + jj];
      c1.u[jj] = xp[arow][16 + l4 * 4 + jj];
    }
#pragma unroll
    for (int Nt = 0; Nt < 2; ++Nt) {
      float bb = sgb1[Nt * 16 + l15];
      f32x4 acc = (f32x4){bb, bb, bb, bb};
      FU b0f, b1f;
      int brow = Nt * 16 + l15;
#pragma unroll
      for (int jj = 0; jj < 4; ++jj) {
        b0f.u[jj] = SgT[brow][l4 * 4 + jj];
        b1f.u[jj] = SgT[brow][16 + l4 * 4 + jj];
      }
      acc = __builtin_amdgcn_mfma_f32_16x16x32_bf16(c0.f, b0f.f, acc, 0, 0, 0);
      acc = __builtin_amdgcn_mfma_f32_16x16x32_bf16(c1.f, b1f.f, acc, 0, 0, 0);
#pragma unroll
      for (int r = 0; r < 4; ++r) {
        float v = acc[r];
        xef[wv * 16 + l4 * 4 + r][Nt * 16 + l15] = v * sigmoidf_(v);
      }
    }
    __syncthreads();   // D

    // ---- step5: write g1 planes (thread: 8 channels) ----
#pragma unroll
    for (int i = 0; i < 8; ++i)
      g1[(q * 8 + i) * PIX + gg] = xef[p64][q * 8 + i];
  }

  // ---- channel-sum reduce (fixed shuffle order -> deterministic) ----
#pragma unroll
  for (int i = 0; i < 16; ++i) {
    float v = ssum[i];
    v += __shfl_xor(v, 1);
    v += __shfl_xor(v, 2);
    v += __shfl_xor(v, 4);
    v += __shfl_xor(v, 8);
    v += __shfl_xor(v, 16);
    v += __shfl_xor(v, 32);
    if (l == 0) part[blockIdx.x * 64 + q * 16 + i] = v;
  }
}

// ---------------- flux scan (T=24) + all per-(b,t,d) coefficients ----------------
__global__ void k_flux(float* __restrict__ ws, float* __restrict__ out,
                       const float* __restrict__ dt_seq,
                       const float* __restrict__ flux_re, const float* __restrict__ flux_im,
                       const float* __restrict__ lam_flux,
                       const float* __restrict__ bf_re, const float* __restrict__ bf_im,
                       const float* __restrict__ c_re, const float* __restrict__ c_im,
                       const float* __restrict__ g_w, const float* __restrict__ g_b,
                       const float* __restrict__ a_decay, const float* __restrict__ b_freq) {
  int tid = threadIdx.x;
  if (tid >= 64) return;
  int b = tid >> 5, e = tid & 31;
  float sp_lf = softplusf_(lam_flux[e]);
  float lr = -softplusf_(a_decay[e]);
  float li = b_freq[e];
  float den = lr * lr + li * li;
  float bfr = bf_re[e], bfi = bf_im[e];
  float cr = c_re[e], ci = c_im[e];
  float fr = flux_re[b * 32 + e], fi = flux_im[b * 32 + e];
  const float* part = ws + WS_PART;
  for (int t = 0; t < 24; ++t) {
    int n = b * 24 + t;
    float dt = dt_seq[n];
    float A = expf(-sp_lf * dt);
    float xmr = 0.f, xmi = 0.f;
#pragma unroll
    for (int j = 0; j < 16; ++j) {
      xmr += part[(n * 16 + j) * 64 + e];
      xmi += part[(n * 16 + j) * 64 + 32 + e];
    }
    xmr *= (1.f / 4096.f);
    xmi *= (1.f / 4096.f);
    float Xr = (bfr * xmr - bfi * xmi) * dt;
    float Xi = (bfr * xmi + bfi * xmr) * dt;
    fr = A * fr + Xr;
    fi = A * fi + Xi;
    ws[WS_GATE + n * 32 + e] = sigmoidf_(fr * g_w[e] + g_b[e]);
    ws[WS_SRCR + n * 32 + e] = fr * cr - fi * ci;
    ws[WS_SRCI + n * 32 + e] = fr * ci + fi * cr;
    float er = expf(lr * dt);
    float odr = er * cosf(li * dt);
    float odi = er * sinf(li * dt);
    ws[WS_ODR + n * 32 + e] = odr;
    ws[WS_ODI + n * 32 + e] = odi;
    float nr = odr - 1.f, ni = odi;
    ws[WS_OFR + n * 32 + e] = (nr * lr + ni * li) / den;
    ws[WS_OFI + n * 32 + e] = (ni * lr - nr * li) / den;
  }
  out[FLUX_RE + b * 32 + e] = fr;
  out[FLUX_IM + b * 32 + e] = fi;
}

// ---------------- spatial gate 2: depthwise 3x3 on planes ----------------
__global__ void __launch_bounds__(256) k_sgdw(
    const float* __restrict__ g1, float* __restrict__ g2, const float* __restrict__ dw) {
  int g = blockIdx.x * 256 + threadIdx.x;
  int oc = blockIdx.y;                  // block-uniform
  int n = g >> 12, p = g & 4095;
  int y = p >> 6, x = p & 63;
  const float* src = g1 + oc * PIX + n * 4096;
  const float* w = dw + oc * 9;         // uniform -> s_load
  float acc = 0.f;
#pragma unroll
  for (int ky = 0; ky < 3; ++ky) {
    int yy = y + ky - 1;
    if ((unsigned)yy < 64u) {
#pragma unroll
      for (int kx = 0; kx < 3; ++kx) {
        int xx = x + kx - 1;
        if ((unsigned)xx < 64u)
          acc = fmaf(src[yy * 64 + xx], w[ky * 3 + kx], acc);
      }
    }
  }
  g2[oc * PIX + g] = acc;
}

// ---------------- sg3 (1x1 32->32 + sigmoid) fused with forcing -> u_t ----------------
__global__ void __launch_bounds__(256) k_force(
    const float* __restrict__ g2p, float* __restrict__ xe,
    const float* __restrict__ gate, const float* __restrict__ srcr,
    const float* __restrict__ srci, const float* __restrict__ ofr_p,
    const float* __restrict__ ofi_p, const float* __restrict__ odr_p,
    const float* __restrict__ odi_p,
    const float* __restrict__ hre, const float* __restrict__ him,
    const float* __restrict__ w2, const float* __restrict__ b2) {
  int g = blockIdx.x * 256 + threadIdx.x;
  int n = g >> 12, p = g & 4095;
  int b = (n >= 24) ? 1 : 0;
  int t = n - b * 24;
  float v[32];
#pragma unroll
  for (int c = 0; c < 32; ++c) v[c] = g2p[c * PIX + g];
  float spg[32];
#pragma unroll
  for (int o0 = 0; o0 < 32; o0 += 4) {
    float acc[4] = {b2[o0], b2[o0 + 1], b2[o0 + 2], b2[o0 + 3]};
#pragma unroll
    for (int c = 0; c < 32; ++c) {
#pragma unroll
      for (int j = 0; j < 4; ++j)
        acc[j] = fmaf(v[c], w2[(o0 + j) * 32 + c], acc[j]);   // uniform -> s_load
    }
#pragma unroll
    for (int j = 0; j < 4; ++j) spg[o0 + j] = sigmoidf_(acc[j]);
  }
#pragma unroll
  for (int e = 0; e < 32; ++e) {
    int ie = n * 32 + e;
    float gc = gate[ie] * spg[e];
    float xr = xe[e * PIX + g];
    float xi = xe[(32 + e) * PIX + g];
    float om = 1.f - gc;
    float fr2 = xr * gc + srcr[ie] * om;
    float fi2 = xi * gc + srci[ie] * om;
    float ofr = ofr_p[ie], ofi = ofi_p[ie];
    float ur = fr2 * ofr - fi2 * ofi;
    float ui = fr2 * ofi + fi2 * ofr;
    if (t == 0) {                       // wave-uniform branch
      int hb = (b * 4096 + p) * 32 + e;
      float hr = hre[hb], hi = him[hb];
      float odr = odr_p[(b * 24) * 32 + e], odi = odi_p[(b * 24) * 32 + e];
      ur += hr * odr - hi * odi;
      ui += hr * odi + hi * odr;
    }
    xe[e * PIX + g] = ur;
    xe[(32 + e) * PIX + g] = ui;
  }
}

// ---------------- temporal scan over T=24 on planes (in place), emit h_out ----------------
__global__ void __launch_bounds__(256) k_scan(
    float* __restrict__ u, const float* __restrict__ odr_p,
    const float* __restrict__ odi_p, float* __restrict__ out) {
  int p = blockIdx.x * 256 + threadIdx.x;   // 0..4095
  int e = blockIdx.y;                        // 0..31 (block-uniform)
  int b = blockIdx.z;                        // 0..1
  float ur = 0.f, ui = 0.f;
  for (int t = 0; t < 24; ++t) {
    int n = b * 24 + t;
    int idx  = e * PIX + n * 4096 + p;
    int idxi = (32 + e) * PIX + n * 4096 + p;
    float ar = odr_p[n * 32 + e];            // uniform -> s_load
    float ai = odi_p[n * 32 + e];
    float xr = u[idx], xi = u[idxi];
    float nr = ar * ur - ai * ui + xr;
    float ni = ar * ui + ai * ur + xi;
    ur = nr; ui = ni;
    u[idx] = ur;
    u[idxi] = ui;
  }
  out[HOUT_RE + (b * 4096 + p) * 32 + e] = ur;
  out[HOUT_IM + (b * 4096 + p) * 32 + e] = ui;
}

// ---------------- dec = u_out @ Wb_inv : thread-per-pixel, planes -> planes ----------------
__global__ void __launch_bounds__(256) k_dec(
    const float* __restrict__ u, const float* __restrict__ winv,
    float* __restrict__ dec) {
  int g = blockIdx.x * 256 + threadIdx.x;
  float ur[32], ui[32];
#pragma unroll
  for (int e = 0; e < 32; ++e) ur[e] = u[e * PIX + g];
#pragma unroll
  for (int e = 0; e < 32; ++e) ui[e] = u[(32 + e) * PIX + g];
#pragma unroll
  for (int d0 = 0; d0 < 32; d0 += 4) {
    float ar[4] = {0.f, 0.f, 0.f, 0.f}, ai[4] = {0.f, 0.f, 0.f, 0.f};
#pragma unroll
    for (int e = 0; e < 32; ++e) {
      float r = ur[e], im = ui[e];
#pragma unroll
      for (int j = 0; j < 4; ++j) {
        float wr = winv[e * 32 + d0 + j];         // uniform -> s_load
        float wi = winv[1024 + e * 32 + d0 + j];
        ar[j] += r * wr - im * wi;
        ai[j] += r * wi + im * wr;
      }
    }
#pragma unroll
    for (int j = 0; j < 4; ++j) {
      dec[(d0 + j) * PIX + g] = ar[j];
      dec[(32 + d0 + j) * PIX + g] = ai[j];
    }
  }
}

// ---------------- LN_t + FFN (64->128->64) via bf16 MFMA + z = x_upd + dec + delta ----------
__global__ void __launch_bounds__(256) k_final(
    const float* __restrict__ dec, float* __restrict__ out,
    const float* __restrict__ lg, const float* __restrict__ lb,
    const float* __restrict__ w1, const float* __restrict__ b1,
    const float* __restrict__ w2, const float* __restrict__ b2) {
  __shared__ unsigned w1T[128][33];   // [hid][c-pair]  bf16x2, +1 pad
  __shared__ unsigned w2T[64][65];    // [out][h-pair]  bf16x2, +1 pad
  __shared__ unsigned dnp[64][33];    // [pix][c-pair]  bf16x2
  __shared__ unsigned ho[64][65];     // union: ushort[64][130] hid bf16 / float[64][65] o2
  __shared__ float ps1[64][5];        // LN partial sums (stride 5 -> conflict-free)
  __shared__ float ps2[64][5];

  int tid = threadIdx.x;
  int gbase = blockIdx.x * 256;
  int l = tid & 63, wv = tid >> 6;
  int l15 = l & 15, l4 = l >> 4;
  int p64 = l, q = wv;                // LN/epilogue mapping: pixel, channel-quarter

  {
    int hid = tid & 127, half = tid >> 7;
#pragma unroll
    for (int i = 0; i < 16; ++i) {
      int cp = half * 16 + i;
      w1T[hid][cp] = pk2(w1[(2 * cp) * 128 + hid], w1[(2 * cp + 1) * 128 + hid]);
    }
#pragma unroll
    for (int i = 0; i < 16; ++i) {
      int hp = wv * 16 + i;
      w2T[l][hp] = pk2(w2[(2 * hp) * 64 + l], w2[(2 * hp + 1) * 64 + l]);
    }
  }
  float bb1v[8], bb2v[4];
#pragma unroll
  for (int Hn = 0; Hn < 8; ++Hn) bb1v[Hn] = b1[Hn * 16 + l15];
#pragma unroll
  for (int On = 0; On < 4; ++On) bb2v[On] = b2[On * 16 + l15];
  __syncthreads();

  for (int ph = 0; ph < 4; ++ph) {
    int gg = gbase + ph * 64 + p64;

    float dv[16];
    float s1 = 0.f, s2 = 0.f;
#pragma unroll
    for (int i = 0; i < 16; ++i) {
      dv[i] = dec[(q * 16 + i) * PIX + gg];
      s1 += dv[i];
      s2 += dv[i] * dv[i];
    }
    ps1[p64][q] = s1;
    ps2[p64][q] = s2;
    __syncthreads();
    float m  = (ps1[p64][0] + ps1[p64][1] + ps1[p64][2] + ps1[p64][3]) * (1.f / 64.f);
    float e2 = (ps2[p64][0] + ps2[p64][1] + ps2[p64][2] + ps2[p64][3]) * (1.f / 64.f);
    float rs = rsqrtf(e2 - m * m + 1e-5f);
#pragma unroll
    for (int ii = 0; ii < 8; ++ii) {
      int c0 = q * 16 + 2 * ii;
      float a = (dv[2 * ii]     - m) * rs * lg[c0]     + lb[c0];
      float bvl = (dv[2 * ii + 1] - m) * rs * lg[c0 + 1] + lb[c0 + 1];
      dnp[p64][q * 8 + ii] = pk2(a, bvl);
    }
    __syncthreads();

    int arow = wv * 16 + l15;
    FU a0, a1;
#pragma unroll
    for (int jj = 0; jj < 4; ++jj) {
      a0.u[jj] = dnp[arow][l4 * 4 + jj];
      a1.u[jj] = dnp[arow][16 + l4 * 4 + jj];
    }
    f32x4 acc[8];
#pragma unroll
    for (int Hn = 0; Hn < 8; ++Hn) {
      float bb = bb1v[Hn];
      acc[Hn] = (f32x4){bb, bb, bb, bb};
      FU b0f, b1f;
      int brow = Hn * 16 + l15;
#pragma unroll
      for (int jj = 0; jj < 4; ++jj) {
        b0f.u[jj] = w1T[brow][l4 * 4 + jj];
        b1f.u[jj] = w1T[brow][16 + l4 * 4 + jj];
      }
      acc[Hn] = __builtin_amdgcn_mfma_f32_16x16x32_bf16(a0.f, b0f.f, acc[Hn], 0, 0, 0);
      acc[Hn] = __builtin_amdgcn_mfma_f32_16x16x32_bf16(a1.f, b1f.f, acc[Hn], 0, 0, 0);
    }
    unsigned short (*hidb)[130] = (unsigned short(*)[130])ho;
#pragma unroll
    for (int Hn = 0; Hn < 8; ++Hn) {
#pragma unroll
      for (int r = 0; r < 4; ++r) {
        float v = acc[Hn][r];
        v = v * sigmoidf_(v);
        hidb[wv * 16 + l4 * 4 + r][Hn * 16 + l15] = f2bf(v);
      }
    }
    __syncthreads();   // FENCE: ushort hid stores complete before unsigned a2 loads (TBAA)

    FU a2[4];
#pragma unroll
    for (int kk = 0; kk < 4; ++kk)
#pragma unroll
      for (int jj = 0; jj < 4; ++jj)
        a2[kk].u[jj] = ((unsigned(*)[65])ho)[arow][kk * 16 + l4 * 4 + jj];
    f32x4 acc2[4];
#pragma unroll
    for (int On = 0; On < 4; ++On) {
      float bb = bb2v[On];
      acc2[On] = (f32x4){bb, bb, bb, bb};
#pragma unroll
      for (int kk = 0; kk < 4; ++kk) {
        FU b2f;
#pragma unroll
        for (int jj = 0; jj < 4; ++jj)
          b2f.u[jj] = w2T[On * 16 + l15][kk * 16 + l4 * 4 + jj];
        acc2[On] = __builtin_amdgcn_mfma_f32_16x16x32_bf16(a2[kk].f, b2f.f, acc2[On], 0, 0, 0);
      }
    }
    float (*o2f)[65] = (float(*)[65])ho;
#pragma unroll
    for (int On = 0; On < 4; ++On)
#pragma unroll
      for (int r = 0; r < 4; ++r)
        o2f[wv * 16 + l4 * 4 + r][On * 16 + l15] = acc2[On][r];
    __syncthreads();

    {
      int nn = gg >> 12, pim = gg & 4095;
#pragma unroll
      for (int i = 0; i < 16; ++i) {
        int c = q * 16 + i;
        float val = o2f[p64][c] + dv[i];
        int d = c & 31;
        long off = ((c < 32) ? (long)MAIN_RE : (long)MAIN_IM) + (long)(nn * 32 + d) * 4096 + pim;
        out[off] += val;
      }
    }
  }
}

extern "C" void kernel_launch(void* const* d_in, const int* in_sizes, int n_in,
                              void* d_out, int out_size, void* d_ws, size_t ws_size,
                              hipStream_t stream) {
  (void)in_sizes; (void)n_in; (void)out_size; (void)ws_size;
  const float* xre      = (const float*)d_in[0];
  const float* xim      = (const float*)d_in[1];
  const float* hre      = (const float*)d_in[2];
  const float* him      = (const float*)d_in[3];
  const float* flux_re  = (const float*)d_in[4];
  const float* flux_im  = (const float*)d_in[5];
  const float* dt_seq   = (const float*)d_in[6];
  const float* ln_s_g   = (const float*)d_in[7];
  const float* ln_s_b   = (const float*)d_in[8];
  const float* conv_w   = (const float*)d_in[9];
  const float* conv_b   = (const float*)d_in[10];
  const float* ln_t_g   = (const float*)d_in[11];
  const float* ln_t_b   = (const float*)d_in[12];
  const float* W_re     = (const float*)d_in[13];
  const float* W_im     = (const float*)d_in[14];
  const float* lam_flux = (const float*)d_in[15];
  const float* bf_re    = (const float*)d_in[16];
  const float* bf_im    = (const float*)d_in[17];
  const float* c_re     = (const float*)d_in[18];
  const float* c_im     = (const float*)d_in[19];
  const float* g_w      = (const float*)d_in[20];
  const float* g_b      = (const float*)d_in[21];
  const float* a_decay  = (const float*)d_in[22];
  const float* b_freq   = (const float*)d_in[23];
  const float* ffn_w1   = (const float*)d_in[24];
  const float* ffn_b1   = (const float*)d_in[25];
  const float* ffn_w2   = (const float*)d_in[26];
  const float* ffn_b2   = (const float*)d_in[27];
  const float* sg_w1    = (const float*)d_in[28];
  const float* sg_b1    = (const float*)d_in[29];
  const float* sg_dw    = (const float*)d_in[30];
  const float* sg_w2    = (const float*)d_in[31];
  const float* sg_b2    = (const float*)d_in[32];
  float* out = (float*)d_out;
  float* ws  = (float*)d_ws;

  k_invert<<<1, 256, 0, stream>>>(W_re, W_im, ws);
  k_wprep<<<144, 256, 0, stream>>>(conv_w, (unsigned short*)(ws + WS_WPK));
  k_eprep<<<8, 256, 0, stream>>>(W_re, W_im, sg_w1,
                                 (unsigned*)(ws + WS_WE), (unsigned*)(ws + WS_SG));
  k_ln_s<<<PIX / 256, 256, 0, stream>>>(xre, xim, ln_s_g, ln_s_b, ws);
  k_conv<<<768, 256, 0, stream>>>((const unsigned*)(ws + WS_XN),
                                  (const unsigned short*)(ws + WS_WPK),
                                  conv_b, xre, xim, out);
  k_xeig<<<768, 256, 0, stream>>>(out, (const unsigned*)(ws + WS_WE),
                                  (const unsigned*)(ws + WS_SG),
                                  ws + WS_XE, ws + WS_G1, sg_b1, ws + WS_PART);
  k_flux<<<1, 64, 0, stream>>>(ws, out, dt_seq, flux_re, flux_im, lam_flux,
                               bf_re, bf_im, c_re, c_im, g_w, g_b, a_decay, b_freq);
  k_sgdw<<<dim3(PIX / 256, 32), 256, 0, stream>>>(ws + WS_G1, ws + WS_G2, sg_dw);
  k_force<<<PIX / 256, 256, 0, stream>>>(ws + WS_G2, ws + WS_XE,
                                         ws + WS_GATE, ws + WS_SRCR, ws + WS_SRCI,
                                         ws + WS_OFR, ws + WS_OFI, ws + WS_ODR, ws + WS_ODI,
                                         hre, him, sg_w2, sg_b2);
  k_scan<<<dim3(4096 / 256, 32, 2), 256, 0, stream>>>(ws + WS_XE, ws + WS_ODR, ws + WS_ODI, out);
  k_dec<<<PIX / 256, 256, 0, stream>>>(ws + WS_XE, ws + WS_WINV, ws + WS_XN);
  k_final<<<PIX / 256, 256, 0, stream>>>(ws + WS_XN, out, ln_t_g, ln_t_b,
                                         ffn_w1, ffn_b1, ffn_w2, ffn_b2);
}

// Round 11
// 391.487 us; speedup vs baseline: 7.5030x; 1.2201x over previous
//
#include <hip/hip_runtime.h>
#include <math.h>

#define BB 2
#define TT 24
#define DD 32
#define HWp 4096            // 64*64
#define NN (BB*TT)          // 48
#define PIX (NN*HWp)        // 196608
#define C2 (2*DD)           // 64

// d_out offsets (floats)
#define MAIN_RE 0
#define MAIN_IM (NN*DD*HWp)              // 6291456
#define HOUT_RE (2*NN*DD*HWp)            // 12582912
#define HOUT_IM (HOUT_RE + BB*HWp*DD)    // 12845056
#define FLUX_RE (HOUT_RE + 2*BB*HWp*DD)  // 13107200
#define FLUX_IM (FLUX_RE + BB*DD)        // 13107264

// ws offsets (floats)
#define WS_XN   0                        // PIX*64 (bf16 xn for conv)
#define WS_XE   (WS_XN + PIX*C2)         // PIX*64  xe -> u_t -> u_out planes
#define WS_G1   (WS_XE + PIX*C2)         // PIX*32  g1 planes
#define WS_G2   (WS_G1 + PIX*DD)         // PIX*32  (free now)
#define WS_WINV (WS_G2 + PIX*DD)         // 2048 f32 (kept, unused downstream)
#define WS_SUMS (WS_WINV + 2048)         // 3072 (unused)
#define WS_GATE (WS_SUMS + 3072)         // 1536
#define WS_SRCR (WS_GATE + 1536)
#define WS_SRCI (WS_SRCR + 1536)
#define WS_ODR  (WS_SRCI + 1536)
#define WS_ODI  (WS_ODR + 1536)
#define WS_OFR  (WS_ODI + 1536)
#define WS_OFI  (WS_OFR + 1536)
#define WS_WPK  (WS_OFI + 1536)          // 36864 ushorts = 18432 floats
#define WS_PART (WS_WPK + 18432)         // 48*16*64 floats
#define WS_WE   (WS_PART + 49152)        // 2048 u32 eig weights
#define WS_SG   (WS_WE + 2048)           // 1024 u32 sg1 weights
#define WS_WIB  (WS_SG + 1024)           // 2048 u32 Winv packed bf16 B-frag

typedef __attribute__((ext_vector_type(8))) short bf16x8;
typedef __attribute__((ext_vector_type(4))) float f32x4;
union FU { unsigned u[4]; bf16x8 f; };
union FU4 { uint4 v; unsigned u[4]; bf16x8 f; };

__device__ __forceinline__ float sigmoidf_(float x) { return 1.f / (1.f + expf(-x)); }
__device__ __forceinline__ float softplusf_(float x) { return log1pf(expf(x)); }
__device__ __forceinline__ unsigned short f2bf(float f) {
  unsigned u = __float_as_uint(f);
  return (unsigned short)((u + 0x7FFFu + ((u >> 16) & 1u)) >> 16);   // RNE
}
__device__ __forceinline__ unsigned pk2(float lo, float hi) {
  return (unsigned)f2bf(lo) | ((unsigned)f2bf(hi) << 16);
}

// ---------------- Gauss-Jordan inverse of Wb (32x32 complex) + bf16 B-frag pack ----------
__global__ void k_invert(const float* __restrict__ Wre, const float* __restrict__ Wim,
                         float* __restrict__ ws) {
  __shared__ float Mre[32][64];
  __shared__ float Mim[32][64];
  __shared__ float fre[32], fim[32];
  __shared__ float pr_s, pi_s;
  __shared__ int piv_s;
  int tid = threadIdx.x;  // 256 threads
  for (int idx = tid; idx < 2048; idx += 256) {
    int i = idx >> 6, j = idx & 63;
    if (j < 32) { Mre[i][j] = Wre[i * 32 + j]; Mim[i][j] = Wim[i * 32 + j]; }
    else        { Mre[i][j] = (j - 32 == i) ? 1.f : 0.f; Mim[i][j] = 0.f; }
  }
  __syncthreads();
  for (int k = 0; k < 32; ++k) {
    if (tid == 0) {
      int best = k; float bm = fabsf(Mre[k][k]) + fabsf(Mim[k][k]);
      for (int r = k + 1; r < 32; ++r) {
        float m = fabsf(Mre[r][k]) + fabsf(Mim[r][k]);
        if (m > bm) { bm = m; best = r; }
      }
      piv_s = best;
    }
    __syncthreads();
    int pv = piv_s;
    if (pv != k && tid < 64) {
      float tr = Mre[k][tid], ti = Mim[k][tid];
      Mre[k][tid] = Mre[pv][tid]; Mim[k][tid] = Mim[pv][tid];
      Mre[pv][tid] = tr; Mim[pv][tid] = ti;
    }
    __syncthreads();
    if (tid == 0) {
      float a = Mre[k][k], b = Mim[k][k];
      float d = a * a + b * b;
      pr_s = a / d; pi_s = -b / d;
    }
    __syncthreads();
    float pr = pr_s, pi = pi_s;
    if (tid < 64) {
      float a = Mre[k][tid], b = Mim[k][tid];
      Mre[k][tid] = a * pr - b * pi;
      Mim[k][tid] = a * pi + b * pr;
    }
    __syncthreads();
    if (tid < 32) { fre[tid] = Mre[tid][k]; fim[tid] = Mim[tid][k]; }
    __syncthreads();
    for (int idx = tid; idx < 2048; idx += 256) {
      int i = idx >> 6, j = idx & 63;
      if (i != k) {
        float fr = fre[i], fi = fim[i];
        float ar = Mre[k][j], ai = Mim[k][j];
        Mre[i][j] -= fr * ar - fi * ai;
        Mim[i][j] -= fr * ai + fi * ar;
      }
    }
    __syncthreads();
  }
  for (int idx = tid; idx < 1024; idx += 256) {
    int e = idx >> 5, d = idx & 31;
    ws[WS_WINV + e * 32 + d] = Mre[e][32 + d];
    ws[WS_WINV + 1024 + e * 32 + d] = Mim[e][32 + d];
  }
  // pack Winv as bf16 B-fragment [j][kpair]: dec[j] = sum_k u[k]*V[k][j]
  unsigned* wib = (unsigned*)(ws + WS_WIB);
  for (int idx = tid; idx < 2048; idx += 256) {
    int j = idx >> 5, kp = idx & 31;
    float v[2];
#pragma unroll
    for (int h = 0; h < 2; ++h) {
      int k = 2 * kp + h;
      float x;
      if (j < 32) x = (k < 32) ? Mre[k][32 + j] : -Mim[k - 32][32 + j];
      else        x = (k < 32) ? Mim[k][32 + (j - 32)] : Mre[k - 32][32 + (j - 32)];
      v[h] = x;
    }
    wib[idx] = pk2(v[0], v[1]);
  }
}

// ---------------- weight pre-pack: wpack[tap][oc][ci] bf16 <- conv_w[oc][ci][tap] f32 ----
__global__ void k_wprep(const float* __restrict__ w, unsigned short* __restrict__ wpk) {
  int idx = blockIdx.x * 256 + threadIdx.x;
  if (idx >= 9 * 64 * 64) return;
  int tap = idx >> 12;
  int rem = idx & 4095;
  int oc = rem >> 6, ci = rem & 63;
  wpk[idx] = f2bf(w[(oc * 64 + ci) * 9 + tap]);
}

// ---------------- eig + sg1 weight pre-pack (bf16 [N][Kpair] B-fragment layout) ----------
__global__ void k_eprep(const float* __restrict__ Wre, const float* __restrict__ Wim,
                        const float* __restrict__ sgw1,
                        unsigned* __restrict__ we, unsigned* __restrict__ sg) {
  int idx = blockIdx.x * 256 + threadIdx.x;
  if (idx < 2048) {
    int j = idx >> 5, kp = idx & 31;
    float v[2];
#pragma unroll
    for (int h = 0; h < 2; ++h) {
      int k = 2 * kp + h;
      float x;
      if (j < 32) x = (k < 32) ? Wre[k * 32 + j] : -Wim[(k - 32) * 32 + j];
      else        x = (k < 32) ? Wim[k * 32 + (j - 32)] : Wre[(k - 32) * 32 + (j - 32)];
      v[h] = x;
    }
    we[idx] = pk2(v[0], v[1]);
  }
  if (idx < 1024) {
    int oc = idx >> 5, kp = idx & 31;
    sg[idx] = pk2(sgw1[oc * 64 + 2 * kp], sgw1[oc * 64 + 2 * kp + 1]);
  }
}

// ---------------- spatial LayerNorm -> xn bf16 channels-last [n][pix][64] ----------------
__global__ void k_ln_s(const float* __restrict__ xre, const float* __restrict__ xim,
                       const float* __restrict__ g, const float* __restrict__ b,
                       float* __restrict__ ws) {
  int gid = blockIdx.x * 256 + threadIdx.x;
  if (gid >= PIX) return;
  int n = gid >> 12, p = gid & 4095;
  float v[64];
  float s = 0.f;
#pragma unroll
  for (int c = 0; c < 32; ++c) { v[c] = xre[(n * 32 + c) * 4096 + p]; s += v[c]; }
#pragma unroll
  for (int c = 0; c < 32; ++c) { v[32 + c] = xim[(n * 32 + c) * 4096 + p]; s += v[32 + c]; }
  float m = s * (1.f / 64.f);
  float vs = 0.f;
#pragma unroll
  for (int c = 0; c < 64; ++c) { float d = v[c] - m; vs += d * d; }
  float rs = rsqrtf(vs * (1.f / 64.f) + 1e-5f);
#pragma unroll
  for (int c = 0; c < 64; ++c) v[c] = (v[c] - m) * rs * g[c] + b[c];
  uint4* dst = (uint4*)ws + gid * 8;
#pragma unroll
  for (int q = 0; q < 8; ++q) {
    uint4 u;
    u.x = pk2(v[q * 8 + 0], v[q * 8 + 1]);
    u.y = pk2(v[q * 8 + 2], v[q * 8 + 3]);
    u.z = pk2(v[q * 8 + 4], v[q * 8 + 5]);
    u.w = pk2(v[q * 8 + 6], v[q * 8 + 7]);
    dst[q] = u;
  }
}

// ---------------- 3x3 conv 64->64 as 9 shifted bf16 MFMA GEMMs ----------------
__global__ void __launch_bounds__(256) k_conv(
    const unsigned* __restrict__ xnb_u, const unsigned short* __restrict__ wpk,
    const float* __restrict__ bconv,
    const float* __restrict__ xre, const float* __restrict__ xim,
    float* __restrict__ out) {
  __shared__ unsigned xls[6 * 66 * 36];
  int bid = blockIdx.x;
  int n = bid >> 4;
  int y0 = (bid & 15) * 4;
  int tid = threadIdx.x;
  int wv = tid >> 6, l = tid & 63;
  int l15 = l & 15, l4 = l >> 4;

  const uint4* xnb4 = (const uint4*)xnb_u;
  for (int idx = tid; idx < 396; idx += 256) {
    int r = idx / 66, c = idx - r * 66;
    int y = y0 - 1 + r, x = c - 1;
    bool valid = ((unsigned)y < 64u) & ((unsigned)x < 64u);
    int pg = n * 4096 + y * 64 + x;
    uint4 z; z.x = z.y = z.z = z.w = 0u;
#pragma unroll
    for (int q = 0; q < 8; ++q) {
      uint4 v = valid ? xnb4[pg * 8 + q] : z;
      *(uint4*)&xls[idx * 36 + q * 4] = v;
    }
  }
  __syncthreads();

  f32x4 acc[4][4];
#pragma unroll
  for (int Nt = 0; Nt < 4; ++Nt) {
    float bb = bconv[Nt * 16 + l15];
#pragma unroll
    for (int mt = 0; mt < 4; ++mt) acc[mt][Nt] = (f32x4){bb, bb, bb, bb};
  }

  const uint4* wq = (const uint4*)wpk;
#pragma unroll
  for (int tap = 0; tap < 9; ++tap) {
    int ky = tap / 3, kx = tap - ky * 3;
    int rowbase = (wv + ky) * 66 + kx + l15;
#pragma unroll
    for (int ks = 0; ks < 2; ++ks) {
      FU4 B[4];
#pragma unroll
      for (int Nt = 0; Nt < 4; ++Nt)
        B[Nt].v = wq[tap * 512 + (Nt * 16 + l15) * 8 + ks * 4 + l4];
#pragma unroll
      for (int mt = 0; mt < 4; ++mt) {
        FU4 A;
        A.v = *(const uint4*)&xls[(rowbase + mt * 16) * 36 + ks * 16 + l4 * 4];
#pragma unroll
        for (int Nt = 0; Nt < 4; ++Nt)
          acc[mt][Nt] = __builtin_amdgcn_mfma_f32_16x16x32_bf16(A.f, B[Nt].f, acc[mt][Nt], 0, 0, 0);
      }
    }
  }

#pragma unroll
  for (int Nt = 0; Nt < 4; ++Nt) {
    int oc = Nt * 16 + l15;
    int d = oc & 31;
    const float* resid = (oc < 32) ? xre : xim;
    float* dst = out + ((oc < 32) ? MAIN_RE : MAIN_IM) + (n * 32 + d) * 4096;
    const float* rsd = resid + (n * 32 + d) * 4096;
#pragma unroll
    for (int mt = 0; mt < 4; ++mt) {
      int pixbase = (y0 + wv) * 64 + mt * 16 + l4 * 4;
#pragma unroll
      for (int r = 0; r < 4; ++r)
        dst[pixbase + r] = rsd[pixbase + r] + acc[mt][Nt][r];
    }
  }
}

// ---------------- x_eig v2: bf16 MFMA dual-GEMM (eig 64->64, sg1 64->32) + channel sums ----
__global__ void __launch_bounds__(256) k_xeig(
    const float* __restrict__ out, const unsigned* __restrict__ weP,
    const unsigned* __restrict__ sgP, float* __restrict__ xe,
    float* __restrict__ g1, const float* __restrict__ sgb1,
    float* __restrict__ part) {
  __shared__ unsigned WeT[64][33];
  __shared__ unsigned SgT[32][33];
  __shared__ unsigned xp[64][33];
  __shared__ float xef[64][65];

  int tid = threadIdx.x;
  int gbase = blockIdx.x * 256;
  int l = tid & 63, wv = tid >> 6;
  int l15 = l & 15, l4 = l >> 4;
  int p64 = l, q = wv;

  {
#pragma unroll
    for (int i = 0; i < 8; ++i) {
      int idx = tid + i * 256;
      WeT[idx >> 5][idx & 31] = weP[idx];
    }
#pragma unroll
    for (int i = 0; i < 4; ++i) {
      int idx = tid + i * 256;
      SgT[idx >> 5][idx & 31] = sgP[idx];
    }
  }
  float ssum[16];
#pragma unroll
  for (int i = 0; i < 16; ++i) ssum[i] = 0.f;
  __syncthreads();

  for (int ph = 0; ph < 4; ++ph) {
    int gg = gbase + ph * 64 + p64;
    int n = gg >> 12, p = gg & 4095;

    float xv[16];
#pragma unroll
    for (int i = 0; i < 16; ++i) {
      int c = q * 16 + i;
      xv[i] = (c < 32) ? out[MAIN_RE + (n * 32 + c) * 4096 + p]
                       : out[MAIN_IM + (n * 32 + (c - 32)) * 4096 + p];
    }
#pragma unroll
    for (int ii = 0; ii < 8; ++ii)
      xp[p64][q * 8 + ii] = pk2(xv[2 * ii], xv[2 * ii + 1]);
    __syncthreads();   // A

    int arow = wv * 16 + l15;
    FU a0, a1;
#pragma unroll
    for (int jj = 0; jj < 4; ++jj) {
      a0.u[jj] = xp[arow][l4 * 4 + jj];
      a1.u[jj] = xp[arow][16 + l4 * 4 + jj];
    }
#pragma unroll
    for (int Nt = 0; Nt < 4; ++Nt) {
      f32x4 acc = (f32x4){0.f, 0.f, 0.f, 0.f};
      FU b0f, b1f;
      int brow = Nt * 16 + l15;
#pragma unroll
      for (int jj = 0; jj < 4; ++jj) {
        b0f.u[jj] = WeT[brow][l4 * 4 + jj];
        b1f.u[jj] = WeT[brow][16 + l4 * 4 + jj];
      }
      acc = __builtin_amdgcn_mfma_f32_16x16x32_bf16(a0.f, b0f.f, acc, 0, 0, 0);
      acc = __builtin_amdgcn_mfma_f32_16x16x32_bf16(a1.f, b1f.f, acc, 0, 0, 0);
#pragma unroll
      for (int r = 0; r < 4; ++r)
        xef[wv * 16 + l4 * 4 + r][Nt * 16 + l15] = acc[r];
    }
    __syncthreads();   // B

    float xo[16];
#pragma unroll
    for (int i = 0; i < 16; ++i) {
      xo[i] = xef[p64][q * 16 + i];
      ssum[i] += xo[i];
      xe[(q * 16 + i) * PIX + gg] = xo[i];
    }
#pragma unroll
    for (int ii = 0; ii < 8; ++ii)
      xp[p64][q * 8 + ii] = pk2(xo[2 * ii], xo[2 * ii + 1]);
    __syncthreads();   // C

    FU c0, c1;
#pragma unroll
    for (int jj = 0; jj < 4; ++jj) {
      c0.u[jj] = xp[arow][l4 * 4 + jj];
      c1.u[jj] = xp[arow][16 + l4 * 4 + jj];
    }
#pragma unroll
    for (int Nt = 0; Nt < 2; ++Nt) {
      float bb = sgb1[Nt * 16 + l15];
      f32x4 acc = (f32x4){bb, bb, bb, bb};
      FU b0f, b1f;
      int brow = Nt * 16 + l15;
#pragma unroll
      for (int jj = 0; jj < 4; ++jj) {
        b0f.u[jj] = SgT[brow][l4 * 4 + jj];
        b1f.u[jj] = SgT[brow][16 + l4 * 4 + jj];
      }
      acc = __builtin_amdgcn_mfma_f32_16x16x32_bf16(c0.f, b0f.f, acc, 0, 0, 0);
      acc = __builtin_amdgcn_mfma_f32_16x16x32_bf16(c1.f, b1f.f, acc, 0, 0, 0);
#pragma unroll
      for (int r = 0; r < 4; ++r) {
        float v = acc[r];
        xef[wv * 16 + l4 * 4 + r][Nt * 16 + l15] = v * sigmoidf_(v);
      }
    }
    __syncthreads();   // D

#pragma unroll
    for (int i = 0; i < 8; ++i)
      g1[(q * 8 + i) * PIX + gg] = xef[p64][q * 8 + i];
  }

#pragma unroll
  for (int i = 0; i < 16; ++i) {
    float v = ssum[i];
    v += __shfl_xor(v, 1);
    v += __shfl_xor(v, 2);
    v += __shfl_xor(v, 4);
    v += __shfl_xor(v, 8);
    v += __shfl_xor(v, 16);
    v += __shfl_xor(v, 32);
    if (l == 0) part[blockIdx.x * 64 + q * 16 + i] = v;
  }
}

// ---------------- flux scan (T=24) + all per-(b,t,d) coefficients ----------------
__global__ void k_flux(float* __restrict__ ws, float* __restrict__ out,
                       const float* __restrict__ dt_seq,
                       const float* __restrict__ flux_re, const float* __restrict__ flux_im,
                       const float* __restrict__ lam_flux,
                       const float* __restrict__ bf_re, const float* __restrict__ bf_im,
                       const float* __restrict__ c_re, const float* __restrict__ c_im,
                       const float* __restrict__ g_w, const float* __restrict__ g_b,
                       const float* __restrict__ a_decay, const float* __restrict__ b_freq) {
  int tid = threadIdx.x;
  if (tid >= 64) return;
  int b = tid >> 5, e = tid & 31;
  float sp_lf = softplusf_(lam_flux[e]);
  float lr = -softplusf_(a_decay[e]);
  float li = b_freq[e];
  float den = lr * lr + li * li;
  float bfr = bf_re[e], bfi = bf_im[e];
  float cr = c_re[e], ci = c_im[e];
  float fr = flux_re[b * 32 + e], fi = flux_im[b * 32 + e];
  const float* part = ws + WS_PART;
  for (int t = 0; t < 24; ++t) {
    int n = b * 24 + t;
    float dt = dt_seq[n];
    float A = expf(-sp_lf * dt);
    float xmr = 0.f, xmi = 0.f;
#pragma unroll
    for (int j = 0; j < 16; ++j) {
      xmr += part[(n * 16 + j) * 64 + e];
      xmi += part[(n * 16 + j) * 64 + 32 + e];
    }
    xmr *= (1.f / 4096.f);
    xmi *= (1.f / 4096.f);
    float Xr = (bfr * xmr - bfi * xmi) * dt;
    float Xi = (bfr * xmi + bfi * xmr) * dt;
    fr = A * fr + Xr;
    fi = A * fi + Xi;
    ws[WS_GATE + n * 32 + e] = sigmoidf_(fr * g_w[e] + g_b[e]);
    ws[WS_SRCR + n * 32 + e] = fr * cr - fi * ci;
    ws[WS_SRCI + n * 32 + e] = fr * ci + fi * cr;
    float er = expf(lr * dt);
    float odr = er * cosf(li * dt);
    float odi = er * sinf(li * dt);
    ws[WS_ODR + n * 32 + e] = odr;
    ws[WS_ODI + n * 32 + e] = odi;
    float nr = odr - 1.f, ni = odi;
    ws[WS_OFR + n * 32 + e] = (nr * lr + ni * li) / den;
    ws[WS_OFI + n * 32 + e] = (ni * lr - nr * li) / den;
  }
  out[FLUX_RE + b * 32 + e] = fr;
  out[FLUX_IM + b * 32 + e] = fi;
}

// ---------------- fused gate: depthwise 3x3 + sg3 (1x1+sigmoid) + forcing -> u_t ----------
__global__ void __launch_bounds__(256) k_gate(
    const float* __restrict__ g1, float* __restrict__ xe,
    const float* __restrict__ gate, const float* __restrict__ srcr,
    const float* __restrict__ srci, const float* __restrict__ ofr_p,
    const float* __restrict__ ofi_p, const float* __restrict__ odr_p,
    const float* __restrict__ odi_p,
    const float* __restrict__ hre, const float* __restrict__ him,
    const float* __restrict__ dw, const float* __restrict__ w2,
    const float* __restrict__ b2) {
  int g = blockIdx.x * 256 + threadIdx.x;
  int n = g >> 12, p = g & 4095;
  int y = p >> 6, x = p & 63;
  int b = (n >= 24) ? 1 : 0;
  int t = n - b * 24;

  // depthwise 3x3 over 32 channels (weights uniform -> s_load; g1 rows L2-hot)
  float g2[32];
#pragma unroll 4
  for (int oc = 0; oc < 32; ++oc) {
    const float* src = g1 + oc * PIX + n * 4096;
    const float* w = dw + oc * 9;
    float acc = 0.f;
#pragma unroll
    for (int ky = 0; ky < 3; ++ky) {
      int yy = y + ky - 1;
      if ((unsigned)yy < 64u) {
#pragma unroll
        for (int kx = 0; kx < 3; ++kx) {
          int xx = x + kx - 1;
          if ((unsigned)xx < 64u)
            acc = fmaf(src[yy * 64 + xx], w[ky * 3 + kx], acc);
        }
      }
    }
    g2[oc] = acc;
  }
  // sg3
  float spg[32];
#pragma unroll
  for (int o0 = 0; o0 < 32; o0 += 4) {
    float acc[4] = {b2[o0], b2[o0 + 1], b2[o0 + 2], b2[o0 + 3]};
#pragma unroll
    for (int c = 0; c < 32; ++c) {
#pragma unroll
      for (int j = 0; j < 4; ++j)
        acc[j] = fmaf(g2[c], w2[(o0 + j) * 32 + c], acc[j]);
    }
#pragma unroll
    for (int j = 0; j < 4; ++j) spg[o0 + j] = sigmoidf_(acc[j]);
  }
  // forcing -> u_t in place
#pragma unroll
  for (int e = 0; e < 32; ++e) {
    int ie = n * 32 + e;
    float gc = gate[ie] * spg[e];
    float xr = xe[e * PIX + g];
    float xi = xe[(32 + e) * PIX + g];
    float om = 1.f - gc;
    float fr2 = xr * gc + srcr[ie] * om;
    float fi2 = xi * gc + srci[ie] * om;
    float ofr = ofr_p[ie], ofi = ofi_p[ie];
    float ur = fr2 * ofr - fi2 * ofi;
    float ui = fr2 * ofi + fi2 * ofr;
    if (t == 0) {                       // block-uniform branch
      int hb = (b * 4096 + p) * 32 + e;
      float hr = hre[hb], hi = him[hb];
      float odr = odr_p[(b * 24) * 32 + e], odi = odi_p[(b * 24) * 32 + e];
      ur += hr * odr - hi * odi;
      ui += hr * odi + hi * odr;
    }
    xe[e * PIX + g] = ur;
    xe[(32 + e) * PIX + g] = ui;
  }
}

// ---------------- temporal scan over T=24 on planes (in place), emit h_out ----------------
__global__ void __launch_bounds__(256) k_scan(
    float* __restrict__ u, const float* __restrict__ odr_p,
    const float* __restrict__ odi_p, float* __restrict__ out) {
  int p = blockIdx.x * 256 + threadIdx.x;   // 0..4095
  int e = blockIdx.y;                        // 0..31 (block-uniform)
  int b = blockIdx.z;                        // 0..1
  float ur = 0.f, ui = 0.f;
  for (int t = 0; t < 24; ++t) {
    int n = b * 24 + t;
    int idx  = e * PIX + n * 4096 + p;
    int idxi = (32 + e) * PIX + n * 4096 + p;
    float ar = odr_p[n * 32 + e];
    float ai = odi_p[n * 32 + e];
    float xr = u[idx], xi = u[idxi];
    float nr = ar * ur - ai * ui + xr;
    float ni = ar * ui + ai * ur + xi;
    ur = nr; ui = ni;
    u[idx] = ur;
    u[idxi] = ui;
  }
  out[HOUT_RE + (b * 4096 + p) * 32 + e] = ur;
  out[HOUT_IM + (b * 4096 + p) * 32 + e] = ui;
}

// ---------------- dec(Winv MFMA) + LN_t + FFN MFMA + z = x_upd + dec + delta --------------
// LDS aliasing: dnp holds u-pack then dn-pack; ho holds decf f32 / hid bf16 / o2 f32.
// All alias pairs barrier-separated; TBAA fence kept between ushort stores and u32 loads.
__global__ void __launch_bounds__(256) k_final(
    const float* __restrict__ u, float* __restrict__ out,
    const unsigned* __restrict__ wibP,
    const float* __restrict__ lg, const float* __restrict__ lb,
    const float* __restrict__ w1, const float* __restrict__ b1,
    const float* __restrict__ w2, const float* __restrict__ b2) {
  __shared__ unsigned wiT[64][33];
  __shared__ unsigned w1T[128][33];
  __shared__ unsigned w2T[64][65];
  __shared__ unsigned dnp[64][33];
  __shared__ unsigned ho[64][65];
  __shared__ float ps1[64][5];
  __shared__ float ps2[64][5];

  int tid = threadIdx.x;
  int gbase = blockIdx.x * 256;
  int l = tid & 63, wv = tid >> 6;
  int l15 = l & 15, l4 = l >> 4;
  int p64 = l, q = wv;

  {
#pragma unroll
    for (int i = 0; i < 8; ++i) {
      int idx = tid + i * 256;
      wiT[idx >> 5][idx & 31] = wibP[idx];
    }
    int hid = tid & 127, half = tid >> 7;
#pragma unroll
    for (int i = 0; i < 16; ++i) {
      int cp = half * 16 + i;
      w1T[hid][cp] = pk2(w1[(2 * cp) * 128 + hid], w1[(2 * cp + 1) * 128 + hid]);
    }
#pragma unroll
    for (int i = 0; i < 16; ++i) {
      int hp = wv * 16 + i;
      w2T[l][hp] = pk2(w2[(2 * hp) * 64 + l], w2[(2 * hp + 1) * 64 + l]);
    }
  }
  float bb1v[8], bb2v[4];
#pragma unroll
  for (int Hn = 0; Hn < 8; ++Hn) bb1v[Hn] = b1[Hn * 16 + l15];
#pragma unroll
  for (int On = 0; On < 4; ++On) bb2v[On] = b2[On * 16 + l15];
  __syncthreads();

  for (int ph = 0; ph < 4; ++ph) {
    int gg = gbase + ph * 64 + p64;
    int arow = wv * 16 + l15;

    // ---- step1: load u (16 ch/thread), pack bf16 into dnp (as u-pack) ----
    float uv[16];
#pragma unroll
    for (int i = 0; i < 16; ++i) uv[i] = u[(q * 16 + i) * PIX + gg];
#pragma unroll
    for (int ii = 0; ii < 8; ++ii)
      dnp[p64][q * 8 + ii] = pk2(uv[2 * ii], uv[2 * ii + 1]);
    __syncthreads();   // A

    // ---- step2: dec = u @ Winv (packed-real MFMA), stage decf f32 in ho ----
    {
      FU a0, a1;
#pragma unroll
      for (int jj = 0; jj < 4; ++jj) {
        a0.u[jj] = dnp[arow][l4 * 4 + jj];
        a1.u[jj] = dnp[arow][16 + l4 * 4 + jj];
      }
      float (*decf)[65] = (float(*)[65])ho;
#pragma unroll
      for (int Nt = 0; Nt < 4; ++Nt) {
        f32x4 acc = (f32x4){0.f, 0.f, 0.f, 0.f};
        FU b0f, b1f;
        int brow = Nt * 16 + l15;
#pragma unroll
        for (int jj = 0; jj < 4; ++jj) {
          b0f.u[jj] = wiT[brow][l4 * 4 + jj];
          b1f.u[jj] = wiT[brow][16 + l4 * 4 + jj];
        }
        acc = __builtin_amdgcn_mfma_f32_16x16x32_bf16(a0.f, b0f.f, acc, 0, 0, 0);
        acc = __builtin_amdgcn_mfma_f32_16x16x32_bf16(a1.f, b1f.f, acc, 0, 0, 0);
#pragma unroll
        for (int r = 0; r < 4; ++r)
          decf[wv * 16 + l4 * 4 + r][Nt * 16 + l15] = acc[r];
      }
    }
    __syncthreads();   // B

    // ---- step3: dv = raw dec (regs), LN sums, normalize, pack dnp ----
    float dv[16];
    float s1 = 0.f, s2 = 0.f;
    {
      float (*decf)[65] = (float(*)[65])ho;
#pragma unroll
      for (int i = 0; i < 16; ++i) {
        dv[i] = decf[p64][q * 16 + i];
        s1 += dv[i];
        s2 += dv[i] * dv[i];
      }
    }
    ps1[p64][q] = s1;
    ps2[p64][q] = s2;
    __syncthreads();   // C
    float m  = (ps1[p64][0] + ps1[p64][1] + ps1[p64][2] + ps1[p64][3]) * (1.f / 64.f);
    float e2 = (ps2[p64][0] + ps2[p64][1] + ps2[p64][2] + ps2[p64][3]) * (1.f / 64.f);
    float rs = rsqrtf(e2 - m * m + 1e-5f);
#pragma unroll
    for (int ii = 0; ii < 8; ++ii) {
      int c0 = q * 16 + 2 * ii;
      float a = (dv[2 * ii]     - m) * rs * lg[c0]     + lb[c0];
      float bvl = (dv[2 * ii + 1] - m) * rs * lg[c0 + 1] + lb[c0 + 1];
      dnp[p64][q * 8 + ii] = pk2(a, bvl);
    }
    __syncthreads();   // D

    // ---- step4: FFN layer1 MFMA + silu -> hid bf16 (ho as ushort) ----
    FU a0, a1;
#pragma unroll
    for (int jj = 0; jj < 4; ++jj) {
      a0.u[jj] = dnp[arow][l4 * 4 + jj];
      a1.u[jj] = dnp[arow][16 + l4 * 4 + jj];
    }
    f32x4 acc[8];
#pragma unroll
    for (int Hn = 0; Hn < 8; ++Hn) {
      float bb = bb1v[Hn];
      acc[Hn] = (f32x4){bb, bb, bb, bb};
      FU b0f, b1f;
      int brow = Hn * 16 + l15;
#pragma unroll
      for (int jj = 0; jj < 4; ++jj) {
        b0f.u[jj] = w1T[brow][l4 * 4 + jj];
        b1f.u[jj] = w1T[brow][16 + l4 * 4 + jj];
      }
      acc[Hn] = __builtin_amdgcn_mfma_f32_16x16x32_bf16(a0.f, b0f.f, acc[Hn], 0, 0, 0);
      acc[Hn] = __builtin_amdgcn_mfma_f32_16x16x32_bf16(a1.f, b1f.f, acc[Hn], 0, 0, 0);
    }
    unsigned short (*hidb)[130] = (unsigned short(*)[130])ho;
#pragma unroll
    for (int Hn = 0; Hn < 8; ++Hn) {
#pragma unroll
      for (int r = 0; r < 4; ++r) {
        float v = acc[Hn][r];
        v = v * sigmoidf_(v);
        hidb[wv * 16 + l4 * 4 + r][Hn * 16 + l15] = f2bf(v);
      }
    }
    __syncthreads();   // E: TBAA fence (ushort stores -> u32 loads)

    // ---- step5: FFN layer2 MFMA -> o2 f32 (ho as float) ----
    FU a2[4];
#pragma unroll
    for (int kk = 0; kk < 4; ++kk)
#pragma unroll
      for (int jj = 0; jj < 4; ++jj)
        a2[kk].u[jj] = ((unsigned(*)[65])ho)[arow][kk * 16 + l4 * 4 + jj];
    f32x4 acc2[4];
#pragma unroll
    for (int On = 0; On < 4; ++On) {
      float bb = bb2v[On];
      acc2[On] = (f32x4){bb, bb, bb, bb};
#pragma unroll
      for (int kk = 0; kk < 4; ++kk) {
        FU b2f;
#pragma unroll
        for (int jj = 0; jj < 4; ++jj)
          b2f.u[jj] = w2T[On * 16 + l15][kk * 16 + l4 * 4 + jj];
        acc2[On] = __builtin_amdgcn_mfma_f32_16x16x32_bf16(a2[kk].f, b2f.f, acc2[On], 0, 0, 0);
      }
    }
    float (*o2f)[65] = (float(*)[65])ho;
#pragma unroll
    for (int On = 0; On < 4; ++On)
#pragma unroll
      for (int r = 0; r < 4; ++r)
        o2f[wv * 16 + l4 * 4 + r][On * 16 + l15] = acc2[On][r];
    __syncthreads();   // F

    // ---- epilogue: out += dec + delta (dv in regs, o2f cross-wave) ----
    {
      int nn = gg >> 12, pim = gg & 4095;
#pragma unroll
      for (int i = 0; i < 16; ++i) {
        int c = q * 16 + i;
        float val = o2f[p64][c] + dv[i];
        int d = c & 31;
        long off = ((c < 32) ? (long)MAIN_RE : (long)MAIN_IM) + (long)(nn * 32 + d) * 4096 + pim;
        out[off] += val;
      }
    }
    // next phase's dnp writes are after barrier A-next; o2f reads separated likewise
    __syncthreads();   // G: protect ho (o2f) reads vs next-phase decf writes
  }
}

extern "C" void kernel_launch(void* const* d_in, const int* in_sizes, int n_in,
                              void* d_out, int out_size, void* d_ws, size_t ws_size,
                              hipStream_t stream) {
  (void)in_sizes; (void)n_in; (void)out_size; (void)ws_size;
  const float* xre      = (const float*)d_in[0];
  const float* xim      = (const float*)d_in[1];
  const float* hre      = (const float*)d_in[2];
  const float* him      = (const float*)d_in[3];
  const float* flux_re  = (const float*)d_in[4];
  const float* flux_im  = (const float*)d_in[5];
  const float* dt_seq   = (const float*)d_in[6];
  const float* ln_s_g   = (const float*)d_in[7];
  const float* ln_s_b   = (const float*)d_in[8];
  const float* conv_w   = (const float*)d_in[9];
  const float* conv_b   = (const float*)d_in[10];
  const float* ln_t_g   = (const float*)d_in[11];
  const float* ln_t_b   = (const float*)d_in[12];
  const float* W_re     = (const float*)d_in[13];
  const float* W_im     = (const float*)d_in[14];
  const float* lam_flux = (const float*)d_in[15];
  const float* bf_re    = (const float*)d_in[16];
  const float* bf_im    = (const float*)d_in[17];
  const float* c_re     = (const float*)d_in[18];
  const float* c_im     = (const float*)d_in[19];
  const float* g_w      = (const float*)d_in[20];
  const float* g_b      = (const float*)d_in[21];
  const float* a_decay  = (const float*)d_in[22];
  const float* b_freq   = (const float*)d_in[23];
  const float* ffn_w1   = (const float*)d_in[24];
  const float* ffn_b1   = (const float*)d_in[25];
  const float* ffn_w2   = (const float*)d_in[26];
  const float* ffn_b2   = (const float*)d_in[27];
  const float* sg_w1    = (const float*)d_in[28];
  const float* sg_b1    = (const float*)d_in[29];
  const float* sg_dw    = (const float*)d_in[30];
  const float* sg_w2    = (const float*)d_in[31];
  const float* sg_b2    = (const float*)d_in[32];
  float* out = (float*)d_out;
  float* ws  = (float*)d_ws;

  k_invert<<<1, 256, 0, stream>>>(W_re, W_im, ws);
  k_wprep<<<144, 256, 0, stream>>>(conv_w, (unsigned short*)(ws + WS_WPK));
  k_eprep<<<8, 256, 0, stream>>>(W_re, W_im, sg_w1,
                                 (unsigned*)(ws + WS_WE), (unsigned*)(ws + WS_SG));
  k_ln_s<<<PIX / 256, 256, 0, stream>>>(xre, xim, ln_s_g, ln_s_b, ws);
  k_conv<<<768, 256, 0, stream>>>((const unsigned*)(ws + WS_XN),
                                  (const unsigned short*)(ws + WS_WPK),
                                  conv_b, xre, xim, out);
  k_xeig<<<768, 256, 0, stream>>>(out, (const unsigned*)(ws + WS_WE),
                                  (const unsigned*)(ws + WS_SG),
                                  ws + WS_XE, ws + WS_G1, sg_b1, ws + WS_PART);
  k_flux<<<1, 64, 0, stream>>>(ws, out, dt_seq, flux_re, flux_im, lam_flux,
                               bf_re, bf_im, c_re, c_im, g_w, g_b, a_decay, b_freq);
  k_gate<<<PIX / 256, 256, 0, stream>>>(ws + WS_G1, ws + WS_XE,
                                        ws + WS_GATE, ws + WS_SRCR, ws + WS_SRCI,
                                        ws + WS_OFR, ws + WS_OFI, ws + WS_ODR, ws + WS_ODI,
                                        hre, him, sg_dw, sg_w2, sg_b2);
  k_scan<<<dim3(4096 / 256, 32, 2), 256, 0, stream>>>(ws + WS_XE, ws + WS_ODR, ws + WS_ODI, out);
  k_final<<<768, 256, 0, stream>>>(ws + WS_XE, out, (const unsigned*)(ws + WS_WIB),
                                   ln_t_g, ln_t_b, ffn_w1, ffn_b1, ffn_w2, ffn_b2);
}

// Round 12
// 348.399 us; speedup vs baseline: 8.4309x; 1.1237x over previous
//
#include <hip/hip_runtime.h>
#include <math.h>

#define BB 2
#define TT 24
#define DD 32
#define HWp 4096            // 64*64
#define NN (BB*TT)          // 48
#define PIX (NN*HWp)        // 196608
#define C2 (2*DD)           // 64

// d_out offsets (floats)
#define MAIN_RE 0
#define MAIN_IM (NN*DD*HWp)              // 6291456
#define HOUT_RE (2*NN*DD*HWp)            // 12582912
#define HOUT_IM (HOUT_RE + BB*HWp*DD)    // 12845056
#define FLUX_RE (HOUT_RE + 2*BB*HWp*DD)  // 13107200
#define FLUX_IM (FLUX_RE + BB*DD)        // 13107264

// ws offsets (floats)
#define WS_XN   0                        // PIX*64 (bf16 xn for conv)
#define WS_XE   (WS_XN + PIX*C2)         // PIX*64  xe -> u_t -> u_out planes
#define WS_G1   (WS_XE + PIX*C2)         // PIX*32  g1 planes
#define WS_G2   (WS_G1 + PIX*DD)         // PIX*32  (free)
#define WS_WINV (WS_G2 + PIX*DD)         // 2048 f32
#define WS_SUMS (WS_WINV + 2048)         // 3072 (unused)
#define WS_GATE (WS_SUMS + 3072)         // 1536
#define WS_SRCR (WS_GATE + 1536)
#define WS_SRCI (WS_SRCR + 1536)
#define WS_ODR  (WS_SRCI + 1536)
#define WS_ODI  (WS_ODR + 1536)
#define WS_OFR  (WS_ODI + 1536)
#define WS_OFI  (WS_OFR + 1536)
#define WS_WPK  (WS_OFI + 1536)          // 36864 ushorts = 18432 floats
#define WS_PART (WS_WPK + 18432)         // 48*16*64 floats
#define WS_WE   (WS_PART + 49152)        // 2048 u32 eig weights
#define WS_SG   (WS_WE + 2048)           // 1024 u32 sg1 weights
#define WS_WIB  (WS_SG + 1024)           // 2048 u32 Winv packed bf16 B-frag

typedef __attribute__((ext_vector_type(8))) short bf16x8;
typedef __attribute__((ext_vector_type(4))) float f32x4;
union FU { unsigned u[4]; bf16x8 f; };
union FU4 { uint4 v; unsigned u[4]; bf16x8 f; };

__device__ __forceinline__ float sigmoidf_(float x) { return 1.f / (1.f + expf(-x)); }
__device__ __forceinline__ float softplusf_(float x) { return log1pf(expf(x)); }
__device__ __forceinline__ unsigned short f2bf(float f) {
  unsigned u = __float_as_uint(f);
  return (unsigned short)((u + 0x7FFFu + ((u >> 16) & 1u)) >> 16);   // RNE
}
__device__ __forceinline__ unsigned pk2(float lo, float hi) {
  return (unsigned)f2bf(lo) | ((unsigned)f2bf(hi) << 16);
}

// ---------------- Gauss-Jordan inverse of Wb (32x32 complex) + bf16 B-frag pack ----------
__global__ void k_invert(const float* __restrict__ Wre, const float* __restrict__ Wim,
                         float* __restrict__ ws) {
  __shared__ float Mre[32][64];
  __shared__ float Mim[32][64];
  __shared__ float fre[32], fim[32];
  __shared__ float pr_s, pi_s;
  __shared__ int piv_s;
  int tid = threadIdx.x;  // 256 threads
  for (int idx = tid; idx < 2048; idx += 256) {
    int i = idx >> 6, j = idx & 63;
    if (j < 32) { Mre[i][j] = Wre[i * 32 + j]; Mim[i][j] = Wim[i * 32 + j]; }
    else        { Mre[i][j] = (j - 32 == i) ? 1.f : 0.f; Mim[i][j] = 0.f; }
  }
  __syncthreads();
  for (int k = 0; k < 32; ++k) {
    if (tid == 0) {
      int best = k; float bm = fabsf(Mre[k][k]) + fabsf(Mim[k][k]);
      for (int r = k + 1; r < 32; ++r) {
        float m = fabsf(Mre[r][k]) + fabsf(Mim[r][k]);
        if (m > bm) { bm = m; best = r; }
      }
      piv_s = best;
    }
    __syncthreads();
    int pv = piv_s;
    if (pv != k && tid < 64) {
      float tr = Mre[k][tid], ti = Mim[k][tid];
      Mre[k][tid] = Mre[pv][tid]; Mim[k][tid] = Mim[pv][tid];
      Mre[pv][tid] = tr; Mim[pv][tid] = ti;
    }
    __syncthreads();
    if (tid == 0) {
      float a = Mre[k][k], b = Mim[k][k];
      float d = a * a + b * b;
      pr_s = a / d; pi_s = -b / d;
    }
    __syncthreads();
    float pr = pr_s, pi = pi_s;
    if (tid < 64) {
      float a = Mre[k][tid], b = Mim[k][tid];
      Mre[k][tid] = a * pr - b * pi;
      Mim[k][tid] = a * pi + b * pr;
    }
    __syncthreads();
    if (tid < 32) { fre[tid] = Mre[tid][k]; fim[tid] = Mim[tid][k]; }
    __syncthreads();
    for (int idx = tid; idx < 2048; idx += 256) {
      int i = idx >> 6, j = idx & 63;
      if (i != k) {
        float fr = fre[i], fi = fim[i];
        float ar = Mre[k][j], ai = Mim[k][j];
        Mre[i][j] -= fr * ar - fi * ai;
        Mim[i][j] -= fr * ai + fi * ar;
      }
    }
    __syncthreads();
  }
  for (int idx = tid; idx < 1024; idx += 256) {
    int e = idx >> 5, d = idx & 31;
    ws[WS_WINV + e * 32 + d] = Mre[e][32 + d];
    ws[WS_WINV + 1024 + e * 32 + d] = Mim[e][32 + d];
  }
  unsigned* wib = (unsigned*)(ws + WS_WIB);
  for (int idx = tid; idx < 2048; idx += 256) {
    int j = idx >> 5, kp = idx & 31;
    float v[2];
#pragma unroll
    for (int h = 0; h < 2; ++h) {
      int k = 2 * kp + h;
      float x;
      if (j < 32) x = (k < 32) ? Mre[k][32 + j] : -Mim[k - 32][32 + j];
      else        x = (k < 32) ? Mim[k][32 + (j - 32)] : Mre[k - 32][32 + (j - 32)];
      v[h] = x;
    }
    wib[idx] = pk2(v[0], v[1]);
  }
}

// ---------------- weight pre-pack: wpack[tap][oc][ci] bf16 <- conv_w[oc][ci][tap] f32 ----
__global__ void k_wprep(const float* __restrict__ w, unsigned short* __restrict__ wpk) {
  int idx = blockIdx.x * 256 + threadIdx.x;
  if (idx >= 9 * 64 * 64) return;
  int tap = idx >> 12;
  int rem = idx & 4095;
  int oc = rem >> 6, ci = rem & 63;
  wpk[idx] = f2bf(w[(oc * 64 + ci) * 9 + tap]);
}

// ---------------- eig + sg1 weight pre-pack (bf16 [N][Kpair] B-fragment layout) ----------
__global__ void k_eprep(const float* __restrict__ Wre, const float* __restrict__ Wim,
                        const float* __restrict__ sgw1,
                        unsigned* __restrict__ we, unsigned* __restrict__ sg) {
  int idx = blockIdx.x * 256 + threadIdx.x;
  if (idx < 2048) {
    int j = idx >> 5, kp = idx & 31;
    float v[2];
#pragma unroll
    for (int h = 0; h < 2; ++h) {
      int k = 2 * kp + h;
      float x;
      if (j < 32) x = (k < 32) ? Wre[k * 32 + j] : -Wim[(k - 32) * 32 + j];
      else        x = (k < 32) ? Wim[k * 32 + (j - 32)] : Wre[(k - 32) * 32 + (j - 32)];
      v[h] = x;
    }
    we[idx] = pk2(v[0], v[1]);
  }
  if (idx < 1024) {
    int oc = idx >> 5, kp = idx & 31;
    sg[idx] = pk2(sgw1[oc * 64 + 2 * kp], sgw1[oc * 64 + 2 * kp + 1]);
  }
}

// ---------------- spatial LayerNorm -> xn bf16 channels-last [n][pix][64] ----------------
__global__ void k_ln_s(const float* __restrict__ xre, const float* __restrict__ xim,
                       const float* __restrict__ g, const float* __restrict__ b,
                       float* __restrict__ ws) {
  int gid = blockIdx.x * 256 + threadIdx.x;
  if (gid >= PIX) return;
  int n = gid >> 12, p = gid & 4095;
  float v[64];
  float s = 0.f;
#pragma unroll
  for (int c = 0; c < 32; ++c) { v[c] = xre[(n * 32 + c) * 4096 + p]; s += v[c]; }
#pragma unroll
  for (int c = 0; c < 32; ++c) { v[32 + c] = xim[(n * 32 + c) * 4096 + p]; s += v[32 + c]; }
  float m = s * (1.f / 64.f);
  float vs = 0.f;
#pragma unroll
  for (int c = 0; c < 64; ++c) { float d = v[c] - m; vs += d * d; }
  float rs = rsqrtf(vs * (1.f / 64.f) + 1e-5f);
#pragma unroll
  for (int c = 0; c < 64; ++c) v[c] = (v[c] - m) * rs * g[c] + b[c];
  uint4* dst = (uint4*)ws + gid * 8;
#pragma unroll
  for (int q = 0; q < 8; ++q) {
    uint4 u;
    u.x = pk2(v[q * 8 + 0], v[q * 8 + 1]);
    u.y = pk2(v[q * 8 + 2], v[q * 8 + 3]);
    u.z = pk2(v[q * 8 + 4], v[q * 8 + 5]);
    u.w = pk2(v[q * 8 + 6], v[q * 8 + 7]);
    dst[q] = u;
  }
}

// ---------------- 3x3 conv 64->64 as 9 shifted bf16 MFMA GEMMs ----------------
__global__ void __launch_bounds__(256) k_conv(
    const unsigned* __restrict__ xnb_u, const unsigned short* __restrict__ wpk,
    const float* __restrict__ bconv,
    const float* __restrict__ xre, const float* __restrict__ xim,
    float* __restrict__ out) {
  __shared__ unsigned xls[6 * 66 * 36];
  int bid = blockIdx.x;
  int n = bid >> 4;
  int y0 = (bid & 15) * 4;
  int tid = threadIdx.x;
  int wv = tid >> 6, l = tid & 63;
  int l15 = l & 15, l4 = l >> 4;

  const uint4* xnb4 = (const uint4*)xnb_u;
  for (int idx = tid; idx < 396; idx += 256) {
    int r = idx / 66, c = idx - r * 66;
    int y = y0 - 1 + r, x = c - 1;
    bool valid = ((unsigned)y < 64u) & ((unsigned)x < 64u);
    int pg = n * 4096 + y * 64 + x;
    uint4 z; z.x = z.y = z.z = z.w = 0u;
#pragma unroll
    for (int q = 0; q < 8; ++q) {
      uint4 v = valid ? xnb4[pg * 8 + q] : z;
      *(uint4*)&xls[idx * 36 + q * 4] = v;
    }
  }
  __syncthreads();

  f32x4 acc[4][4];
#pragma unroll
  for (int Nt = 0; Nt < 4; ++Nt) {
    float bb = bconv[Nt * 16 + l15];
#pragma unroll
    for (int mt = 0; mt < 4; ++mt) acc[mt][Nt] = (f32x4){bb, bb, bb, bb};
  }

  const uint4* wq = (const uint4*)wpk;
#pragma unroll
  for (int tap = 0; tap < 9; ++tap) {
    int ky = tap / 3, kx = tap - ky * 3;
    int rowbase = (wv + ky) * 66 + kx + l15;
#pragma unroll
    for (int ks = 0; ks < 2; ++ks) {
      FU4 B[4];
#pragma unroll
      for (int Nt = 0; Nt < 4; ++Nt)
        B[Nt].v = wq[tap * 512 + (Nt * 16 + l15) * 8 + ks * 4 + l4];
#pragma unroll
      for (int mt = 0; mt < 4; ++mt) {
        FU4 A;
        A.v = *(const uint4*)&xls[(rowbase + mt * 16) * 36 + ks * 16 + l4 * 4];
#pragma unroll
        for (int Nt = 0; Nt < 4; ++Nt)
          acc[mt][Nt] = __builtin_amdgcn_mfma_f32_16x16x32_bf16(A.f, B[Nt].f, acc[mt][Nt], 0, 0, 0);
      }
    }
  }

#pragma unroll
  for (int Nt = 0; Nt < 4; ++Nt) {
    int oc = Nt * 16 + l15;
    int d = oc & 31;
    const float* resid = (oc < 32) ? xre : xim;
    float* dst = out + ((oc < 32) ? MAIN_RE : MAIN_IM) + (n * 32 + d) * 4096;
    const float* rsd = resid + (n * 32 + d) * 4096;
#pragma unroll
    for (int mt = 0; mt < 4; ++mt) {
      int pixbase = (y0 + wv) * 64 + mt * 16 + l4 * 4;
#pragma unroll
      for (int r = 0; r < 4; ++r)
        dst[pixbase + r] = rsd[pixbase + r] + acc[mt][Nt][r];
    }
  }
}

// ---------------- x_eig v2: bf16 MFMA dual-GEMM (eig 64->64, sg1 64->32) + channel sums ----
__global__ void __launch_bounds__(256) k_xeig(
    const float* __restrict__ out, const unsigned* __restrict__ weP,
    const unsigned* __restrict__ sgP, float* __restrict__ xe,
    float* __restrict__ g1, const float* __restrict__ sgb1,
    float* __restrict__ part) {
  __shared__ unsigned WeT[64][33];
  __shared__ unsigned SgT[32][33];
  __shared__ unsigned xp[64][33];
  __shared__ float xef[64][65];

  int tid = threadIdx.x;
  int gbase = blockIdx.x * 256;
  int l = tid & 63, wv = tid >> 6;
  int l15 = l & 15, l4 = l >> 4;
  int p64 = l, q = wv;

  {
#pragma unroll
    for (int i = 0; i < 8; ++i) {
      int idx = tid + i * 256;
      WeT[idx >> 5][idx & 31] = weP[idx];
    }
#pragma unroll
    for (int i = 0; i < 4; ++i) {
      int idx = tid + i * 256;
      SgT[idx >> 5][idx & 31] = sgP[idx];
    }
  }
  float ssum[16];
#pragma unroll
  for (int i = 0; i < 16; ++i) ssum[i] = 0.f;
  __syncthreads();

  for (int ph = 0; ph < 4; ++ph) {
    int gg = gbase + ph * 64 + p64;
    int n = gg >> 12, p = gg & 4095;

    float xv[16];
#pragma unroll
    for (int i = 0; i < 16; ++i) {
      int c = q * 16 + i;
      xv[i] = (c < 32) ? out[MAIN_RE + (n * 32 + c) * 4096 + p]
                       : out[MAIN_IM + (n * 32 + (c - 32)) * 4096 + p];
    }
#pragma unroll
    for (int ii = 0; ii < 8; ++ii)
      xp[p64][q * 8 + ii] = pk2(xv[2 * ii], xv[2 * ii + 1]);
    __syncthreads();   // A

    int arow = wv * 16 + l15;
    FU a0, a1;
#pragma unroll
    for (int jj = 0; jj < 4; ++jj) {
      a0.u[jj] = xp[arow][l4 * 4 + jj];
      a1.u[jj] = xp[arow][16 + l4 * 4 + jj];
    }
#pragma unroll
    for (int Nt = 0; Nt < 4; ++Nt) {
      f32x4 acc = (f32x4){0.f, 0.f, 0.f, 0.f};
      FU b0f, b1f;
      int brow = Nt * 16 + l15;
#pragma unroll
      for (int jj = 0; jj < 4; ++jj) {
        b0f.u[jj] = WeT[brow][l4 * 4 + jj];
        b1f.u[jj] = WeT[brow][16 + l4 * 4 + jj];
      }
      acc = __builtin_amdgcn_mfma_f32_16x16x32_bf16(a0.f, b0f.f, acc, 0, 0, 0);
      acc = __builtin_amdgcn_mfma_f32_16x16x32_bf16(a1.f, b1f.f, acc, 0, 0, 0);
#pragma unroll
      for (int r = 0; r < 4; ++r)
        xef[wv * 16 + l4 * 4 + r][Nt * 16 + l15] = acc[r];
    }
    __syncthreads();   // B

    float xo[16];
#pragma unroll
    for (int i = 0; i < 16; ++i) {
      xo[i] = xef[p64][q * 16 + i];
      ssum[i] += xo[i];
      xe[(q * 16 + i) * PIX + gg] = xo[i];
    }
#pragma unroll
    for (int ii = 0; ii < 8; ++ii)
      xp[p64][q * 8 + ii] = pk2(xo[2 * ii], xo[2 * ii + 1]);
    __syncthreads();   // C

    FU c0, c1;
#pragma unroll
    for (int jj = 0; jj < 4; ++jj) {
      c0.u[jj] = xp[arow][l4 * 4 + jj];
      c1.u[jj] = xp[arow][16 + l4 * 4 + jj];
    }
#pragma unroll
    for (int Nt = 0; Nt < 2; ++Nt) {
      float bb = sgb1[Nt * 16 + l15];
      f32x4 acc = (f32x4){bb, bb, bb, bb};
      FU b0f, b1f;
      int brow = Nt * 16 + l15;
#pragma unroll
      for (int jj = 0; jj < 4; ++jj) {
        b0f.u[jj] = SgT[brow][l4 * 4 + jj];
        b1f.u[jj] = SgT[brow][16 + l4 * 4 + jj];
      }
      acc = __builtin_amdgcn_mfma_f32_16x16x32_bf16(c0.f, b0f.f, acc, 0, 0, 0);
      acc = __builtin_amdgcn_mfma_f32_16x16x32_bf16(c1.f, b1f.f, acc, 0, 0, 0);
#pragma unroll
      for (int r = 0; r < 4; ++r) {
        float v = acc[r];
        xef[wv * 16 + l4 * 4 + r][Nt * 16 + l15] = v * sigmoidf_(v);
      }
    }
    __syncthreads();   // D

#pragma unroll
    for (int i = 0; i < 8; ++i)
      g1[(q * 8 + i) * PIX + gg] = xef[p64][q * 8 + i];
  }

#pragma unroll
  for (int i = 0; i < 16; ++i) {
    float v = ssum[i];
    v += __shfl_xor(v, 1);
    v += __shfl_xor(v, 2);
    v += __shfl_xor(v, 4);
    v += __shfl_xor(v, 8);
    v += __shfl_xor(v, 16);
    v += __shfl_xor(v, 32);
    if (l == 0) part[blockIdx.x * 64 + q * 16 + i] = v;
  }
}

// ---------------- flux scan (T=24) + all per-(b,t,d) coefficients ----------------
__global__ void k_flux(float* __restrict__ ws, float* __restrict__ out,
                       const float* __restrict__ dt_seq,
                       const float* __restrict__ flux_re, const float* __restrict__ flux_im,
                       const float* __restrict__ lam_flux,
                       const float* __restrict__ bf_re, const float* __restrict__ bf_im,
                       const float* __restrict__ c_re, const float* __restrict__ c_im,
                       const float* __restrict__ g_w, const float* __restrict__ g_b,
                       const float* __restrict__ a_decay, const float* __restrict__ b_freq) {
  int tid = threadIdx.x;
  if (tid >= 64) return;
  int b = tid >> 5, e = tid & 31;
  float sp_lf = softplusf_(lam_flux[e]);
  float lr = -softplusf_(a_decay[e]);
  float li = b_freq[e];
  float den = lr * lr + li * li;
  float bfr = bf_re[e], bfi = bf_im[e];
  float cr = c_re[e], ci = c_im[e];
  float fr = flux_re[b * 32 + e], fi = flux_im[b * 32 + e];
  const float* part = ws + WS_PART;
  for (int t = 0; t < 24; ++t) {
    int n = b * 24 + t;
    float dt = dt_seq[n];
    float A = expf(-sp_lf * dt);
    float xmr = 0.f, xmi = 0.f;
#pragma unroll
    for (int j = 0; j < 16; ++j) {
      xmr += part[(n * 16 + j) * 64 + e];
      xmi += part[(n * 16 + j) * 64 + 32 + e];
    }
    xmr *= (1.f / 4096.f);
    xmi *= (1.f / 4096.f);
    float Xr = (bfr * xmr - bfi * xmi) * dt;
    float Xi = (bfr * xmi + bfi * xmr) * dt;
    fr = A * fr + Xr;
    fi = A * fi + Xi;
    ws[WS_GATE + n * 32 + e] = sigmoidf_(fr * g_w[e] + g_b[e]);
    ws[WS_SRCR + n * 32 + e] = fr * cr - fi * ci;
    ws[WS_SRCI + n * 32 + e] = fr * ci + fi * cr;
    float er = expf(lr * dt);
    float odr = er * cosf(li * dt);
    float odi = er * sinf(li * dt);
    ws[WS_ODR + n * 32 + e] = odr;
    ws[WS_ODI + n * 32 + e] = odi;
    float nr = odr - 1.f, ni = odi;
    ws[WS_OFR + n * 32 + e] = (nr * lr + ni * li) / den;
    ws[WS_OFI + n * 32 + e] = (ni * lr - nr * li) / den;
  }
  out[FLUX_RE + b * 32 + e] = fr;
  out[FLUX_IM + b * 32 + e] = fi;
}

// ---------------- fused gate v2: dw 3x3 (shuffle stencil) + sg3 + forcing -> u_t ----------
// thread = (pixel, channel-half). Block: 128 pixels (2 rows) x 2 halves; wave = one row.
// x-neighbors via __shfl_up/down (no L2 re-reads); g2 halves exchanged via LDS for sg3.
__global__ void __launch_bounds__(256) k_gate(
    const float* __restrict__ g1, float* __restrict__ xe,
    const float* __restrict__ gate, const float* __restrict__ srcr,
    const float* __restrict__ srci, const float* __restrict__ ofr_p,
    const float* __restrict__ ofi_p, const float* __restrict__ odr_p,
    const float* __restrict__ odi_p,
    const float* __restrict__ hre, const float* __restrict__ him,
    const float* __restrict__ dw, const float* __restrict__ w2,
    const float* __restrict__ b2) {
  __shared__ float g2s[128][33];
  int tid = threadIdx.x;
  int l = tid & 63;
  int wv = tid >> 6;
  int r = wv >> 1, h = wv & 1;
  int pixbase = blockIdx.x * 128;
  int n = pixbase >> 12;
  int y = ((pixbase & 4095) >> 6) + r;
  int g = pixbase + r * 64 + l;
  int b = (n >= 24) ? 1 : 0;
  int t = n - b * 24;
  int rp = r * 64 + l;

  // depthwise 3x3 for this half's 16 channels
#pragma unroll
  for (int c = 0; c < 16; ++c) {
    int oc = h * 16 + c;
    const float* src = g1 + oc * PIX + n * 4096;
    const float* w = dw + oc * 9;        // uniform -> s_load
    float r0 = (y > 0)  ? src[(y - 1) * 64 + l] : 0.f;
    float r1 = src[y * 64 + l];
    float r2 = (y < 63) ? src[(y + 1) * 64 + l] : 0.f;
    float l0 = __shfl_up(r0, 1), t0 = __shfl_down(r0, 1);
    float l1 = __shfl_up(r1, 1), t1 = __shfl_down(r1, 1);
    float l2 = __shfl_up(r2, 1), t2 = __shfl_down(r2, 1);
    if (l == 0)  { l0 = 0.f; l1 = 0.f; l2 = 0.f; }
    if (l == 63) { t0 = 0.f; t1 = 0.f; t2 = 0.f; }
    float acc = 0.f;
    acc = fmaf(l0, w[0], acc); acc = fmaf(r0, w[1], acc); acc = fmaf(t0, w[2], acc);
    acc = fmaf(l1, w[3], acc); acc = fmaf(r1, w[4], acc); acc = fmaf(t1, w[5], acc);
    acc = fmaf(l2, w[6], acc); acc = fmaf(r2, w[7], acc); acc = fmaf(t2, w[8], acc);
    g2s[rp][oc] = acc;
  }
  __syncthreads();
  float g2a[32];
#pragma unroll
  for (int c = 0; c < 32; ++c) g2a[c] = g2s[rp][c];

  // sg3 + forcing for this half's 16 eigenchannels
#pragma unroll
  for (int c = 0; c < 16; ++c) {
    int e = h * 16 + c;
    float acc = b2[e];
#pragma unroll
    for (int k = 0; k < 32; ++k)
      acc = fmaf(g2a[k], w2[e * 32 + k], acc);     // uniform -> s_load
    float spg = sigmoidf_(acc);
    int ie = n * 32 + e;
    float gc = gate[ie] * spg;
    float xr = xe[e * PIX + g];
    float xi = xe[(32 + e) * PIX + g];
    float om = 1.f - gc;
    float fr2 = xr * gc + srcr[ie] * om;
    float fi2 = xi * gc + srci[ie] * om;
    float ofr = ofr_p[ie], ofi = ofi_p[ie];
    float ur = fr2 * ofr - fi2 * ofi;
    float ui = fr2 * ofi + fi2 * ofr;
    if (t == 0) {                       // block-uniform branch
      int hb = (b * 4096 + (g & 4095)) * 32 + e;
      float hr = hre[hb], hi = him[hb];
      float odr = odr_p[(b * 24) * 32 + e], odi = odi_p[(b * 24) * 32 + e];
      ur += hr * odr - hi * odi;
      ui += hr * odi + hi * odr;
    }
    xe[e * PIX + g] = ur;
    xe[(32 + e) * PIX + g] = ui;
  }
}

// ---------------- temporal scan over T=24 on planes (in place), emit h_out ----------------
__global__ void __launch_bounds__(256) k_scan(
    float* __restrict__ u, const float* __restrict__ odr_p,
    const float* __restrict__ odi_p, float* __restrict__ out) {
  int p = blockIdx.x * 256 + threadIdx.x;   // 0..4095
  int e = blockIdx.y;                        // 0..31 (block-uniform)
  int b = blockIdx.z;                        // 0..1
  float ur = 0.f, ui = 0.f;
  for (int t = 0; t < 24; ++t) {
    int n = b * 24 + t;
    int idx  = e * PIX + n * 4096 + p;
    int idxi = (32 + e) * PIX + n * 4096 + p;
    float ar = odr_p[n * 32 + e];
    float ai = odi_p[n * 32 + e];
    float xr = u[idx], xi = u[idxi];
    float nr = ar * ur - ai * ui + xr;
    float ni = ar * ui + ai * ur + xi;
    ur = nr; ui = ni;
    u[idx] = ur;
    u[idxi] = ui;
  }
  out[HOUT_RE + (b * 4096 + p) * 32 + e] = ur;
  out[HOUT_IM + (b * 4096 + p) * 32 + e] = ui;
}

// ---------------- dec(Winv MFMA) + LN_t + FFN MFMA + z = x_upd + dec + delta --------------
__global__ void __launch_bounds__(256) k_final(
    const float* __restrict__ u, float* __restrict__ out,
    const unsigned* __restrict__ wibP,
    const float* __restrict__ lg, const float* __restrict__ lb,
    const float* __restrict__ w1, const float* __restrict__ b1,
    const float* __restrict__ w2, const float* __restrict__ b2) {
  __shared__ unsigned wiT[64][33];
  __shared__ unsigned w1T[128][33];
  __shared__ unsigned w2T[64][65];
  __shared__ unsigned dnp[64][33];
  __shared__ unsigned ho[64][65];
  __shared__ float ps1[64][5];
  __shared__ float ps2[64][5];

  int tid = threadIdx.x;
  int gbase = blockIdx.x * 256;
  int l = tid & 63, wv = tid >> 6;
  int l15 = l & 15, l4 = l >> 4;
  int p64 = l, q = wv;

  {
#pragma unroll
    for (int i = 0; i < 8; ++i) {
      int idx = tid + i * 256;
      wiT[idx >> 5][idx & 31] = wibP[idx];
    }
    int hid = tid & 127, half = tid >> 7;
#pragma unroll
    for (int i = 0; i < 16; ++i) {
      int cp = half * 16 + i;
      w1T[hid][cp] = pk2(w1[(2 * cp) * 128 + hid], w1[(2 * cp + 1) * 128 + hid]);
    }
#pragma unroll
    for (int i = 0; i < 16; ++i) {
      int hp = wv * 16 + i;
      w2T[l][hp] = pk2(w2[(2 * hp) * 64 + l], w2[(2 * hp + 1) * 64 + l]);
    }
  }
  float bb1v[8], bb2v[4];
#pragma unroll
  for (int Hn = 0; Hn < 8; ++Hn) bb1v[Hn] = b1[Hn * 16 + l15];
#pragma unroll
  for (int On = 0; On < 4; ++On) bb2v[On] = b2[On * 16 + l15];
  __syncthreads();

  for (int ph = 0; ph < 4; ++ph) {
    int gg = gbase + ph * 64 + p64;
    int arow = wv * 16 + l15;

    float uv[16];
#pragma unroll
    for (int i = 0; i < 16; ++i) uv[i] = u[(q * 16 + i) * PIX + gg];
#pragma unroll
    for (int ii = 0; ii < 8; ++ii)
      dnp[p64][q * 8 + ii] = pk2(uv[2 * ii], uv[2 * ii + 1]);
    __syncthreads();   // A

    {
      FU a0, a1;
#pragma unroll
      for (int jj = 0; jj < 4; ++jj) {
        a0.u[jj] = dnp[arow][l4 * 4 + jj];
        a1.u[jj] = dnp[arow][16 + l4 * 4 + jj];
      }
      float (*decf)[65] = (float(*)[65])ho;
#pragma unroll
      for (int Nt = 0; Nt < 4; ++Nt) {
        f32x4 acc = (f32x4){0.f, 0.f, 0.f, 0.f};
        FU b0f, b1f;
        int brow = Nt * 16 + l15;
#pragma unroll
        for (int jj = 0; jj < 4; ++jj) {
          b0f.u[jj] = wiT[brow][l4 * 4 + jj];
          b1f.u[jj] = wiT[brow][16 + l4 * 4 + jj];
        }
        acc = __builtin_amdgcn_mfma_f32_16x16x32_bf16(a0.f, b0f.f, acc, 0, 0, 0);
        acc = __builtin_amdgcn_mfma_f32_16x16x32_bf16(a1.f, b1f.f, acc, 0, 0, 0);
#pragma unroll
        for (int r = 0; r < 4; ++r)
          decf[wv * 16 + l4 * 4 + r][Nt * 16 + l15] = acc[r];
      }
    }
    __syncthreads();   // B

    float dv[16];
    float s1 = 0.f, s2 = 0.f;
    {
      float (*decf)[65] = (float(*)[65])ho;
#pragma unroll
      for (int i = 0; i < 16; ++i) {
        dv[i] = decf[p64][q * 16 + i];
        s1 += dv[i];
        s2 += dv[i] * dv[i];
      }
    }
    ps1[p64][q] = s1;
    ps2[p64][q] = s2;
    __syncthreads();   // C
    float m  = (ps1[p64][0] + ps1[p64][1] + ps1[p64][2] + ps1[p64][3]) * (1.f / 64.f);
    float e2 = (ps2[p64][0] + ps2[p64][1] + ps2[p64][2] + ps2[p64][3]) * (1.f / 64.f);
    float rs = rsqrtf(e2 - m * m + 1e-5f);
#pragma unroll
    for (int ii = 0; ii < 8; ++ii) {
      int c0 = q * 16 + 2 * ii;
      float a = (dv[2 * ii]     - m) * rs * lg[c0]     + lb[c0];
      float bvl = (dv[2 * ii + 1] - m) * rs * lg[c0 + 1] + lb[c0 + 1];
      dnp[p64][q * 8 + ii] = pk2(a, bvl);
    }
    __syncthreads();   // D

    FU a0, a1;
#pragma unroll
    for (int jj = 0; jj < 4; ++jj) {
      a0.u[jj] = dnp[arow][l4 * 4 + jj];
      a1.u[jj] = dnp[arow][16 + l4 * 4 + jj];
    }
    f32x4 acc[8];
#pragma unroll
    for (int Hn = 0; Hn < 8; ++Hn) {
      float bb = bb1v[Hn];
      acc[Hn] = (f32x4){bb, bb, bb, bb};
      FU b0f, b1f;
      int brow = Hn * 16 + l15;
#pragma unroll
      for (int jj = 0; jj < 4; ++jj) {
        b0f.u[jj] = w1T[brow][l4 * 4 + jj];
        b1f.u[jj] = w1T[brow][16 + l4 * 4 + jj];
      }
      acc[Hn] = __builtin_amdgcn_mfma_f32_16x16x32_bf16(a0.f, b0f.f, acc[Hn], 0, 0, 0);
      acc[Hn] = __builtin_amdgcn_mfma_f32_16x16x32_bf16(a1.f, b1f.f, acc[Hn], 0, 0, 0);
    }
    unsigned short (*hidb)[130] = (unsigned short(*)[130])ho;
#pragma unroll
    for (int Hn = 0; Hn < 8; ++Hn) {
#pragma unroll
      for (int r = 0; r < 4; ++r) {
        float v = acc[Hn][r];
        v = v * sigmoidf_(v);
        hidb[wv * 16 + l4 * 4 + r][Hn * 16 + l15] = f2bf(v);
      }
    }
    __syncthreads();   // E: TBAA fence (ushort stores -> u32 loads)

    FU a2[4];
#pragma unroll
    for (int kk = 0; kk < 4; ++kk)
#pragma unroll
      for (int jj = 0; jj < 4; ++jj)
        a2[kk].u[jj] = ((unsigned(*)[65])ho)[arow][kk * 16 + l4 * 4 + jj];
    f32x4 acc2[4];
#pragma unroll
    for (int On = 0; On < 4; ++On) {
      float bb = bb2v[On];
      acc2[On] = (f32x4){bb, bb, bb, bb};
#pragma unroll
      for (int kk = 0; kk < 4; ++kk) {
        FU b2f;
#pragma unroll
        for (int jj = 0; jj < 4; ++jj)
          b2f.u[jj] = w2T[On * 16 + l15][kk * 16 + l4 * 4 + jj];
        acc2[On] = __builtin_amdgcn_mfma_f32_16x16x32_bf16(a2[kk].f, b2f.f, acc2[On], 0, 0, 0);
      }
    }
    float (*o2f)[65] = (float(*)[65])ho;
#pragma unroll
    for (int On = 0; On < 4; ++On)
#pragma unroll
      for (int r = 0; r < 4; ++r)
        o2f[wv * 16 + l4 * 4 + r][On * 16 + l15] = acc2[On][r];
    __syncthreads();   // F

    {
      int nn = gg >> 12, pim = gg & 4095;
#pragma unroll
      for (int i = 0; i < 16; ++i) {
        int c = q * 16 + i;
        float val = o2f[p64][c] + dv[i];
        int d = c & 31;
        long off = ((c < 32) ? (long)MAIN_RE : (long)MAIN_IM) + (long)(nn * 32 + d) * 4096 + pim;
        out[off] += val;
      }
    }
    __syncthreads();   // G: protect ho (o2f) reads vs next-phase decf writes
  }
}

extern "C" void kernel_launch(void* const* d_in, const int* in_sizes, int n_in,
                              void* d_out, int out_size, void* d_ws, size_t ws_size,
                              hipStream_t stream) {
  (void)in_sizes; (void)n_in; (void)out_size; (void)ws_size;
  const float* xre      = (const float*)d_in[0];
  const float* xim      = (const float*)d_in[1];
  const float* hre      = (const float*)d_in[2];
  const float* him      = (const float*)d_in[3];
  const float* flux_re  = (const float*)d_in[4];
  const float* flux_im  = (const float*)d_in[5];
  const float* dt_seq   = (const float*)d_in[6];
  const float* ln_s_g   = (const float*)d_in[7];
  const float* ln_s_b   = (const float*)d_in[8];
  const float* conv_w   = (const float*)d_in[9];
  const float* conv_b   = (const float*)d_in[10];
  const float* ln_t_g   = (const float*)d_in[11];
  const float* ln_t_b   = (const float*)d_in[12];
  const float* W_re     = (const float*)d_in[13];
  const float* W_im     = (const float*)d_in[14];
  const float* lam_flux = (const float*)d_in[15];
  const float* bf_re    = (const float*)d_in[16];
  const float* bf_im    = (const float*)d_in[17];
  const float* c_re     = (const float*)d_in[18];
  const float* c_im     = (const float*)d_in[19];
  const float* g_w      = (const float*)d_in[20];
  const float* g_b      = (const float*)d_in[21];
  const float* a_decay  = (const float*)d_in[22];
  const float* b_freq   = (const float*)d_in[23];
  const float* ffn_w1   = (const float*)d_in[24];
  const float* ffn_b1   = (const float*)d_in[25];
  const float* ffn_w2   = (const float*)d_in[26];
  const float* ffn_b2   = (const float*)d_in[27];
  const float* sg_w1    = (const float*)d_in[28];
  const float* sg_b1    = (const float*)d_in[29];
  const float* sg_dw    = (const float*)d_in[30];
  const float* sg_w2    = (const float*)d_in[31];
  const float* sg_b2    = (const float*)d_in[32];
  float* out = (float*)d_out;
  float* ws  = (float*)d_ws;

  k_invert<<<1, 256, 0, stream>>>(W_re, W_im, ws);
  k_wprep<<<144, 256, 0, stream>>>(conv_w, (unsigned short*)(ws + WS_WPK));
  k_eprep<<<8, 256, 0, stream>>>(W_re, W_im, sg_w1,
                                 (unsigned*)(ws + WS_WE), (unsigned*)(ws + WS_SG));
  k_ln_s<<<PIX / 256, 256, 0, stream>>>(xre, xim, ln_s_g, ln_s_b, ws);
  k_conv<<<768, 256, 0, stream>>>((const unsigned*)(ws + WS_XN),
                                  (const unsigned short*)(ws + WS_WPK),
                                  conv_b, xre, xim, out);
  k_xeig<<<768, 256, 0, stream>>>(out, (const unsigned*)(ws + WS_WE),
                                  (const unsigned*)(ws + WS_SG),
                                  ws + WS_XE, ws + WS_G1, sg_b1, ws + WS_PART);
  k_flux<<<1, 64, 0, stream>>>(ws, out, dt_seq, flux_re, flux_im, lam_flux,
                               bf_re, bf_im, c_re, c_im, g_w, g_b, a_decay, b_freq);
  k_gate<<<PIX / 128, 256, 0, stream>>>(ws + WS_G1, ws + WS_XE,
                                        ws + WS_GATE, ws + WS_SRCR, ws + WS_SRCI,
                                        ws + WS_OFR, ws + WS_OFI, ws + WS_ODR, ws + WS_ODI,
                                        hre, him, sg_dw, sg_w2, sg_b2);
  k_scan<<<dim3(4096 / 256, 32, 2), 256, 0, stream>>>(ws + WS_XE, ws + WS_ODR, ws + WS_ODI, out);
  k_final<<<768, 256, 0, stream>>>(ws + WS_XE, out, (const unsigned*)(ws + WS_WIB),
                                   ln_t_g, ln_t_b, ffn_w1, ffn_b1, ffn_w2, ffn_b2);
}

// Round 13
// 335.200 us; speedup vs baseline: 8.7629x; 1.0394x over previous
//
#include <hip/hip_runtime.h>
#include <math.h>

#define BB 2
#define TT 24
#define DD 32
#define HWp 4096            // 64*64
#define NN (BB*TT)          // 48
#define PIX (NN*HWp)        // 196608
#define C2 (2*DD)           // 64

// d_out offsets (floats)
#define MAIN_RE 0
#define MAIN_IM (NN*DD*HWp)              // 6291456
#define HOUT_RE (2*NN*DD*HWp)            // 12582912
#define HOUT_IM (HOUT_RE + BB*HWp*DD)    // 12845056
#define FLUX_RE (HOUT_RE + 2*BB*HWp*DD)  // 13107200
#define FLUX_IM (FLUX_RE + BB*DD)        // 13107264

// ws offsets (floats)
#define WS_XN   0                        // PIX*64 (bf16 xn for conv)
#define WS_XE   (WS_XN + PIX*C2)         // PIX*64  xe -> u planes
#define WS_G1   (WS_XE + PIX*C2)         // PIX*32  g1 planes
#define WS_G2   (WS_G1 + PIX*DD)         // PIX*32  spg planes
#define WS_WINV (WS_G2 + PIX*DD)         // 2048 f32
#define WS_SUMS (WS_WINV + 2048)         // 3072 (unused)
#define WS_GATE (WS_SUMS + 3072)         // 1536
#define WS_SRCR (WS_GATE + 1536)
#define WS_SRCI (WS_SRCR + 1536)
#define WS_ODR  (WS_SRCI + 1536)
#define WS_ODI  (WS_ODR + 1536)
#define WS_OFR  (WS_ODI + 1536)
#define WS_OFI  (WS_OFR + 1536)
#define WS_WPK  (WS_OFI + 1536)          // 36864 ushorts = 18432 floats
#define WS_PART (WS_WPK + 18432)         // 48*16*64 floats
#define WS_WE   (WS_PART + 49152)        // 2048 u32 eig weights
#define WS_SG   (WS_WE + 2048)           // 1024 u32 sg1 weights
#define WS_WIB  (WS_SG + 1024)           // 2048 u32 Winv packed bf16 B-frag

typedef __attribute__((ext_vector_type(8))) short bf16x8;
typedef __attribute__((ext_vector_type(4))) float f32x4;
union FU { unsigned u[4]; bf16x8 f; };
union FU4 { uint4 v; unsigned u[4]; bf16x8 f; };

__device__ __forceinline__ float sigmoidf_(float x) { return 1.f / (1.f + expf(-x)); }
__device__ __forceinline__ float softplusf_(float x) { return log1pf(expf(x)); }
__device__ __forceinline__ unsigned short f2bf(float f) {
  unsigned u = __float_as_uint(f);
  return (unsigned short)((u + 0x7FFFu + ((u >> 16) & 1u)) >> 16);   // RNE
}
__device__ __forceinline__ unsigned pk2(float lo, float hi) {
  return (unsigned)f2bf(lo) | ((unsigned)f2bf(hi) << 16);
}

// ---------------- Gauss-Jordan inverse of Wb (32x32 complex) + bf16 B-frag pack ----------
__global__ void k_invert(const float* __restrict__ Wre, const float* __restrict__ Wim,
                         float* __restrict__ ws) {
  __shared__ float Mre[32][64];
  __shared__ float Mim[32][64];
  __shared__ float fre[32], fim[32];
  __shared__ float pr_s, pi_s;
  __shared__ int piv_s;
  int tid = threadIdx.x;  // 256 threads
  for (int idx = tid; idx < 2048; idx += 256) {
    int i = idx >> 6, j = idx & 63;
    if (j < 32) { Mre[i][j] = Wre[i * 32 + j]; Mim[i][j] = Wim[i * 32 + j]; }
    else        { Mre[i][j] = (j - 32 == i) ? 1.f : 0.f; Mim[i][j] = 0.f; }
  }
  __syncthreads();
  for (int k = 0; k < 32; ++k) {
    if (tid == 0) {
      int best = k; float bm = fabsf(Mre[k][k]) + fabsf(Mim[k][k]);
      for (int r = k + 1; r < 32; ++r) {
        float m = fabsf(Mre[r][k]) + fabsf(Mim[r][k]);
        if (m > bm) { bm = m; best = r; }
      }
      piv_s = best;
    }
    __syncthreads();
    int pv = piv_s;
    if (pv != k && tid < 64) {
      float tr = Mre[k][tid], ti = Mim[k][tid];
      Mre[k][tid] = Mre[pv][tid]; Mim[k][tid] = Mim[pv][tid];
      Mre[pv][tid] = tr; Mim[pv][tid] = ti;
    }
    __syncthreads();
    if (tid == 0) {
      float a = Mre[k][k], b = Mim[k][k];
      float d = a * a + b * b;
      pr_s = a / d; pi_s = -b / d;
    }
    __syncthreads();
    float pr = pr_s, pi = pi_s;
    if (tid < 64) {
      float a = Mre[k][tid], b = Mim[k][tid];
      Mre[k][tid] = a * pr - b * pi;
      Mim[k][tid] = a * pi + b * pr;
    }
    __syncthreads();
    if (tid < 32) { fre[tid] = Mre[tid][k]; fim[tid] = Mim[tid][k]; }
    __syncthreads();
    for (int idx = tid; idx < 2048; idx += 256) {
      int i = idx >> 6, j = idx & 63;
      if (i != k) {
        float fr = fre[i], fi = fim[i];
        float ar = Mre[k][j], ai = Mim[k][j];
        Mre[i][j] -= fr * ar - fi * ai;
        Mim[i][j] -= fr * ai + fi * ar;
      }
    }
    __syncthreads();
  }
  for (int idx = tid; idx < 1024; idx += 256) {
    int e = idx >> 5, d = idx & 31;
    ws[WS_WINV + e * 32 + d] = Mre[e][32 + d];
    ws[WS_WINV + 1024 + e * 32 + d] = Mim[e][32 + d];
  }
  unsigned* wib = (unsigned*)(ws + WS_WIB);
  for (int idx = tid; idx < 2048; idx += 256) {
    int j = idx >> 5, kp = idx & 31;
    float v[2];
#pragma unroll
    for (int h = 0; h < 2; ++h) {
      int k = 2 * kp + h;
      float x;
      if (j < 32) x = (k < 32) ? Mre[k][32 + j] : -Mim[k - 32][32 + j];
      else        x = (k < 32) ? Mim[k][32 + (j - 32)] : Mre[k - 32][32 + (j - 32)];
      v[h] = x;
    }
    wib[idx] = pk2(v[0], v[1]);
  }
}

// ---------------- weight pre-pack: wpack[tap][oc][ci] bf16 <- conv_w[oc][ci][tap] f32 ----
__global__ void k_wprep(const float* __restrict__ w, unsigned short* __restrict__ wpk) {
  int idx = blockIdx.x * 256 + threadIdx.x;
  if (idx >= 9 * 64 * 64) return;
  int tap = idx >> 12;
  int rem = idx & 4095;
  int oc = rem >> 6, ci = rem & 63;
  wpk[idx] = f2bf(w[(oc * 64 + ci) * 9 + tap]);
}

// ---------------- eig + sg1 weight pre-pack (bf16 [N][Kpair] B-fragment layout) ----------
__global__ void k_eprep(const float* __restrict__ Wre, const float* __restrict__ Wim,
                        const float* __restrict__ sgw1,
                        unsigned* __restrict__ we, unsigned* __restrict__ sg) {
  int idx = blockIdx.x * 256 + threadIdx.x;
  if (idx < 2048) {
    int j = idx >> 5, kp = idx & 31;
    float v[2];
#pragma unroll
    for (int h = 0; h < 2; ++h) {
      int k = 2 * kp + h;
      float x;
      if (j < 32) x = (k < 32) ? Wre[k * 32 + j] : -Wim[(k - 32) * 32 + j];
      else        x = (k < 32) ? Wim[k * 32 + (j - 32)] : Wre[(k - 32) * 32 + (j - 32)];
      v[h] = x;
    }
    we[idx] = pk2(v[0], v[1]);
  }
  if (idx < 1024) {
    int oc = idx >> 5, kp = idx & 31;
    sg[idx] = pk2(sgw1[oc * 64 + 2 * kp], sgw1[oc * 64 + 2 * kp + 1]);
  }
}

// ---------------- spatial LayerNorm -> xn bf16 channels-last [n][pix][64] ----------------
__global__ void k_ln_s(const float* __restrict__ xre, const float* __restrict__ xim,
                       const float* __restrict__ g, const float* __restrict__ b,
                       float* __restrict__ ws) {
  int gid = blockIdx.x * 256 + threadIdx.x;
  if (gid >= PIX) return;
  int n = gid >> 12, p = gid & 4095;
  float v[64];
  float s = 0.f;
#pragma unroll
  for (int c = 0; c < 32; ++c) { v[c] = xre[(n * 32 + c) * 4096 + p]; s += v[c]; }
#pragma unroll
  for (int c = 0; c < 32; ++c) { v[32 + c] = xim[(n * 32 + c) * 4096 + p]; s += v[32 + c]; }
  float m = s * (1.f / 64.f);
  float vs = 0.f;
#pragma unroll
  for (int c = 0; c < 64; ++c) { float d = v[c] - m; vs += d * d; }
  float rs = rsqrtf(vs * (1.f / 64.f) + 1e-5f);
#pragma unroll
  for (int c = 0; c < 64; ++c) v[c] = (v[c] - m) * rs * g[c] + b[c];
  uint4* dst = (uint4*)ws + gid * 8;
#pragma unroll
  for (int q = 0; q < 8; ++q) {
    uint4 u;
    u.x = pk2(v[q * 8 + 0], v[q * 8 + 1]);
    u.y = pk2(v[q * 8 + 2], v[q * 8 + 3]);
    u.z = pk2(v[q * 8 + 4], v[q * 8 + 5]);
    u.w = pk2(v[q * 8 + 6], v[q * 8 + 7]);
    dst[q] = u;
  }
}

// ---------------- 3x3 conv 64->64 as 9 shifted bf16 MFMA GEMMs ----------------
__global__ void __launch_bounds__(256) k_conv(
    const unsigned* __restrict__ xnb_u, const unsigned short* __restrict__ wpk,
    const float* __restrict__ bconv,
    const float* __restrict__ xre, const float* __restrict__ xim,
    float* __restrict__ out) {
  __shared__ unsigned xls[6 * 66 * 36];
  int bid = blockIdx.x;
  int n = bid >> 4;
  int y0 = (bid & 15) * 4;
  int tid = threadIdx.x;
  int wv = tid >> 6, l = tid & 63;
  int l15 = l & 15, l4 = l >> 4;

  const uint4* xnb4 = (const uint4*)xnb_u;
  for (int idx = tid; idx < 396; idx += 256) {
    int r = idx / 66, c = idx - r * 66;
    int y = y0 - 1 + r, x = c - 1;
    bool valid = ((unsigned)y < 64u) & ((unsigned)x < 64u);
    int pg = n * 4096 + y * 64 + x;
    uint4 z; z.x = z.y = z.z = z.w = 0u;
#pragma unroll
    for (int q = 0; q < 8; ++q) {
      uint4 v = valid ? xnb4[pg * 8 + q] : z;
      *(uint4*)&xls[idx * 36 + q * 4] = v;
    }
  }
  __syncthreads();

  f32x4 acc[4][4];
#pragma unroll
  for (int Nt = 0; Nt < 4; ++Nt) {
    float bb = bconv[Nt * 16 + l15];
#pragma unroll
    for (int mt = 0; mt < 4; ++mt) acc[mt][Nt] = (f32x4){bb, bb, bb, bb};
  }

  const uint4* wq = (const uint4*)wpk;
#pragma unroll
  for (int tap = 0; tap < 9; ++tap) {
    int ky = tap / 3, kx = tap - ky * 3;
    int rowbase = (wv + ky) * 66 + kx + l15;
#pragma unroll
    for (int ks = 0; ks < 2; ++ks) {
      FU4 B[4];
#pragma unroll
      for (int Nt = 0; Nt < 4; ++Nt)
        B[Nt].v = wq[tap * 512 + (Nt * 16 + l15) * 8 + ks * 4 + l4];
#pragma unroll
      for (int mt = 0; mt < 4; ++mt) {
        FU4 A;
        A.v = *(const uint4*)&xls[(rowbase + mt * 16) * 36 + ks * 16 + l4 * 4];
#pragma unroll
        for (int Nt = 0; Nt < 4; ++Nt)
          acc[mt][Nt] = __builtin_amdgcn_mfma_f32_16x16x32_bf16(A.f, B[Nt].f, acc[mt][Nt], 0, 0, 0);
      }
    }
  }

#pragma unroll
  for (int Nt = 0; Nt < 4; ++Nt) {
    int oc = Nt * 16 + l15;
    int d = oc & 31;
    const float* resid = (oc < 32) ? xre : xim;
    float* dst = out + ((oc < 32) ? MAIN_RE : MAIN_IM) + (n * 32 + d) * 4096;
    const float* rsd = resid + (n * 32 + d) * 4096;
#pragma unroll
    for (int mt = 0; mt < 4; ++mt) {
      int pixbase = (y0 + wv) * 64 + mt * 16 + l4 * 4;
#pragma unroll
      for (int r = 0; r < 4; ++r)
        dst[pixbase + r] = rsd[pixbase + r] + acc[mt][Nt][r];
    }
  }
}

// ---------------- x_eig v2: bf16 MFMA dual-GEMM (eig 64->64, sg1 64->32) + channel sums ----
__global__ void __launch_bounds__(256) k_xeig(
    const float* __restrict__ out, const unsigned* __restrict__ weP,
    const unsigned* __restrict__ sgP, float* __restrict__ xe,
    float* __restrict__ g1, const float* __restrict__ sgb1,
    float* __restrict__ part) {
  __shared__ unsigned WeT[64][33];
  __shared__ unsigned SgT[32][33];
  __shared__ unsigned xp[64][33];
  __shared__ float xef[64][66];   // stride 66: 2-way bank alias (free)

  int tid = threadIdx.x;
  int gbase = blockIdx.x * 256;
  int l = tid & 63, wv = tid >> 6;
  int l15 = l & 15, l4 = l >> 4;
  int p64 = l, q = wv;

  {
#pragma unroll
    for (int i = 0; i < 8; ++i) {
      int idx = tid + i * 256;
      WeT[idx >> 5][idx & 31] = weP[idx];
    }
#pragma unroll
    for (int i = 0; i < 4; ++i) {
      int idx = tid + i * 256;
      SgT[idx >> 5][idx & 31] = sgP[idx];
    }
  }
  float ssum[16];
#pragma unroll
  for (int i = 0; i < 16; ++i) ssum[i] = 0.f;
  __syncthreads();

  for (int ph = 0; ph < 4; ++ph) {
    int gg = gbase + ph * 64 + p64;
    int n = gg >> 12, p = gg & 4095;

    float xv[16];
#pragma unroll
    for (int i = 0; i < 16; ++i) {
      int c = q * 16 + i;
      xv[i] = (c < 32) ? out[MAIN_RE + (n * 32 + c) * 4096 + p]
                       : out[MAIN_IM + (n * 32 + (c - 32)) * 4096 + p];
    }
#pragma unroll
    for (int ii = 0; ii < 8; ++ii)
      xp[p64][q * 8 + ii] = pk2(xv[2 * ii], xv[2 * ii + 1]);
    __syncthreads();   // A

    int arow = wv * 16 + l15;
    FU a0, a1;
#pragma unroll
    for (int jj = 0; jj < 4; ++jj) {
      a0.u[jj] = xp[arow][l4 * 4 + jj];
      a1.u[jj] = xp[arow][16 + l4 * 4 + jj];
    }
#pragma unroll
    for (int Nt = 0; Nt < 4; ++Nt) {
      f32x4 acc = (f32x4){0.f, 0.f, 0.f, 0.f};
      FU b0f, b1f;
      int brow = Nt * 16 + l15;
#pragma unroll
      for (int jj = 0; jj < 4; ++jj) {
        b0f.u[jj] = WeT[brow][l4 * 4 + jj];
        b1f.u[jj] = WeT[brow][16 + l4 * 4 + jj];
      }
      acc = __builtin_amdgcn_mfma_f32_16x16x32_bf16(a0.f, b0f.f, acc, 0, 0, 0);
      acc = __builtin_amdgcn_mfma_f32_16x16x32_bf16(a1.f, b1f.f, acc, 0, 0, 0);
#pragma unroll
      for (int r = 0; r < 4; ++r)
        xef[wv * 16 + l4 * 4 + r][Nt * 16 + l15] = acc[r];
    }
    __syncthreads();   // B

    float xo[16];
#pragma unroll
    for (int i = 0; i < 16; ++i) {
      xo[i] = xef[p64][q * 16 + i];
      ssum[i] += xo[i];
      xe[(q * 16 + i) * PIX + gg] = xo[i];
    }
#pragma unroll
    for (int ii = 0; ii < 8; ++ii)
      xp[p64][q * 8 + ii] = pk2(xo[2 * ii], xo[2 * ii + 1]);
    __syncthreads();   // C

    FU c0, c1;
#pragma unroll
    for (int jj = 0; jj < 4; ++jj) {
      c0.u[jj] = xp[arow][l4 * 4 + jj];
      c1.u[jj] = xp[arow][16 + l4 * 4 + jj];
    }
#pragma unroll
    for (int Nt = 0; Nt < 2; ++Nt) {
      float bb = sgb1[Nt * 16 + l15];
      f32x4 acc = (f32x4){bb, bb, bb, bb};
      FU b0f, b1f;
      int brow = Nt * 16 + l15;
#pragma unroll
      for (int jj = 0; jj < 4; ++jj) {
        b0f.u[jj] = SgT[brow][l4 * 4 + jj];
        b1f.u[jj] = SgT[brow][16 + l4 * 4 + jj];
      }
      acc = __builtin_amdgcn_mfma_f32_16x16x32_bf16(c0.f, b0f.f, acc, 0, 0, 0);
      acc = __builtin_amdgcn_mfma_f32_16x16x32_bf16(c1.f, b1f.f, acc, 0, 0, 0);
#pragma unroll
      for (int r = 0; r < 4; ++r) {
        float v = acc[r];
        xef[wv * 16 + l4 * 4 + r][Nt * 16 + l15] = v * sigmoidf_(v);
      }
    }
    __syncthreads();   // D

#pragma unroll
    for (int i = 0; i < 8; ++i)
      g1[(q * 8 + i) * PIX + gg] = xef[p64][q * 8 + i];
  }

#pragma unroll
  for (int i = 0; i < 16; ++i) {
    float v = ssum[i];
    v += __shfl_xor(v, 1);
    v += __shfl_xor(v, 2);
    v += __shfl_xor(v, 4);
    v += __shfl_xor(v, 8);
    v += __shfl_xor(v, 16);
    v += __shfl_xor(v, 32);
    if (l == 0) part[blockIdx.x * 64 + q * 16 + i] = v;
  }
}

// ---------------- flux scan (T=24) + all per-(b,t,d) coefficients ----------------
__global__ void k_flux(float* __restrict__ ws, float* __restrict__ out,
                       const float* __restrict__ dt_seq,
                       const float* __restrict__ flux_re, const float* __restrict__ flux_im,
                       const float* __restrict__ lam_flux,
                       const float* __restrict__ bf_re, const float* __restrict__ bf_im,
                       const float* __restrict__ c_re, const float* __restrict__ c_im,
                       const float* __restrict__ g_w, const float* __restrict__ g_b,
                       const float* __restrict__ a_decay, const float* __restrict__ b_freq) {
  int tid = threadIdx.x;
  if (tid >= 64) return;
  int b = tid >> 5, e = tid & 31;
  float sp_lf = softplusf_(lam_flux[e]);
  float lr = -softplusf_(a_decay[e]);
  float li = b_freq[e];
  float den = lr * lr + li * li;
  float bfr = bf_re[e], bfi = bf_im[e];
  float cr = c_re[e], ci = c_im[e];
  float fr = flux_re[b * 32 + e], fi = flux_im[b * 32 + e];
  const float* part = ws + WS_PART;
  for (int t = 0; t < 24; ++t) {
    int n = b * 24 + t;
    float dt = dt_seq[n];
    float A = expf(-sp_lf * dt);
    float xmr = 0.f, xmi = 0.f;
#pragma unroll
    for (int j = 0; j < 16; ++j) {
      xmr += part[(n * 16 + j) * 64 + e];
      xmi += part[(n * 16 + j) * 64 + 32 + e];
    }
    xmr *= (1.f / 4096.f);
    xmi *= (1.f / 4096.f);
    float Xr = (bfr * xmr - bfi * xmi) * dt;
    float Xi = (bfr * xmi + bfi * xmr) * dt;
    fr = A * fr + Xr;
    fi = A * fi + Xi;
    ws[WS_GATE + n * 32 + e] = sigmoidf_(fr * g_w[e] + g_b[e]);
    ws[WS_SRCR + n * 32 + e] = fr * cr - fi * ci;
    ws[WS_SRCI + n * 32 + e] = fr * ci + fi * cr;
    float er = expf(lr * dt);
    float odr = er * cosf(li * dt);
    float odi = er * sinf(li * dt);
    ws[WS_ODR + n * 32 + e] = odr;
    ws[WS_ODI + n * 32 + e] = odi;
    float nr = odr - 1.f, ni = odi;
    ws[WS_OFR + n * 32 + e] = (nr * lr + ni * li) / den;
    ws[WS_OFI + n * 32 + e] = (ni * lr - nr * li) / den;
  }
  out[FLUX_RE + b * 32 + e] = fr;
  out[FLUX_IM + b * 32 + e] = fi;
}

// ---------------- gate v3: dw 3x3 (shuffle stencil) + sg3 + sigmoid -> spg planes ---------
// thread = (pixel, channel-half); wave = one row; g2 halves exchanged via LDS.
__global__ void __launch_bounds__(256) k_gate(
    const float* __restrict__ g1, float* __restrict__ spgP,
    const float* __restrict__ dw, const float* __restrict__ w2,
    const float* __restrict__ b2) {
  __shared__ float g2s[128][33];
  int tid = threadIdx.x;
  int l = tid & 63;
  int wv = tid >> 6;
  int r = wv >> 1, h = wv & 1;
  int pixbase = blockIdx.x * 128;
  int n = pixbase >> 12;
  int y = ((pixbase & 4095) >> 6) + r;
  int g = pixbase + r * 64 + l;
  int rp = r * 64 + l;

#pragma unroll
  for (int c = 0; c < 16; ++c) {
    int oc = h * 16 + c;
    const float* src = g1 + oc * PIX + n * 4096;
    const float* w = dw + oc * 9;        // uniform -> s_load
    float r0 = (y > 0)  ? src[(y - 1) * 64 + l] : 0.f;
    float r1 = src[y * 64 + l];
    float r2 = (y < 63) ? src[(y + 1) * 64 + l] : 0.f;
    float l0 = __shfl_up(r0, 1), t0 = __shfl_down(r0, 1);
    float l1 = __shfl_up(r1, 1), t1 = __shfl_down(r1, 1);
    float l2 = __shfl_up(r2, 1), t2 = __shfl_down(r2, 1);
    if (l == 0)  { l0 = 0.f; l1 = 0.f; l2 = 0.f; }
    if (l == 63) { t0 = 0.f; t1 = 0.f; t2 = 0.f; }
    float acc = 0.f;
    acc = fmaf(l0, w[0], acc); acc = fmaf(r0, w[1], acc); acc = fmaf(t0, w[2], acc);
    acc = fmaf(l1, w[3], acc); acc = fmaf(r1, w[4], acc); acc = fmaf(t1, w[5], acc);
    acc = fmaf(l2, w[6], acc); acc = fmaf(r2, w[7], acc); acc = fmaf(t2, w[8], acc);
    g2s[rp][oc] = acc;
  }
  __syncthreads();
  float g2a[32];
#pragma unroll
  for (int c = 0; c < 32; ++c) g2a[c] = g2s[rp][c];

#pragma unroll
  for (int c = 0; c < 16; ++c) {
    int e = h * 16 + c;
    float acc = b2[e];
#pragma unroll
    for (int k = 0; k < 32; ++k)
      acc = fmaf(g2a[k], w2[e * 32 + k], acc);     // uniform -> s_load
    spgP[e * PIX + g] = sigmoidf_(acc);
  }
}

// ---------------- fused forcing + temporal scan over T=24 (in place), emit h_out ----------
__global__ void __launch_bounds__(256) k_scan(
    float* __restrict__ u, const float* __restrict__ spgP,
    const float* __restrict__ gate, const float* __restrict__ srcr,
    const float* __restrict__ srci, const float* __restrict__ ofr_p,
    const float* __restrict__ ofi_p, const float* __restrict__ odr_p,
    const float* __restrict__ odi_p,
    const float* __restrict__ hre, const float* __restrict__ him,
    float* __restrict__ out) {
  int p = blockIdx.x * 256 + threadIdx.x;   // 0..4095
  int e = blockIdx.y;                        // 0..31 (block-uniform)
  int b = blockIdx.z;                        // 0..1
  float ur = 0.f, ui = 0.f;
  for (int t = 0; t < 24; ++t) {
    int n = b * 24 + t;
    int ie = n * 32 + e;                     // uniform -> s_load coefficients
    int idx  = e * PIX + n * 4096 + p;
    int idxi = (32 + e) * PIX + n * 4096 + p;
    // forcing
    float gc = gate[ie] * spgP[idx];
    float xr = u[idx], xi = u[idxi];
    float om = 1.f - gc;
    float fr2 = xr * gc + srcr[ie] * om;
    float fi2 = xi * gc + srci[ie] * om;
    float ofr = ofr_p[ie], ofi = ofi_p[ie];
    float utr = fr2 * ofr - fi2 * ofi;
    float uti = fr2 * ofi + fi2 * ofr;
    if (t == 0) {
      int hb = (b * 4096 + p) * 32 + e;
      float hr = hre[hb], hi = him[hb];
      float odr0 = odr_p[ie], odi0 = odi_p[ie];
      utr += hr * odr0 - hi * odi0;
      uti += hr * odi0 + hi * odr0;
    }
    // scan
    float ar = odr_p[ie], ai = odi_p[ie];
    float nr = ar * ur - ai * ui + utr;
    float ni = ar * ui + ai * ur + uti;
    ur = nr; ui = ni;
    u[idx] = ur;
    u[idxi] = ui;
  }
  out[HOUT_RE + (b * 4096 + p) * 32 + e] = ur;
  out[HOUT_IM + (b * 4096 + p) * 32 + e] = ui;
}

// ---------------- dec(Winv MFMA) + LN_t + FFN MFMA + z = x_upd + dec + delta --------------
__global__ void __launch_bounds__(256) k_final(
    const float* __restrict__ u, float* __restrict__ out,
    const unsigned* __restrict__ wibP,
    const float* __restrict__ lg, const float* __restrict__ lb,
    const float* __restrict__ w1, const float* __restrict__ b1,
    const float* __restrict__ w2, const float* __restrict__ b2) {
  __shared__ unsigned wiT[64][33];
  __shared__ unsigned w1T[128][33];
  __shared__ unsigned w2T[64][65];
  __shared__ unsigned dnp[64][33];
  __shared__ unsigned ho[64][66];   // stride 66: 2-way bank alias (free); was 65 (4-way)
  __shared__ float ps1[64][5];
  __shared__ float ps2[64][5];

  int tid = threadIdx.x;
  int gbase = blockIdx.x * 256;
  int l = tid & 63, wv = tid >> 6;
  int l15 = l & 15, l4 = l >> 4;
  int p64 = l, q = wv;

  {
#pragma unroll
    for (int i = 0; i < 8; ++i) {
      int idx = tid + i * 256;
      wiT[idx >> 5][idx & 31] = wibP[idx];
    }
    int hid = tid & 127, half = tid >> 7;
#pragma unroll
    for (int i = 0; i < 16; ++i) {
      int cp = half * 16 + i;
      w1T[hid][cp] = pk2(w1[(2 * cp) * 128 + hid], w1[(2 * cp + 1) * 128 + hid]);
    }
#pragma unroll
    for (int i = 0; i < 16; ++i) {
      int hp = wv * 16 + i;
      w2T[l][hp] = pk2(w2[(2 * hp) * 64 + l], w2[(2 * hp + 1) * 64 + l]);
    }
  }
  float bb1v[8], bb2v[4];
#pragma unroll
  for (int Hn = 0; Hn < 8; ++Hn) bb1v[Hn] = b1[Hn * 16 + l15];
#pragma unroll
  for (int On = 0; On < 4; ++On) bb2v[On] = b2[On * 16 + l15];
  __syncthreads();

  for (int ph = 0; ph < 4; ++ph) {
    int gg = gbase + ph * 64 + p64;
    int arow = wv * 16 + l15;

    float uv[16];
#pragma unroll
    for (int i = 0; i < 16; ++i) uv[i] = u[(q * 16 + i) * PIX + gg];
#pragma unroll
    for (int ii = 0; ii < 8; ++ii)
      dnp[p64][q * 8 + ii] = pk2(uv[2 * ii], uv[2 * ii + 1]);
    __syncthreads();   // A

    {
      FU a0, a1;
#pragma unroll
      for (int jj = 0; jj < 4; ++jj) {
        a0.u[jj] = dnp[arow][l4 * 4 + jj];
        a1.u[jj] = dnp[arow][16 + l4 * 4 + jj];
      }
      float (*decf)[66] = (float(*)[66])ho;
#pragma unroll
      for (int Nt = 0; Nt < 4; ++Nt) {
        f32x4 acc = (f32x4){0.f, 0.f, 0.f, 0.f};
        FU b0f, b1f;
        int brow = Nt * 16 + l15;
#pragma unroll
        for (int jj = 0; jj < 4; ++jj) {
          b0f.u[jj] = wiT[brow][l4 * 4 + jj];
          b1f.u[jj] = wiT[brow][16 + l4 * 4 + jj];
        }
        acc = __builtin_amdgcn_mfma_f32_16x16x32_bf16(a0.f, b0f.f, acc, 0, 0, 0);
        acc = __builtin_amdgcn_mfma_f32_16x16x32_bf16(a1.f, b1f.f, acc, 0, 0, 0);
#pragma unroll
        for (int r = 0; r < 4; ++r)
          decf[wv * 16 + l4 * 4 + r][Nt * 16 + l15] = acc[r];
      }
    }
    __syncthreads();   // B

    float dv[16];
    float s1 = 0.f, s2 = 0.f;
    {
      float (*decf)[66] = (float(*)[66])ho;
#pragma unroll
      for (int i = 0; i < 16; ++i) {
        dv[i] = decf[p64][q * 16 + i];
        s1 += dv[i];
        s2 += dv[i] * dv[i];
      }
    }
    ps1[p64][q] = s1;
    ps2[p64][q] = s2;
    __syncthreads();   // C
    float m  = (ps1[p64][0] + ps1[p64][1] + ps1[p64][2] + ps1[p64][3]) * (1.f / 64.f);
    float e2 = (ps2[p64][0] + ps2[p64][1] + ps2[p64][2] + ps2[p64][3]) * (1.f / 64.f);
    float rs = rsqrtf(e2 - m * m + 1e-5f);
#pragma unroll
    for (int ii = 0; ii < 8; ++ii) {
      int c0 = q * 16 + 2 * ii;
      float a = (dv[2 * ii]     - m) * rs * lg[c0]     + lb[c0];
      float bvl = (dv[2 * ii + 1] - m) * rs * lg[c0 + 1] + lb[c0 + 1];
      dnp[p64][q * 8 + ii] = pk2(a, bvl);
    }
    __syncthreads();   // D

    FU a0, a1;
#pragma unroll
    for (int jj = 0; jj < 4; ++jj) {
      a0.u[jj] = dnp[arow][l4 * 4 + jj];
      a1.u[jj] = dnp[arow][16 + l4 * 4 + jj];
    }
    f32x4 acc[8];
#pragma unroll
    for (int Hn = 0; Hn < 8; ++Hn) {
      float bb = bb1v[Hn];
      acc[Hn] = (f32x4){bb, bb, bb, bb};
      FU b0f, b1f;
      int brow = Hn * 16 + l15;
#pragma unroll
      for (int jj = 0; jj < 4; ++jj) {
        b0f.u[jj] = w1T[brow][l4 * 4 + jj];
        b1f.u[jj] = w1T[brow][16 + l4 * 4 + jj];
      }
      acc[Hn] = __builtin_amdgcn_mfma_f32_16x16x32_bf16(a0.f, b0f.f, acc[Hn], 0, 0, 0);
      acc[Hn] = __builtin_amdgcn_mfma_f32_16x16x32_bf16(a1.f, b1f.f, acc[Hn], 0, 0, 0);
    }
    unsigned short (*hidb)[132] = (unsigned short(*)[132])ho;
#pragma unroll
    for (int Hn = 0; Hn < 8; ++Hn) {
#pragma unroll
      for (int r = 0; r < 4; ++r) {
        float v = acc[Hn][r];
        v = v * sigmoidf_(v);
        hidb[wv * 16 + l4 * 4 + r][Hn * 16 + l15] = f2bf(v);
      }
    }
    __syncthreads();   // E: TBAA fence (ushort stores -> u32 loads)

    FU a2[4];
#pragma unroll
    for (int kk = 0; kk < 4; ++kk)
#pragma unroll
      for (int jj = 0; jj < 4; ++jj)
        a2[kk].u[jj] = ((unsigned(*)[66])ho)[arow][kk * 16 + l4 * 4 + jj];
    f32x4 acc2[4];
#pragma unroll
    for (int On = 0; On < 4; ++On) {
      float bb = bb2v[On];
      acc2[On] = (f32x4){bb, bb, bb, bb};
#pragma unroll
      for (int kk = 0; kk < 4; ++kk) {
        FU b2f;
#pragma unroll
        for (int jj = 0; jj < 4; ++jj)
          b2f.u[jj] = w2T[On * 16 + l15][kk * 16 + l4 * 4 + jj];
        acc2[On] = __builtin_amdgcn_mfma_f32_16x16x32_bf16(a2[kk].f, b2f.f, acc2[On], 0, 0, 0);
      }
    }
    float (*o2f)[66] = (float(*)[66])ho;
#pragma unroll
    for (int On = 0; On < 4; ++On)
#pragma unroll
      for (int r = 0; r < 4; ++r)
        o2f[wv * 16 + l4 * 4 + r][On * 16 + l15] = acc2[On][r];
    __syncthreads();   // F

    {
      int nn = gg >> 12, pim = gg & 4095;
#pragma unroll
      for (int i = 0; i < 16; ++i) {
        int c = q * 16 + i;
        float val = o2f[p64][c] + dv[i];
        int d = c & 31;
        long off = ((c < 32) ? (long)MAIN_RE : (long)MAIN_IM) + (long)(nn * 32 + d) * 4096 + pim;
        out[off] += val;
      }
    }
    __syncthreads();   // G: protect ho (o2f) reads vs next-phase decf writes
  }
}

extern "C" void kernel_launch(void* const* d_in, const int* in_sizes, int n_in,
                              void* d_out, int out_size, void* d_ws, size_t ws_size,
                              hipStream_t stream) {
  (void)in_sizes; (void)n_in; (void)out_size; (void)ws_size;
  const float* xre      = (const float*)d_in[0];
  const float* xim      = (const float*)d_in[1];
  const float* hre      = (const float*)d_in[2];
  const float* him      = (const float*)d_in[3];
  const float* flux_re  = (const float*)d_in[4];
  const float* flux_im  = (const float*)d_in[5];
  const float* dt_seq   = (const float*)d_in[6];
  const float* ln_s_g   = (const float*)d_in[7];
  const float* ln_s_b   = (const float*)d_in[8];
  const float* conv_w   = (const float*)d_in[9];
  const float* conv_b   = (const float*)d_in[10];
  const float* ln_t_g   = (const float*)d_in[11];
  const float* ln_t_b   = (const float*)d_in[12];
  const float* W_re     = (const float*)d_in[13];
  const float* W_im     = (const float*)d_in[14];
  const float* lam_flux = (const float*)d_in[15];
  const float* bf_re    = (const float*)d_in[16];
  const float* bf_im    = (const float*)d_in[17];
  const float* c_re     = (const float*)d_in[18];
  const float* c_im     = (const float*)d_in[19];
  const float* g_w      = (const float*)d_in[20];
  const float* g_b      = (const float*)d_in[21];
  const float* a_decay  = (const float*)d_in[22];
  const float* b_freq   = (const float*)d_in[23];
  const float* ffn_w1   = (const float*)d_in[24];
  const float* ffn_b1   = (const float*)d_in[25];
  const float* ffn_w2   = (const float*)d_in[26];
  const float* ffn_b2   = (const float*)d_in[27];
  const float* sg_w1    = (const float*)d_in[28];
  const float* sg_b1    = (const float*)d_in[29];
  const float* sg_dw    = (const float*)d_in[30];
  const float* sg_w2    = (const float*)d_in[31];
  const float* sg_b2    = (const float*)d_in[32];
  float* out = (float*)d_out;
  float* ws  = (float*)d_ws;

  k_invert<<<1, 256, 0, stream>>>(W_re, W_im, ws);
  k_wprep<<<144, 256, 0, stream>>>(conv_w, (unsigned short*)(ws + WS_WPK));
  k_eprep<<<8, 256, 0, stream>>>(W_re, W_im, sg_w1,
                                 (unsigned*)(ws + WS_WE), (unsigned*)(ws + WS_SG));
  k_ln_s<<<PIX / 256, 256, 0, stream>>>(xre, xim, ln_s_g, ln_s_b, ws);
  k_conv<<<768, 256, 0, stream>>>((const unsigned*)(ws + WS_XN),
                                  (const unsigned short*)(ws + WS_WPK),
                                  conv_b, xre, xim, out);
  k_xeig<<<768, 256, 0, stream>>>(out, (const unsigned*)(ws + WS_WE),
                                  (const unsigned*)(ws + WS_SG),
                                  ws + WS_XE, ws + WS_G1, sg_b1, ws + WS_PART);
  k_flux<<<1, 64, 0, stream>>>(ws, out, dt_seq, flux_re, flux_im, lam_flux,
                               bf_re, bf_im, c_re, c_im, g_w, g_b, a_decay, b_freq);
  k_gate<<<PIX / 128, 256, 0, stream>>>(ws + WS_G1, ws + WS_G2, sg_dw, sg_w2, sg_b2);
  k_scan<<<dim3(4096 / 256, 32, 2), 256, 0, stream>>>(ws + WS_XE, ws + WS_G2,
                                                      ws + WS_GATE, ws + WS_SRCR, ws + WS_SRCI,
                                                      ws + WS_OFR, ws + WS_OFI,
                                                      ws + WS_ODR, ws + WS_ODI,
                                                      hre, him, out);
  k_final<<<768, 256, 0, stream>>>(ws + WS_XE, out, (const unsigned*)(ws + WS_WIB),
                                   ln_t_g, ln_t_b, ffn_w1, ffn_b1, ffn_w2, ffn_b2);
}